// Round 1
// baseline (707.667 us; speedup 1.0000x reference)
//
#include <hip/hip_runtime.h>
#include <hip/hip_bf16.h>
#include <cstddef>

#define B_   8
#define C_   256
#define HH   64
#define WW   64
#define NPOS 4096
#define NH   8
#define HD   32
#define NA   16
#define SCALE 0.17677669529663687f

// ---------------- agent pooling + agent vectors ----------------
// agent[b,h,a,d] = mean_{16x16 tile a}(g) * q_w[h*32+d] + q_b[h*32+d]
__global__ __launch_bounds__(256) void k_agent(const float* __restrict__ g,
                                               const float* __restrict__ q_w,
                                               const float* __restrict__ q_b,
                                               float* __restrict__ agent_buf) {
  const int b = blockIdx.x;
  const int t = threadIdx.x;
  __shared__ float red[256];
  __shared__ float gb[16];
  const int ag = t >> 4, sub = t & 15;
  const int p1 = ag >> 2, p2 = ag & 3;
  const int y = p1 * 16 + sub, x0 = p2 * 16;
  const float* gp = g + (size_t)b * NPOS + y * WW + x0;
  float s = 0.f;
#pragma unroll
  for (int i = 0; i < 16; ++i) s += gp[i];
  red[t] = s;
  __syncthreads();
  if (sub == 0) {
    float tot = 0.f;
    for (int i = 0; i < 16; ++i) tot += red[(ag << 4) + i];
    gb[ag] = tot * (1.0f / 256.0f);
  }
  __syncthreads();
  for (int idx = t; idx < NA * C_; idx += 256) {
    const int a = idx >> 8, ci = idx & 255;
    const int h = ci >> 5, d = ci & 31;
    agent_buf[(((size_t)b * NH + h) * NA + a) * HD + d] = gb[a] * q_w[ci] + q_b[ci];
  }
}

// ---------------- position / agent biases (bilinear 4x4 -> 64x64) ----------------
__global__ __launch_bounds__(256) void k_bias(const float* __restrict__ an_b, const float* __restrict__ na_b,
                                              const float* __restrict__ ah_b, const float* __restrict__ aw_b,
                                              const float* __restrict__ ha_b, const float* __restrict__ wa_b,
                                              float* __restrict__ posb, float* __restrict__ agb) {
  const int idx = blockIdx.x * 256 + threadIdx.x;  // (h,a,pos), total NH*NA*NPOS
  const int pos = idx & (NPOS - 1);
  const int ha_i = idx >> 12;
  const int h = ha_i >> 4, a = ha_i & 15;
  const int y = pos >> 6, x = pos & 63;
  const float sy = (y + 0.5f) * 0.0625f - 0.5f;
  const float sx = (x + 0.5f) * 0.0625f - 0.5f;
  const int y0 = (int)floorf(sy);
  const int x0 = (int)floorf(sx);
  const float wy = sy - (float)y0, wx = sx - (float)x0;
  const int y0c = min(max(y0, 0), 3), y1c = min(max(y0 + 1, 0), 3);
  const int x0c = min(max(x0, 0), 3), x1c = min(max(x0 + 1, 0), 3);
  const float* an4 = an_b + ((size_t)h * NA + a) * 16;
  const float* na4 = na_b + ((size_t)h * NA + a) * 16;
  const float pa_ = (1.f - wy) * ((1.f - wx) * an4[y0c * 4 + x0c] + wx * an4[y0c * 4 + x1c]) +
                    wy * ((1.f - wx) * an4[y1c * 4 + x0c] + wx * an4[y1c * 4 + x1c]);
  const float nv_ = (1.f - wy) * ((1.f - wx) * na4[y0c * 4 + x0c] + wx * na4[y0c * 4 + x1c]) +
                    wy * ((1.f - wx) * na4[y1c * 4 + x0c] + wx * na4[y1c * 4 + x1c]);
  posb[idx] = pa_ + ah_b[((size_t)h * NA + a) * HH + y] + aw_b[((size_t)h * NA + a) * WW + x];
  agb[((size_t)h * NPOS + pos) * NA + a] =
      nv_ + ha_b[((size_t)h * HH + y) * NA + a] + wa_b[((size_t)h * WW + x) * NA + a];
}

// ---------------- kv projection GEMM: kv[b,pos,j] = sum_ci in[b,ci,pos]*kv_w[ci,j] + kv_b[j] ----------------
__global__ __launch_bounds__(256) void k_kv(const float* __restrict__ in1, const float* __restrict__ in2,
                                            const float* __restrict__ kv_w, const float* __restrict__ kv_b,
                                            float* __restrict__ kv1, float* __restrict__ kv2) {
  const float* in = blockIdx.z ? in2 : in1;
  float* out = blockIdx.z ? kv2 : kv1;
  const int mb = blockIdx.x;
  const int b = mb >> 5;
  const int pos0 = (mb & 31) << 7;
  const int j0 = blockIdx.y << 7;
  __shared__ float As[16][132];
  __shared__ float Bs[16][132];
  const int t = threadIdx.x;
  const int tx = t & 15, ty = t >> 4;
  float acc[8][8] = {};
  const float* Ab = in + (size_t)b * (C_ * NPOS);
  const int ar = t >> 5, ac = (t & 31) << 2;
  for (int k0 = 0; k0 < C_; k0 += 16) {
    const float4 a0 = *(const float4*)(Ab + (size_t)(k0 + ar) * NPOS + pos0 + ac);
    const float4 a1 = *(const float4*)(Ab + (size_t)(k0 + ar + 8) * NPOS + pos0 + ac);
    const float4 b0 = *(const float4*)(kv_w + (size_t)(k0 + ar) * 512 + j0 + ac);
    const float4 b1 = *(const float4*)(kv_w + (size_t)(k0 + ar + 8) * 512 + j0 + ac);
    __syncthreads();
    *(float4*)&As[ar][ac] = a0;
    *(float4*)&As[ar + 8][ac] = a1;
    *(float4*)&Bs[ar][ac] = b0;
    *(float4*)&Bs[ar + 8][ac] = b1;
    __syncthreads();
#pragma unroll
    for (int kk = 0; kk < 16; ++kk) {
      float av_[8], bv[8];
#pragma unroll
      for (int i = 0; i < 8; ++i) av_[i] = As[kk][(ty << 3) + i];
#pragma unroll
      for (int j = 0; j < 8; ++j) bv[j] = Bs[kk][(tx << 3) + j];
#pragma unroll
      for (int i = 0; i < 8; ++i)
#pragma unroll
        for (int j = 0; j < 8; ++j) acc[i][j] += av_[i] * bv[j];
    }
  }
  float bias[8];
#pragma unroll
  for (int j = 0; j < 8; ++j) bias[j] = kv_b[j0 + (tx << 3) + j];
#pragma unroll
  for (int i = 0; i < 8; ++i) {
    const int pos = pos0 + (ty << 3) + i;
    float* op = out + ((size_t)b * NPOS + pos) * 512 + j0 + (tx << 3);
    *(float4*)op = make_float4(acc[i][0] + bias[0], acc[i][1] + bias[1], acc[i][2] + bias[2], acc[i][3] + bias[3]);
    *(float4*)(op + 4) = make_float4(acc[i][4] + bias[4], acc[i][5] + bias[5], acc[i][6] + bias[6], acc[i][7] + bias[7]);
  }
}

// ---------------- agent attention: softmax over 4096 positions, fused PV ----------------
__global__ __launch_bounds__(256) void k_agent_attn(const float* __restrict__ kv1, const float* __restrict__ kv2,
                                                    const float* __restrict__ agent_buf,
                                                    const float* __restrict__ pos_bias,
                                                    float* __restrict__ agent_v) {
  const int a = blockIdx.x;
  const int bh = blockIdx.y;
  const int src = blockIdx.z;
  const int b = bh >> 3, h = bh & 7;
  const float* kv = src ? kv2 : kv1;
  const int t = threadIdx.x;
  __shared__ float ag[32];
  __shared__ float red[16];
  __shared__ float wred[128];
  if (t < 32) ag[t] = agent_buf[(((size_t)b * NH + h) * NA + a) * HD + t];
  __syncthreads();
  const float* kb = kv + (size_t)b * NPOS * 512 + h * HD;
  const float* pb = pos_bias + ((size_t)h * NA + a) * NPOS;
  float sreg[16];
  float lmax = -1e30f;
  for (int i = 0; i < 16; ++i) {
    const int pos = i * 256 + t;
    const float4* kp = (const float4*)(kb + (size_t)pos * 512);
    float s = 0.f;
#pragma unroll
    for (int q = 0; q < 8; ++q) {
      const float4 kk = kp[q];
      s += ag[q * 4 + 0] * kk.x + ag[q * 4 + 1] * kk.y + ag[q * 4 + 2] * kk.z + ag[q * 4 + 3] * kk.w;
    }
    s = s * SCALE + pb[pos];
    sreg[i] = s;
    lmax = fmaxf(lmax, s);
  }
#pragma unroll
  for (int off = 32; off; off >>= 1) lmax = fmaxf(lmax, __shfl_xor(lmax, off));
  if ((t & 63) == 0) red[t >> 6] = lmax;
  __syncthreads();
  const float m = fmaxf(fmaxf(red[0], red[1]), fmaxf(red[2], red[3]));
  float lsum = 0.f;
  for (int i = 0; i < 16; ++i) {
    const float e = __expf(sreg[i] - m);
    sreg[i] = e;
    lsum += e;
  }
#pragma unroll
  for (int off = 32; off; off >>= 1) lsum += __shfl_xor(lsum, off);
  if ((t & 63) == 0) red[8 + (t >> 6)] = lsum;
  __syncthreads();
  const float invl = 1.0f / (red[8] + red[9] + red[10] + red[11]);
  float acc[32] = {};
  const float* vbase = kv + (size_t)b * NPOS * 512 + 256 + h * HD;
  for (int i = 0; i < 16; ++i) {
    const int pos = i * 256 + t;
    const float e = sreg[i];
    const float4* vp = (const float4*)(vbase + (size_t)pos * 512);
#pragma unroll
    for (int q = 0; q < 8; ++q) {
      const float4 vv = vp[q];
      acc[q * 4 + 0] += e * vv.x;
      acc[q * 4 + 1] += e * vv.y;
      acc[q * 4 + 2] += e * vv.z;
      acc[q * 4 + 3] += e * vv.w;
    }
  }
#pragma unroll
  for (int d = 0; d < 32; ++d) {
#pragma unroll
    for (int off = 32; off; off >>= 1) acc[d] += __shfl_xor(acc[d], off);
  }
  if ((t & 63) == 0) {
    const int wv = t >> 6;
#pragma unroll
    for (int d = 0; d < 32; ++d) wred[wv * 32 + d] = acc[d];
  }
  __syncthreads();
  if (t < 32) {
    const float r = (wred[t] + wred[32 + t]) + (wred[64 + t] + wred[96 + t]);
    agent_v[((((size_t)src * B_ + b) * NH + h) * NA + a) * HD + t] = r * invl;
  }
}

// ---------------- query attention over 16 agents + output assembly ----------------
__global__ __launch_bounds__(256) void k_qattn(const float* __restrict__ g,
                                               const float* __restrict__ q_w, const float* __restrict__ q_b,
                                               const float* __restrict__ agent_buf,
                                               const float* __restrict__ agent_v,
                                               const float* __restrict__ agent_bias,
                                               float* __restrict__ o1s, float* __restrict__ o2s) {
  const int h = blockIdx.y, b = blockIdx.z;
  const int t = threadIdx.x;
  const int pos = blockIdx.x * 256 + t;
  __shared__ float dotW[16], dotB[16];
  __shared__ float av1[16][32], av2[16][32];
  for (int idx = t; idx < 512; idx += 256) {
    const int a = idx >> 5, d = idx & 31;
    av1[a][d] = agent_v[((((size_t)0 * B_ + b) * NH + h) * NA + a) * HD + d];
    av2[a][d] = agent_v[((((size_t)1 * B_ + b) * NH + h) * NA + a) * HD + d];
  }
  if (t < 16) {
    float dw = 0.f, db = 0.f;
    const float* agp = agent_buf + (((size_t)b * NH + h) * NA + t) * HD;
#pragma unroll
    for (int d = 0; d < HD; ++d) {
      const float ad = agp[d];
      dw += ad * q_w[h * HD + d];
      db += ad * q_b[h * HD + d];
    }
    dotW[t] = dw * SCALE;
    dotB[t] = db * SCALE;
  }
  __syncthreads();
  const float gv = g[(size_t)b * NPOS + pos];
  const float* abp = agent_bias + ((size_t)h * NPOS + pos) * NA;
  float s[16];
  float m = -1e30f;
#pragma unroll
  for (int a = 0; a < 16; ++a) {
    s[a] = gv * dotW[a] + dotB[a] + abp[a];
    m = fmaxf(m, s[a]);
  }
  float l = 0.f;
#pragma unroll
  for (int a = 0; a < 16; ++a) {
    s[a] = __expf(s[a] - m);
    l += s[a];
  }
  const float inv = 1.0f / l;
  float o1[32] = {}, o2[32] = {};
#pragma unroll
  for (int a = 0; a < 16; ++a) {
    const float pa = s[a] * inv;
    const float4* r1 = (const float4*)av1[a];
    const float4* r2 = (const float4*)av2[a];
#pragma unroll
    for (int q = 0; q < 8; ++q) {
      const float4 x1 = r1[q], x2 = r2[q];
      o1[q * 4 + 0] += pa * x1.x; o1[q * 4 + 1] += pa * x1.y; o1[q * 4 + 2] += pa * x1.z; o1[q * 4 + 3] += pa * x1.w;
      o2[q * 4 + 0] += pa * x2.x; o2[q * 4 + 1] += pa * x2.y; o2[q * 4 + 2] += pa * x2.z; o2[q * 4 + 3] += pa * x2.w;
    }
  }
  float* o1p = o1s + ((size_t)b * NPOS + pos) * C_ + h * HD;
  float* o2p = o2s + ((size_t)b * NPOS + pos) * C_ + h * HD;
#pragma unroll
  for (int q = 0; q < 8; ++q) {
    *(float4*)(o1p + q * 4) = make_float4(o1[q * 4], o1[q * 4 + 1], o1[q * 4 + 2], o1[q * 4 + 3]);
    *(float4*)(o2p + q * 4) = make_float4(o2[q * 4], o2[q * 4 + 1], o2[q * 4 + 2], o2[q * 4 + 3]);
  }
}

// ---------------- depthwise 3x3 conv on v (zero pad), += into out buffers ----------------
__global__ __launch_bounds__(256) void k_dwconv(const float* __restrict__ kv1, const float* __restrict__ kv2,
                                                const float* __restrict__ dwc_w, const float* __restrict__ dwc_b,
                                                float* __restrict__ o1s, float* __restrict__ o2s) {
  const float* kv = blockIdx.z ? kv2 : kv1;
  float* out = blockIdx.z ? o2s : o1s;
  const int b = blockIdx.y;
  const int ci = threadIdx.x;
  const int pos0 = blockIdx.x << 3;
  float w[9];
#pragma unroll
  for (int q = 0; q < 9; ++q) w[q] = dwc_w[ci * 9 + q];
  const float bias = dwc_b[ci];
  const float* vb = kv + (size_t)b * NPOS * 512 + 256 + ci;
  for (int pp = 0; pp < 8; ++pp) {
    const int pos = pos0 + pp;
    const int y = pos >> 6, x = pos & 63;
    float acc = bias;
#pragma unroll
    for (int dy = -1; dy <= 1; ++dy) {
      const int yy = y + dy;
      if (yy < 0 || yy > 63) continue;
#pragma unroll
      for (int dx = -1; dx <= 1; ++dx) {
        const int xx = x + dx;
        if (xx < 0 || xx > 63) continue;
        acc += w[(dy + 1) * 3 + (dx + 1)] * vb[(size_t)(yy * 64 + xx) * 512];
      }
    }
    out[((size_t)b * NPOS + pos) * C_ + ci] += acc;
  }
}

// ---------------- output projection + residual, final (b,c,n) layout ----------------
__global__ __launch_bounds__(256) void k_proj(const float* __restrict__ o1s, const float* __restrict__ o2s,
                                              const float* __restrict__ proj_w, const float* __restrict__ proj_b,
                                              const float* __restrict__ in1, const float* __restrict__ in2,
                                              float* __restrict__ out1, float* __restrict__ out2) {
  const float* S = blockIdx.z ? o2s : o1s;
  const float* inp = blockIdx.z ? in2 : in1;
  float* outp = blockIdx.z ? out2 : out1;
  const int mb = blockIdx.x;
  const int b = mb >> 5;
  const int pos0 = (mb & 31) << 7;
  const int ci0 = blockIdx.y << 7;
  __shared__ float Ss[16][132];
  __shared__ float Ws[16][132];
  const int t = threadIdx.x;
  const int py = t & 15, cx = t >> 4;
  float acc[8][8] = {};
  const int lr = t >> 2, lc = (t & 3) << 2;
  const int wr = t >> 5, wc = (t & 31) << 2;
  for (int k0 = 0; k0 < C_; k0 += 16) {
    const float4 s0 = *(const float4*)(S + ((size_t)b * NPOS + pos0 + lr) * C_ + k0 + lc);
    const float4 s1 = *(const float4*)(S + ((size_t)b * NPOS + pos0 + lr + 64) * C_ + k0 + lc);
    const float4 w0 = *(const float4*)(proj_w + (size_t)(k0 + wr) * C_ + ci0 + wc);
    const float4 w1 = *(const float4*)(proj_w + (size_t)(k0 + wr + 8) * C_ + ci0 + wc);
    __syncthreads();
    Ss[lc + 0][lr] = s0.x; Ss[lc + 1][lr] = s0.y; Ss[lc + 2][lr] = s0.z; Ss[lc + 3][lr] = s0.w;
    Ss[lc + 0][lr + 64] = s1.x; Ss[lc + 1][lr + 64] = s1.y; Ss[lc + 2][lr + 64] = s1.z; Ss[lc + 3][lr + 64] = s1.w;
    *(float4*)&Ws[wr][wc] = w0;
    *(float4*)&Ws[wr + 8][wc] = w1;
    __syncthreads();
#pragma unroll
    for (int kk = 0; kk < 16; ++kk) {
      float sv[8], wv[8];
#pragma unroll
      for (int i = 0; i < 8; ++i) sv[i] = Ss[kk][(py << 3) + i];
#pragma unroll
      for (int j = 0; j < 8; ++j) wv[j] = Ws[kk][(cx << 3) + j];
#pragma unroll
      for (int i = 0; i < 8; ++i)
#pragma unroll
        for (int j = 0; j < 8; ++j) acc[i][j] += sv[i] * wv[j];
    }
  }
#pragma unroll
  for (int j = 0; j < 8; ++j) {
    const int ci = ci0 + (cx << 3) + j;
    const float pbj = proj_b[ci];
    const size_t base = ((size_t)b * C_ + ci) * NPOS + pos0 + (py << 3);
    const float* ip = inp + base;
    float* op = outp + base;
    const float4 i0 = *(const float4*)ip;
    const float4 i1 = *(const float4*)(ip + 4);
    *(float4*)op = make_float4(acc[0][j] + pbj + i0.x, acc[1][j] + pbj + i0.y,
                               acc[2][j] + pbj + i0.z, acc[3][j] + pbj + i0.w);
    *(float4*)(op + 4) = make_float4(acc[4][j] + pbj + i1.x, acc[5][j] + pbj + i1.y,
                                     acc[6][j] + pbj + i1.z, acc[7][j] + pbj + i1.w);
  }
}

extern "C" void kernel_launch(void* const* d_in, const int* in_sizes, int n_in,
                              void* d_out, int out_size, void* d_ws, size_t ws_size,
                              hipStream_t stream) {
  const float* input1 = (const float*)d_in[0];
  const float* input2 = (const float*)d_in[1];
  const float* guid   = (const float*)d_in[2];
  const float* kv_w   = (const float*)d_in[3];
  const float* kv_b   = (const float*)d_in[4];
  const float* q_w    = (const float*)d_in[5];
  const float* q_b    = (const float*)d_in[6];
  const float* proj_w = (const float*)d_in[7];
  const float* proj_b = (const float*)d_in[8];
  const float* dwc_w  = (const float*)d_in[9];
  const float* dwc_b  = (const float*)d_in[10];
  const float* an_b   = (const float*)d_in[11];
  const float* na_b   = (const float*)d_in[12];
  const float* ah_b   = (const float*)d_in[13];
  const float* aw_b   = (const float*)d_in[14];
  const float* ha_b   = (const float*)d_in[15];
  const float* wa_b   = (const float*)d_in[16];

  float* ws = (float*)d_ws;
  float* kv1 = ws;
  float* kv2 = kv1 + (size_t)B_ * NPOS * 512;
  float* o1s = kv2 + (size_t)B_ * NPOS * 512;
  float* o2s = o1s + (size_t)B_ * NPOS * C_;
  float* posb = o2s + (size_t)B_ * NPOS * C_;
  float* agb  = posb + (size_t)NH * NA * NPOS;
  float* agentb = agb + (size_t)NH * NPOS * NA;
  float* av     = agentb + (size_t)B_ * NH * NA * HD;

  float* out1 = (float*)d_out;
  float* out2 = out1 + (size_t)B_ * C_ * NPOS;

  hipLaunchKernelGGL(k_agent, dim3(B_), dim3(256), 0, stream, guid, q_w, q_b, agentb);
  hipLaunchKernelGGL(k_bias, dim3((NH * NA * NPOS) / 256), dim3(256), 0, stream,
                     an_b, na_b, ah_b, aw_b, ha_b, wa_b, posb, agb);
  hipLaunchKernelGGL(k_kv, dim3(B_ * NPOS / 128, 4, 2), dim3(256), 0, stream,
                     input1, input2, kv_w, kv_b, kv1, kv2);
  hipLaunchKernelGGL(k_agent_attn, dim3(NA, B_ * NH, 2), dim3(256), 0, stream,
                     kv1, kv2, agentb, posb, av);
  hipLaunchKernelGGL(k_qattn, dim3(NPOS / 256, NH, B_), dim3(256), 0, stream,
                     guid, q_w, q_b, agentb, av, agb, o1s, o2s);
  hipLaunchKernelGGL(k_dwconv, dim3(NPOS / 8, B_, 2), dim3(256), 0, stream,
                     kv1, kv2, dwc_w, dwc_b, o1s, o2s);
  hipLaunchKernelGGL(k_proj, dim3(B_ * NPOS / 128, 2, 2), dim3(256), 0, stream,
                     o1s, o2s, proj_w, proj_b, input1, input2, out1, out2);
}

// Round 2
// 497.629 us; speedup vs baseline: 1.4221x; 1.4221x over previous
//
#include <hip/hip_runtime.h>
#include <hip/hip_bf16.h>
#include <cstddef>

#define B_   8
#define C_   256
#define HH   64
#define WW   64
#define NPOS 4096
#define NH   8
#define HD   32
#define NA   16
#define NCHUNK 4
#define SCALE 0.17677669529663687f

// ---------------- agent pooling + agent vectors ----------------
// agent[b,h,a,d] = mean_{16x16 tile a}(g) * q_w[h*32+d] + q_b[h*32+d]
__global__ __launch_bounds__(256) void k_agent(const float* __restrict__ g,
                                               const float* __restrict__ q_w,
                                               const float* __restrict__ q_b,
                                               float* __restrict__ agent_buf) {
  const int b = blockIdx.x;
  const int t = threadIdx.x;
  __shared__ float red[256];
  __shared__ float gb[16];
  const int ag = t >> 4, sub = t & 15;
  const int p1 = ag >> 2, p2 = ag & 3;
  const int y = p1 * 16 + sub, x0 = p2 * 16;
  const float* gp = g + (size_t)b * NPOS + y * WW + x0;
  float s = 0.f;
#pragma unroll
  for (int i = 0; i < 16; ++i) s += gp[i];
  red[t] = s;
  __syncthreads();
  if (sub == 0) {
    float tot = 0.f;
    for (int i = 0; i < 16; ++i) tot += red[(ag << 4) + i];
    gb[ag] = tot * (1.0f / 256.0f);
  }
  __syncthreads();
  for (int idx = t; idx < NA * C_; idx += 256) {
    const int a = idx >> 8, ci = idx & 255;
    const int h = ci >> 5, d = ci & 31;
    agent_buf[(((size_t)b * NH + h) * NA + a) * HD + d] = gb[a] * q_w[ci] + q_b[ci];
  }
}

// ---------------- position / agent biases (bilinear 4x4 -> 64x64) ----------------
__global__ __launch_bounds__(256) void k_bias(const float* __restrict__ an_b, const float* __restrict__ na_b,
                                              const float* __restrict__ ah_b, const float* __restrict__ aw_b,
                                              const float* __restrict__ ha_b, const float* __restrict__ wa_b,
                                              float* __restrict__ posb, float* __restrict__ agb) {
  const int idx = blockIdx.x * 256 + threadIdx.x;  // (h,a,pos), total NH*NA*NPOS
  const int pos = idx & (NPOS - 1);
  const int ha_i = idx >> 12;
  const int h = ha_i >> 4, a = ha_i & 15;
  const int y = pos >> 6, x = pos & 63;
  const float sy = (y + 0.5f) * 0.0625f - 0.5f;
  const float sx = (x + 0.5f) * 0.0625f - 0.5f;
  const int y0 = (int)floorf(sy);
  const int x0 = (int)floorf(sx);
  const float wy = sy - (float)y0, wx = sx - (float)x0;
  const int y0c = min(max(y0, 0), 3), y1c = min(max(y0 + 1, 0), 3);
  const int x0c = min(max(x0, 0), 3), x1c = min(max(x0 + 1, 0), 3);
  const float* an4 = an_b + ((size_t)h * NA + a) * 16;
  const float* na4 = na_b + ((size_t)h * NA + a) * 16;
  const float pa_ = (1.f - wy) * ((1.f - wx) * an4[y0c * 4 + x0c] + wx * an4[y0c * 4 + x1c]) +
                    wy * ((1.f - wx) * an4[y1c * 4 + x0c] + wx * an4[y1c * 4 + x1c]);
  const float nv_ = (1.f - wy) * ((1.f - wx) * na4[y0c * 4 + x0c] + wx * na4[y0c * 4 + x1c]) +
                    wy * ((1.f - wx) * na4[y1c * 4 + x0c] + wx * na4[y1c * 4 + x1c]);
  posb[idx] = pa_ + ah_b[((size_t)h * NA + a) * HH + y] + aw_b[((size_t)h * NA + a) * WW + x];
  agb[((size_t)h * NPOS + pos) * NA + a] =
      nv_ + ha_b[((size_t)h * HH + y) * NA + a] + wa_b[((size_t)h * WW + x) * NA + a];
}

// ---------------- kv projection GEMM: kv[b,pos,j] = sum_ci in[b,ci,pos]*kv_w[ci,j] + kv_b[j] ----------------
__global__ __launch_bounds__(256) void k_kv(const float* __restrict__ in1, const float* __restrict__ in2,
                                            const float* __restrict__ kv_w, const float* __restrict__ kv_b,
                                            float* __restrict__ kv1, float* __restrict__ kv2) {
  const float* in = blockIdx.z ? in2 : in1;
  float* out = blockIdx.z ? kv2 : kv1;
  const int mb = blockIdx.x;
  const int b = mb >> 5;
  const int pos0 = (mb & 31) << 7;
  const int j0 = blockIdx.y << 7;
  __shared__ float As[16][132];
  __shared__ float Bs[16][132];
  const int t = threadIdx.x;
  const int tx = t & 15, ty = t >> 4;
  float acc[8][8] = {};
  const float* Ab = in + (size_t)b * (C_ * NPOS);
  const int ar = t >> 5, ac = (t & 31) << 2;
  for (int k0 = 0; k0 < C_; k0 += 16) {
    const float4 a0 = *(const float4*)(Ab + (size_t)(k0 + ar) * NPOS + pos0 + ac);
    const float4 a1 = *(const float4*)(Ab + (size_t)(k0 + ar + 8) * NPOS + pos0 + ac);
    const float4 b0 = *(const float4*)(kv_w + (size_t)(k0 + ar) * 512 + j0 + ac);
    const float4 b1 = *(const float4*)(kv_w + (size_t)(k0 + ar + 8) * 512 + j0 + ac);
    __syncthreads();
    *(float4*)&As[ar][ac] = a0;
    *(float4*)&As[ar + 8][ac] = a1;
    *(float4*)&Bs[ar][ac] = b0;
    *(float4*)&Bs[ar + 8][ac] = b1;
    __syncthreads();
#pragma unroll
    for (int kk = 0; kk < 16; ++kk) {
      float av_[8], bv[8];
#pragma unroll
      for (int i = 0; i < 8; ++i) av_[i] = As[kk][(ty << 3) + i];
#pragma unroll
      for (int j = 0; j < 8; ++j) bv[j] = Bs[kk][(tx << 3) + j];
#pragma unroll
      for (int i = 0; i < 8; ++i)
#pragma unroll
        for (int j = 0; j < 8; ++j) acc[i][j] += av_[i] * bv[j];
    }
  }
  float bias[8];
#pragma unroll
  for (int j = 0; j < 8; ++j) bias[j] = kv_b[j0 + (tx << 3) + j];
#pragma unroll
  for (int i = 0; i < 8; ++i) {
    const int pos = pos0 + (ty << 3) + i;
    float* op = out + ((size_t)b * NPOS + pos) * 512 + j0 + (tx << 3);
    *(float4*)op = make_float4(acc[i][0] + bias[0], acc[i][1] + bias[1], acc[i][2] + bias[2], acc[i][3] + bias[3]);
    *(float4*)(op + 4) = make_float4(acc[i][4] + bias[4], acc[i][5] + bias[5], acc[i][6] + bias[6], acc[i][7] + bias[7]);
  }
}

// ---------------- agent attention v2 ----------------
// One block per (src,b,h,chunk of 1024 pos). 8 waves x 2 agents.
// K/V tiles (256 pos x 32 d) staged in LDS with XOR-swizzled float4 slots.
// exp-sum softmax without max subtraction (scores are tiny); partials -> pav.
__global__ __launch_bounds__(512) void k_agent_attn(const float* __restrict__ kv1, const float* __restrict__ kv2,
                                                    const float* __restrict__ agent_buf,
                                                    const float* __restrict__ pos_bias,
                                                    float* __restrict__ pav) {
  const int chunk = blockIdx.x;
  const int bh = blockIdx.y;
  const int src = blockIdx.z;
  const int b = bh >> 3, h = bh & 7;
  const float* kv = src ? kv2 : kv1;

  __shared__ float4 Kt[256 * 8];
  __shared__ float4 Vt[256 * 8];

  const int t = threadIdx.x;
  const int wave = t >> 6, lane = t & 63;
  const int a0 = wave * 2;

  // agent vectors for this wave's 2 agents, pre-scaled by SCALE, in registers
  float4 agq[2][8];
  const float* agb = agent_buf + (((size_t)b * NH + h) * NA + a0) * HD;
#pragma unroll
  for (int a = 0; a < 2; ++a)
#pragma unroll
    for (int d4 = 0; d4 < 8; ++d4) {
      float4 v = *(const float4*)(agb + a * HD + d4 * 4);
      agq[a][d4] = make_float4(v.x * SCALE, v.y * SCALE, v.z * SCALE, v.w * SCALE);
    }

  const size_t rowbase = (size_t)b * NPOS * 512 + h * HD;
  const float* pb0 = pos_bias + ((size_t)h * NA + a0) * NPOS;
  const float* pb1 = pb0 + NPOS;

  float acc[2][32] = {};
  float lsum[2] = {0.f, 0.f};

  float4 rk[4], rv[4];
  const int pos0 = chunk * (NPOS / NCHUNK);

  // prologue: issue loads for tile 0
#pragma unroll
  for (int i = 0; i < 4; ++i) {
    const int idx = t + 512 * i;
    const int p = idx >> 3, d4 = idx & 7;
    const float* sp = kv + rowbase + (size_t)(pos0 + p) * 512 + d4 * 4;
    rk[i] = *(const float4*)sp;
    rv[i] = *(const float4*)(sp + 256);
  }

  for (int tile = 0; tile < 4; ++tile) {
    __syncthreads();  // previous tile's compute done
#pragma unroll
    for (int i = 0; i < 4; ++i) {
      const int idx = t + 512 * i;
      const int p = idx >> 3, d4 = idx & 7;
      const int slot = p * 8 + (d4 ^ (p & 7));
      Kt[slot] = rk[i];
      Vt[slot] = rv[i];
    }
    __syncthreads();
    if (tile < 3) {
      const int nb = pos0 + (tile + 1) * 256;
#pragma unroll
      for (int i = 0; i < 4; ++i) {
        const int idx = t + 512 * i;
        const int p = idx >> 3, d4 = idx & 7;
        const float* sp = kv + rowbase + (size_t)(nb + p) * 512 + d4 * 4;
        rk[i] = *(const float4*)sp;
        rv[i] = *(const float4*)(sp + 256);
      }
    }
    const int gbase = pos0 + tile * 256;
#pragma unroll
    for (int j = 0; j < 4; ++j) {
      const int p = j * 64 + lane;
      float4 kq[8];
#pragma unroll
      for (int d4 = 0; d4 < 8; ++d4) kq[d4] = Kt[p * 8 + (d4 ^ (lane & 7))];
      float s0 = pb0[gbase + p];
      float s1 = pb1[gbase + p];
#pragma unroll
      for (int d4 = 0; d4 < 8; ++d4) {
        s0 += agq[0][d4].x * kq[d4].x + agq[0][d4].y * kq[d4].y +
              agq[0][d4].z * kq[d4].z + agq[0][d4].w * kq[d4].w;
        s1 += agq[1][d4].x * kq[d4].x + agq[1][d4].y * kq[d4].y +
              agq[1][d4].z * kq[d4].z + agq[1][d4].w * kq[d4].w;
      }
      const float e0 = __expf(s0), e1 = __expf(s1);
      lsum[0] += e0;
      lsum[1] += e1;
#pragma unroll
      for (int d4 = 0; d4 < 8; ++d4) {
        const float4 vv = Vt[p * 8 + (d4 ^ (lane & 7))];
        acc[0][d4 * 4 + 0] += e0 * vv.x; acc[0][d4 * 4 + 1] += e0 * vv.y;
        acc[0][d4 * 4 + 2] += e0 * vv.z; acc[0][d4 * 4 + 3] += e0 * vv.w;
        acc[1][d4 * 4 + 0] += e1 * vv.x; acc[1][d4 * 4 + 1] += e1 * vv.y;
        acc[1][d4 * 4 + 2] += e1 * vv.z; acc[1][d4 * 4 + 3] += e1 * vv.w;
      }
    }
  }

  // cross-lane reduce (per wave) and write partials
#pragma unroll
  for (int a = 0; a < 2; ++a) {
    float l = lsum[a];
#pragma unroll
    for (int off = 32; off; off >>= 1) l += __shfl_xor(l, off);
    lsum[a] = l;
#pragma unroll
    for (int d = 0; d < 32; ++d) {
      float v = acc[a][d];
#pragma unroll
      for (int off = 32; off; off >>= 1) v += __shfl_xor(v, off);
      acc[a][d] = v;
    }
  }
  if (lane == 0) {
    float* outp = pav + ((((size_t)src * B_ + b) * NH + h) * NCHUNK + chunk) * (NA * 33) + a0 * 33;
#pragma unroll
    for (int a = 0; a < 2; ++a) {
#pragma unroll
      for (int d = 0; d < 32; ++d) outp[a * 33 + d] = acc[a][d];
      outp[a * 33 + 32] = lsum[a];
    }
  }
}

// ---------------- query attention over 16 agents + output assembly ----------------
__global__ __launch_bounds__(256) void k_qattn(const float* __restrict__ g,
                                               const float* __restrict__ q_w, const float* __restrict__ q_b,
                                               const float* __restrict__ agent_buf,
                                               const float* __restrict__ pav,
                                               const float* __restrict__ agent_bias,
                                               float* __restrict__ o1s, float* __restrict__ o2s) {
  const int h = blockIdx.y, b = blockIdx.z;
  const int t = threadIdx.x;
  const int pos = blockIdx.x * 256 + t;
  __shared__ float dotW[16], dotB[16];
  __shared__ float av1[16][32], av2[16][32];
  for (int idx = t; idx < 512; idx += 256) {
    const int a = idx >> 5, d = idx & 31;
    float s1 = 0.f, l1 = 0.f, s2 = 0.f, l2 = 0.f;
#pragma unroll
    for (int ch = 0; ch < NCHUNK; ++ch) {
      const float* p1 = pav + ((((size_t)0 * B_ + b) * NH + h) * NCHUNK + ch) * (NA * 33) + a * 33;
      const float* p2 = pav + ((((size_t)1 * B_ + b) * NH + h) * NCHUNK + ch) * (NA * 33) + a * 33;
      s1 += p1[d]; l1 += p1[32];
      s2 += p2[d]; l2 += p2[32];
    }
    av1[a][d] = s1 / l1;
    av2[a][d] = s2 / l2;
  }
  if (t < 16) {
    float dw = 0.f, db = 0.f;
    const float* agp = agent_buf + (((size_t)b * NH + h) * NA + t) * HD;
#pragma unroll
    for (int d = 0; d < HD; ++d) {
      const float ad = agp[d];
      dw += ad * q_w[h * HD + d];
      db += ad * q_b[h * HD + d];
    }
    dotW[t] = dw * SCALE;
    dotB[t] = db * SCALE;
  }
  __syncthreads();
  const float gv = g[(size_t)b * NPOS + pos];
  const float* abp = agent_bias + ((size_t)h * NPOS + pos) * NA;
  float s[16];
  float m = -1e30f;
#pragma unroll
  for (int a = 0; a < 16; ++a) {
    s[a] = gv * dotW[a] + dotB[a] + abp[a];
    m = fmaxf(m, s[a]);
  }
  float l = 0.f;
#pragma unroll
  for (int a = 0; a < 16; ++a) {
    s[a] = __expf(s[a] - m);
    l += s[a];
  }
  const float inv = 1.0f / l;
  float o1[32] = {}, o2[32] = {};
#pragma unroll
  for (int a = 0; a < 16; ++a) {
    const float pa = s[a] * inv;
    const float4* r1 = (const float4*)av1[a];
    const float4* r2 = (const float4*)av2[a];
#pragma unroll
    for (int q = 0; q < 8; ++q) {
      const float4 x1 = r1[q], x2 = r2[q];
      o1[q * 4 + 0] += pa * x1.x; o1[q * 4 + 1] += pa * x1.y; o1[q * 4 + 2] += pa * x1.z; o1[q * 4 + 3] += pa * x1.w;
      o2[q * 4 + 0] += pa * x2.x; o2[q * 4 + 1] += pa * x2.y; o2[q * 4 + 2] += pa * x2.z; o2[q * 4 + 3] += pa * x2.w;
    }
  }
  float* o1p = o1s + ((size_t)b * NPOS + pos) * C_ + h * HD;
  float* o2p = o2s + ((size_t)b * NPOS + pos) * C_ + h * HD;
#pragma unroll
  for (int q = 0; q < 8; ++q) {
    *(float4*)(o1p + q * 4) = make_float4(o1[q * 4], o1[q * 4 + 1], o1[q * 4 + 2], o1[q * 4 + 3]);
    *(float4*)(o2p + q * 4) = make_float4(o2[q * 4], o2[q * 4 + 1], o2[q * 4 + 2], o2[q * 4 + 3]);
  }
}

// ---------------- depthwise 3x3 conv on v (zero pad), += into out buffers ----------------
__global__ __launch_bounds__(256) void k_dwconv(const float* __restrict__ kv1, const float* __restrict__ kv2,
                                                const float* __restrict__ dwc_w, const float* __restrict__ dwc_b,
                                                float* __restrict__ o1s, float* __restrict__ o2s) {
  const float* kv = blockIdx.z ? kv2 : kv1;
  float* out = blockIdx.z ? o2s : o1s;
  const int b = blockIdx.y;
  const int ci = threadIdx.x;
  const int pos0 = blockIdx.x << 3;
  float w[9];
#pragma unroll
  for (int q = 0; q < 9; ++q) w[q] = dwc_w[ci * 9 + q];
  const float bias = dwc_b[ci];
  const float* vb = kv + (size_t)b * NPOS * 512 + 256 + ci;
  for (int pp = 0; pp < 8; ++pp) {
    const int pos = pos0 + pp;
    const int y = pos >> 6, x = pos & 63;
    float acc = bias;
#pragma unroll
    for (int dy = -1; dy <= 1; ++dy) {
      const int yy = y + dy;
      if (yy < 0 || yy > 63) continue;
#pragma unroll
      for (int dx = -1; dx <= 1; ++dx) {
        const int xx = x + dx;
        if (xx < 0 || xx > 63) continue;
        acc += w[(dy + 1) * 3 + (dx + 1)] * vb[(size_t)(yy * 64 + xx) * 512];
      }
    }
    out[((size_t)b * NPOS + pos) * C_ + ci] += acc;
  }
}

// ---------------- output projection + residual, final (b,c,n) layout ----------------
__global__ __launch_bounds__(256) void k_proj(const float* __restrict__ o1s, const float* __restrict__ o2s,
                                              const float* __restrict__ proj_w, const float* __restrict__ proj_b,
                                              const float* __restrict__ in1, const float* __restrict__ in2,
                                              float* __restrict__ out1, float* __restrict__ out2) {
  const float* S = blockIdx.z ? o2s : o1s;
  const float* inp = blockIdx.z ? in2 : in1;
  float* outp = blockIdx.z ? out2 : out1;
  const int mb = blockIdx.x;
  const int b = mb >> 5;
  const int pos0 = (mb & 31) << 7;
  const int ci0 = blockIdx.y << 7;
  __shared__ float Ss[16][132];
  __shared__ float Ws[16][132];
  const int t = threadIdx.x;
  const int py = t & 15, cx = t >> 4;
  float acc[8][8] = {};
  const int lr = t >> 2, lc = (t & 3) << 2;
  const int wr = t >> 5, wc = (t & 31) << 2;
  for (int k0 = 0; k0 < C_; k0 += 16) {
    const float4 s0 = *(const float4*)(S + ((size_t)b * NPOS + pos0 + lr) * C_ + k0 + lc);
    const float4 s1 = *(const float4*)(S + ((size_t)b * NPOS + pos0 + lr + 64) * C_ + k0 + lc);
    const float4 w0 = *(const float4*)(proj_w + (size_t)(k0 + wr) * C_ + ci0 + wc);
    const float4 w1 = *(const float4*)(proj_w + (size_t)(k0 + wr + 8) * C_ + ci0 + wc);
    __syncthreads();
    Ss[lc + 0][lr] = s0.x; Ss[lc + 1][lr] = s0.y; Ss[lc + 2][lr] = s0.z; Ss[lc + 3][lr] = s0.w;
    Ss[lc + 0][lr + 64] = s1.x; Ss[lc + 1][lr + 64] = s1.y; Ss[lc + 2][lr + 64] = s1.z; Ss[lc + 3][lr + 64] = s1.w;
    *(float4*)&Ws[wr][wc] = w0;
    *(float4*)&Ws[wr + 8][wc] = w1;
    __syncthreads();
#pragma unroll
    for (int kk = 0; kk < 16; ++kk) {
      float sv[8], wv[8];
#pragma unroll
      for (int i = 0; i < 8; ++i) sv[i] = Ss[kk][(py << 3) + i];
#pragma unroll
      for (int j = 0; j < 8; ++j) wv[j] = Ws[kk][(cx << 3) + j];
#pragma unroll
      for (int i = 0; i < 8; ++i)
#pragma unroll
        for (int j = 0; j < 8; ++j) acc[i][j] += sv[i] * wv[j];
    }
  }
#pragma unroll
  for (int j = 0; j < 8; ++j) {
    const int ci = ci0 + (cx << 3) + j;
    const float pbj = proj_b[ci];
    const size_t base = ((size_t)b * C_ + ci) * NPOS + pos0 + (py << 3);
    const float* ip = inp + base;
    float* op = outp + base;
    const float4 i0 = *(const float4*)ip;
    const float4 i1 = *(const float4*)(ip + 4);
    *(float4*)op = make_float4(acc[0][j] + pbj + i0.x, acc[1][j] + pbj + i0.y,
                               acc[2][j] + pbj + i0.z, acc[3][j] + pbj + i0.w);
    *(float4*)(op + 4) = make_float4(acc[4][j] + pbj + i1.x, acc[5][j] + pbj + i1.y,
                                     acc[6][j] + pbj + i1.z, acc[7][j] + pbj + i1.w);
  }
}

extern "C" void kernel_launch(void* const* d_in, const int* in_sizes, int n_in,
                              void* d_out, int out_size, void* d_ws, size_t ws_size,
                              hipStream_t stream) {
  const float* input1 = (const float*)d_in[0];
  const float* input2 = (const float*)d_in[1];
  const float* guid   = (const float*)d_in[2];
  const float* kv_w   = (const float*)d_in[3];
  const float* kv_b   = (const float*)d_in[4];
  const float* q_w    = (const float*)d_in[5];
  const float* q_b    = (const float*)d_in[6];
  const float* proj_w = (const float*)d_in[7];
  const float* proj_b = (const float*)d_in[8];
  const float* dwc_w  = (const float*)d_in[9];
  const float* dwc_b  = (const float*)d_in[10];
  const float* an_b   = (const float*)d_in[11];
  const float* na_b   = (const float*)d_in[12];
  const float* ah_b   = (const float*)d_in[13];
  const float* aw_b   = (const float*)d_in[14];
  const float* ha_b   = (const float*)d_in[15];
  const float* wa_b   = (const float*)d_in[16];

  float* ws = (float*)d_ws;
  float* kv1 = ws;
  float* kv2 = kv1 + (size_t)B_ * NPOS * 512;
  float* o1s = kv2 + (size_t)B_ * NPOS * 512;
  float* o2s = o1s + (size_t)B_ * NPOS * C_;
  float* posb = o2s + (size_t)B_ * NPOS * C_;
  float* agb  = posb + (size_t)NH * NA * NPOS;
  float* agentb = agb + (size_t)NH * NPOS * NA;
  float* pav    = agentb + (size_t)B_ * NH * NA * HD;

  float* out1 = (float*)d_out;
  float* out2 = out1 + (size_t)B_ * C_ * NPOS;

  hipLaunchKernelGGL(k_agent, dim3(B_), dim3(256), 0, stream, guid, q_w, q_b, agentb);
  hipLaunchKernelGGL(k_bias, dim3((NH * NA * NPOS) / 256), dim3(256), 0, stream,
                     an_b, na_b, ah_b, aw_b, ha_b, wa_b, posb, agb);
  hipLaunchKernelGGL(k_kv, dim3(B_ * NPOS / 128, 4, 2), dim3(256), 0, stream,
                     input1, input2, kv_w, kv_b, kv1, kv2);
  hipLaunchKernelGGL(k_agent_attn, dim3(NCHUNK, B_ * NH, 2), dim3(512), 0, stream,
                     kv1, kv2, agentb, posb, pav);
  hipLaunchKernelGGL(k_qattn, dim3(NPOS / 256, NH, B_), dim3(256), 0, stream,
                     guid, q_w, q_b, agentb, pav, agb, o1s, o2s);
  hipLaunchKernelGGL(k_dwconv, dim3(NPOS / 8, B_, 2), dim3(256), 0, stream,
                     kv1, kv2, dwc_w, dwc_b, o1s, o2s);
  hipLaunchKernelGGL(k_proj, dim3(B_ * NPOS / 128, 2, 2), dim3(256), 0, stream,
                     o1s, o2s, proj_w, proj_b, input1, input2, out1, out2);
}

// Round 3
// 419.127 us; speedup vs baseline: 1.6884x; 1.1873x over previous
//
#include <hip/hip_runtime.h>
#include <hip/hip_bf16.h>
#include <cstddef>

#define B_   8
#define C_   256
#define HH   64
#define WW   64
#define NPOS 4096
#define NH   8
#define HD   32
#define NA   16
#define NCHUNK 4
#define SCALE 0.17677669529663687f

typedef unsigned short u16;
typedef __attribute__((ext_vector_type(8))) short bf16x8;
typedef __attribute__((ext_vector_type(4))) float f32x4;

__device__ __forceinline__ float bfbits2f(u16 u) {
  union { unsigned int i; float f; } x; x.i = ((unsigned int)u) << 16; return x.f;
}
__device__ __forceinline__ u16 f2bfbits(float f) {
  union { float f; unsigned int i; } x; x.f = f;
  unsigned int r = x.i + 0x7fffu + ((x.i >> 16) & 1u);
  return (u16)(r >> 16);
}
__device__ __forceinline__ void unpack8(const uint4 v, float* f) {
  f[0] = bfbits2f((u16)(v.x & 0xffff)); f[1] = bfbits2f((u16)(v.x >> 16));
  f[2] = bfbits2f((u16)(v.y & 0xffff)); f[3] = bfbits2f((u16)(v.y >> 16));
  f[4] = bfbits2f((u16)(v.z & 0xffff)); f[5] = bfbits2f((u16)(v.z >> 16));
  f[6] = bfbits2f((u16)(v.w & 0xffff)); f[7] = bfbits2f((u16)(v.w >> 16));
}

// ---------------- agent pooling + agent vectors ----------------
__global__ __launch_bounds__(256) void k_agent(const float* __restrict__ g,
                                               const float* __restrict__ q_w,
                                               const float* __restrict__ q_b,
                                               float* __restrict__ agent_buf) {
  const int b = blockIdx.x;
  const int t = threadIdx.x;
  __shared__ float red[256];
  __shared__ float gb[16];
  const int ag = t >> 4, sub = t & 15;
  const int p1 = ag >> 2, p2 = ag & 3;
  const int y = p1 * 16 + sub, x0 = p2 * 16;
  const float* gp = g + (size_t)b * NPOS + y * WW + x0;
  float s = 0.f;
#pragma unroll
  for (int i = 0; i < 16; ++i) s += gp[i];
  red[t] = s;
  __syncthreads();
  if (sub == 0) {
    float tot = 0.f;
    for (int i = 0; i < 16; ++i) tot += red[(ag << 4) + i];
    gb[ag] = tot * (1.0f / 256.0f);
  }
  __syncthreads();
  for (int idx = t; idx < NA * C_; idx += 256) {
    const int a = idx >> 8, ci = idx & 255;
    const int h = ci >> 5, d = ci & 31;
    agent_buf[(((size_t)b * NH + h) * NA + a) * HD + d] = gb[a] * q_w[ci] + q_b[ci];
  }
}

// ---------------- position / agent biases ----------------
__global__ __launch_bounds__(256) void k_bias(const float* __restrict__ an_b, const float* __restrict__ na_b,
                                              const float* __restrict__ ah_b, const float* __restrict__ aw_b,
                                              const float* __restrict__ ha_b, const float* __restrict__ wa_b,
                                              float* __restrict__ posb, float* __restrict__ agb) {
  const int idx = blockIdx.x * 256 + threadIdx.x;
  const int pos = idx & (NPOS - 1);
  const int ha_i = idx >> 12;
  const int h = ha_i >> 4, a = ha_i & 15;
  const int y = pos >> 6, x = pos & 63;
  const float sy = (y + 0.5f) * 0.0625f - 0.5f;
  const float sx = (x + 0.5f) * 0.0625f - 0.5f;
  const int y0 = (int)floorf(sy);
  const int x0 = (int)floorf(sx);
  const float wy = sy - (float)y0, wx = sx - (float)x0;
  const int y0c = min(max(y0, 0), 3), y1c = min(max(y0 + 1, 0), 3);
  const int x0c = min(max(x0, 0), 3), x1c = min(max(x0 + 1, 0), 3);
  const float* an4 = an_b + ((size_t)h * NA + a) * 16;
  const float* na4 = na_b + ((size_t)h * NA + a) * 16;
  const float pa_ = (1.f - wy) * ((1.f - wx) * an4[y0c * 4 + x0c] + wx * an4[y0c * 4 + x1c]) +
                    wy * ((1.f - wx) * an4[y1c * 4 + x0c] + wx * an4[y1c * 4 + x1c]);
  const float nv_ = (1.f - wy) * ((1.f - wx) * na4[y0c * 4 + x0c] + wx * na4[y0c * 4 + x1c]) +
                    wy * ((1.f - wx) * na4[y1c * 4 + x0c] + wx * na4[y1c * 4 + x1c]);
  posb[idx] = pa_ + ah_b[((size_t)h * NA + a) * HH + y] + aw_b[((size_t)h * NA + a) * WW + x];
  agb[((size_t)h * NPOS + pos) * NA + a] =
      nv_ + ha_b[((size_t)h * HH + y) * NA + a] + wa_b[((size_t)h * WW + x) * NA + a];
}

// ---------------- transpose+convert inputs: in (b,c,n) f32 -> At (b,n,c) bf16 ----------------
__global__ __launch_bounds__(256) void k_prep_in(const float* __restrict__ in1, const float* __restrict__ in2,
                                                 u16* __restrict__ At1, u16* __restrict__ At2) {
  const int z = blockIdx.z;
  const int src = z >> 3, b = z & 7;
  const float* in = src ? in2 : in1;
  u16* At = src ? At2 : At1;
  const int pos0 = blockIdx.x * 64;
  const int ci0 = blockIdx.y * 64;
  __shared__ float tile[64][68];
  const int t = threadIdx.x;
  const int rpos = (t & 15) << 2, rci = t >> 4;
#pragma unroll
  for (int i = 0; i < 4; ++i) {
    const int ci_l = rci + 16 * i;
    const float4 v = *(const float4*)(in + ((size_t)b * C_ + ci0 + ci_l) * NPOS + pos0 + rpos);
    tile[ci_l][rpos + 0] = v.x; tile[ci_l][rpos + 1] = v.y;
    tile[ci_l][rpos + 2] = v.z; tile[ci_l][rpos + 3] = v.w;
  }
  __syncthreads();
#pragma unroll
  for (int i = 0; i < 2; ++i) {
    const int u = t + 256 * i;
    const int p = u >> 3, s = u & 7;
    unsigned int w[4];
#pragma unroll
    for (int q = 0; q < 4; ++q) {
      const u16 lo = f2bfbits(tile[s * 8 + 2 * q][p]);
      const u16 hi = f2bfbits(tile[s * 8 + 2 * q + 1][p]);
      w[q] = (unsigned int)lo | ((unsigned int)hi << 16);
    }
    uint4 pk = make_uint4(w[0], w[1], w[2], w[3]);
    *(uint4*)(At + ((size_t)(pos0 + p)) * C_ + (size_t)b * NPOS * C_ + ci0 + s * 8) = pk;
  }
}

// ---------------- transpose+convert weights: kv_w -> Wkt[j][ci], proj_w -> Pwt[co][ci] ----------------
__global__ __launch_bounds__(256) void k_prep_w(const float* __restrict__ kv_w, const float* __restrict__ proj_w,
                                                u16* __restrict__ Wkt, u16* __restrict__ Pwt) {
  const int x = blockIdx.x;
  const float* W; u16* T; int j0, ci0, ncols;
  if (x < 32) { W = kv_w;  T = Wkt; j0 = (x & 7) * 64; ci0 = (x >> 3) * 64; ncols = 512; }
  else        { W = proj_w; T = Pwt; j0 = ((x - 32) & 3) * 64; ci0 = ((x - 32) >> 2) * 64; ncols = 256; }
  __shared__ float tile[64][68];
  const int t = threadIdx.x;
  const int rj = (t & 15) << 2, rci = t >> 4;
#pragma unroll
  for (int i = 0; i < 4; ++i) {
    const int ci_l = rci + 16 * i;
    const float4 v = *(const float4*)(W + (size_t)(ci0 + ci_l) * ncols + j0 + rj);
    tile[ci_l][rj + 0] = v.x; tile[ci_l][rj + 1] = v.y;
    tile[ci_l][rj + 2] = v.z; tile[ci_l][rj + 3] = v.w;
  }
  __syncthreads();
#pragma unroll
  for (int i = 0; i < 2; ++i) {
    const int u = t + 256 * i;
    const int p = u >> 3, s = u & 7;
    unsigned int w[4];
#pragma unroll
    for (int q = 0; q < 4; ++q) {
      const u16 lo = f2bfbits(tile[s * 8 + 2 * q][p]);
      const u16 hi = f2bfbits(tile[s * 8 + 2 * q + 1][p]);
      w[q] = (unsigned int)lo | ((unsigned int)hi << 16);
    }
    *(uint4*)(T + (size_t)(j0 + p) * C_ + ci0 + s * 8) = make_uint4(w[0], w[1], w[2], w[3]);
  }
}

// ---------------- kv projection, bf16 MFMA: D[j,pos] = Wkt[j,:] . At[pos,:] ----------------
// A = Wkt (M=j), B = At (N=pos), K=256. Block 128x128, 4 waves 2x2, K-step 64, dbuf LDS.
__global__ __launch_bounds__(256) void k_kv_mfma(const u16* __restrict__ At1, const u16* __restrict__ At2,
                                                 const u16* __restrict__ Wkt, const float* __restrict__ kv_b,
                                                 u16* __restrict__ kv1, u16* __restrict__ kv2) {
  const int z = blockIdx.z;
  const int src = z >> 3, b = z & 7;
  const u16* At = src ? At2 : At1;
  u16* kvout = src ? kv2 : kv1;
  const int pos0 = blockIdx.x * 128;
  const int j0 = blockIdx.y * 128;

  __shared__ u16 Abuf[2][128 * 64];
  __shared__ u16 Bbuf[2][128 * 64];

  const int t = threadIdx.x;
  const int wave = t >> 6, lane = t & 63;
  const int wm = wave >> 1, wn = wave & 1;

  const u16* Ag = Wkt + (size_t)j0 * C_;
  const u16* Bg = At + ((size_t)b * NPOS + pos0) * C_;

  f32x4 acc[4][4];
#pragma unroll
  for (int m = 0; m < 4; ++m)
#pragma unroll
    for (int n = 0; n < 4; ++n) { acc[m][n][0] = 0.f; acc[m][n][1] = 0.f; acc[m][n][2] = 0.f; acc[m][n][3] = 0.f; }

  uint4 ra[4], rb[4];
#pragma unroll
  for (int i = 0; i < 4; ++i) {
    const int u = t + 256 * i, r = u >> 3, s = u & 7;
    ra[i] = *(const uint4*)(Ag + (size_t)r * C_ + s * 8);
    rb[i] = *(const uint4*)(Bg + (size_t)r * C_ + s * 8);
  }

  for (int kt = 0; kt < 4; ++kt) {
    u16* Ab = Abuf[kt & 1];
    u16* Bb = Bbuf[kt & 1];
#pragma unroll
    for (int i = 0; i < 4; ++i) {
      const int u = t + 256 * i, r = u >> 3, s = u & 7;
      const int sw = (s ^ (r & 7)) << 3;
      *(uint4*)(Ab + r * 64 + sw) = ra[i];
      *(uint4*)(Bb + r * 64 + sw) = rb[i];
    }
    if (kt < 3) {
      const int k0 = (kt + 1) * 64;
#pragma unroll
      for (int i = 0; i < 4; ++i) {
        const int u = t + 256 * i, r = u >> 3, s = u & 7;
        ra[i] = *(const uint4*)(Ag + (size_t)r * C_ + k0 + s * 8);
        rb[i] = *(const uint4*)(Bg + (size_t)r * C_ + k0 + s * 8);
      }
    }
    __syncthreads();
#pragma unroll
    for (int kk = 0; kk < 2; ++kk) {
      bf16x8 af[4], bfr[4];
      const int g = lane >> 4;
#pragma unroll
      for (int m = 0; m < 4; ++m) {
        const int r = wm * 64 + m * 16 + (lane & 15);
        const int slot = (kk * 4 + g) ^ (r & 7);
        af[m] = *(const bf16x8*)(Ab + r * 64 + slot * 8);
      }
#pragma unroll
      for (int n = 0; n < 4; ++n) {
        const int c = wn * 64 + n * 16 + (lane & 15);
        const int slot = (kk * 4 + g) ^ (c & 7);
        bfr[n] = *(const bf16x8*)(Bb + c * 64 + slot * 8);
      }
#pragma unroll
      for (int m = 0; m < 4; ++m)
#pragma unroll
        for (int n = 0; n < 4; ++n)
          acc[m][n] = __builtin_amdgcn_mfma_f32_16x16x32_bf16(af[m], bfr[n], acc[m][n], 0, 0, 0);
    }
  }

  // epilogue: lane holds 4 consecutive j (rows) at fixed pos (col)
#pragma unroll
  for (int m = 0; m < 4; ++m) {
    const int jb = j0 + wm * 64 + m * 16 + (lane >> 4) * 4;
    const float4 bv = *(const float4*)(kv_b + jb);
#pragma unroll
    for (int n = 0; n < 4; ++n) {
      const int pos = pos0 + wn * 64 + n * 16 + (lane & 15);
      const f32x4 a = acc[m][n];
      ushort4 st;
      st.x = f2bfbits(a[0] + bv.x); st.y = f2bfbits(a[1] + bv.y);
      st.z = f2bfbits(a[2] + bv.z); st.w = f2bfbits(a[3] + bv.w);
      *(ushort4*)(kvout + ((size_t)b * NPOS + pos) * 512 + jb) = st;
    }
  }
}

// ---------------- agent attention (bf16 K/V) ----------------
__global__ __launch_bounds__(512) void k_agent_attn(const u16* __restrict__ kv1, const u16* __restrict__ kv2,
                                                    const float* __restrict__ agent_buf,
                                                    const float* __restrict__ pos_bias,
                                                    float* __restrict__ pav) {
  const int chunk = blockIdx.x;
  const int bh = blockIdx.y;
  const int src = blockIdx.z;
  const int b = bh >> 3, h = bh & 7;
  const u16* kv = src ? kv2 : kv1;

  __shared__ uint4 Kt[1024];
  __shared__ uint4 Vt[1024];

  const int t = threadIdx.x;
  const int wave = t >> 6, lane = t & 63;
  const int a0 = wave * 2;

  float ag[2][32];
  const float* agp = agent_buf + (((size_t)b * NH + h) * NA + a0) * HD;
#pragma unroll
  for (int a = 0; a < 2; ++a)
#pragma unroll
    for (int d = 0; d < 32; ++d) ag[a][d] = agp[a * 32 + d] * SCALE;

  const size_t rowbase = (size_t)b * NPOS * 512 + h * HD;
  const float* pb0 = pos_bias + ((size_t)h * NA + a0) * NPOS;
  const float* pb1 = pb0 + NPOS;

  float acc[2][32] = {};
  float lsum[2] = {0.f, 0.f};

  uint4 rk[2], rv[2];
  const int pos0 = chunk * (NPOS / NCHUNK);

#pragma unroll
  for (int i = 0; i < 2; ++i) {
    const int idx = t + 512 * i;
    const int p = idx >> 2, s = idx & 3;
    const u16* sp = kv + rowbase + (size_t)(pos0 + p) * 512 + s * 8;
    rk[i] = *(const uint4*)sp;
    rv[i] = *(const uint4*)(sp + 256);
  }

  for (int tile = 0; tile < 4; ++tile) {
    __syncthreads();
#pragma unroll
    for (int i = 0; i < 2; ++i) {
      const int idx = t + 512 * i;
      const int p = idx >> 2, s = idx & 3;
      const int slot = p * 4 + (s ^ (p & 3));
      Kt[slot] = rk[i];
      Vt[slot] = rv[i];
    }
    __syncthreads();
    if (tile < 3) {
      const int nb = pos0 + (tile + 1) * 256;
#pragma unroll
      for (int i = 0; i < 2; ++i) {
        const int idx = t + 512 * i;
        const int p = idx >> 2, s = idx & 3;
        const u16* sp = kv + rowbase + (size_t)(nb + p) * 512 + s * 8;
        rk[i] = *(const uint4*)sp;
        rv[i] = *(const uint4*)(sp + 256);
      }
    }
    const int gbase = pos0 + tile * 256;
#pragma unroll
    for (int j = 0; j < 4; ++j) {
      const int p = j * 64 + lane;
      float s0 = pb0[gbase + p];
      float s1 = pb1[gbase + p];
      float f8[8];
#pragma unroll
      for (int s = 0; s < 4; ++s) {
        unpack8(Kt[p * 4 + (s ^ (p & 3))], f8);
#pragma unroll
        for (int e = 0; e < 8; ++e) {
          s0 += ag[0][s * 8 + e] * f8[e];
          s1 += ag[1][s * 8 + e] * f8[e];
        }
      }
      const float e0 = __expf(s0), e1 = __expf(s1);
      lsum[0] += e0;
      lsum[1] += e1;
#pragma unroll
      for (int s = 0; s < 4; ++s) {
        unpack8(Vt[p * 4 + (s ^ (p & 3))], f8);
#pragma unroll
        for (int e = 0; e < 8; ++e) {
          acc[0][s * 8 + e] += e0 * f8[e];
          acc[1][s * 8 + e] += e1 * f8[e];
        }
      }
    }
  }

#pragma unroll
  for (int a = 0; a < 2; ++a) {
    float l = lsum[a];
#pragma unroll
    for (int off = 32; off; off >>= 1) l += __shfl_xor(l, off);
    lsum[a] = l;
#pragma unroll
    for (int d = 0; d < 32; ++d) {
      float v = acc[a][d];
#pragma unroll
      for (int off = 32; off; off >>= 1) v += __shfl_xor(v, off);
      acc[a][d] = v;
    }
  }
  if (lane == 0) {
    float* outp = pav + ((((size_t)src * B_ + b) * NH + h) * NCHUNK + chunk) * (NA * 33) + a0 * 33;
#pragma unroll
    for (int a = 0; a < 2; ++a) {
#pragma unroll
      for (int d = 0; d < 32; ++d) outp[a * 33 + d] = acc[a][d];
      outp[a * 33 + 32] = lsum[a];
    }
  }
}

// ---------------- query attention over 16 agents, bf16 outputs ----------------
__global__ __launch_bounds__(256) void k_qattn(const float* __restrict__ g,
                                               const float* __restrict__ q_w, const float* __restrict__ q_b,
                                               const float* __restrict__ agent_buf,
                                               const float* __restrict__ pav,
                                               const float* __restrict__ agent_bias,
                                               u16* __restrict__ o1s, u16* __restrict__ o2s) {
  const int h = blockIdx.y, b = blockIdx.z;
  const int t = threadIdx.x;
  const int pos = blockIdx.x * 256 + t;
  __shared__ float dotW[16], dotB[16];
  __shared__ float av1[16][32], av2[16][32];
  for (int idx = t; idx < 512; idx += 256) {
    const int a = idx >> 5, d = idx & 31;
    float s1 = 0.f, l1 = 0.f, s2 = 0.f, l2 = 0.f;
#pragma unroll
    for (int ch = 0; ch < NCHUNK; ++ch) {
      const float* p1 = pav + ((((size_t)0 * B_ + b) * NH + h) * NCHUNK + ch) * (NA * 33) + a * 33;
      const float* p2 = pav + ((((size_t)1 * B_ + b) * NH + h) * NCHUNK + ch) * (NA * 33) + a * 33;
      s1 += p1[d]; l1 += p1[32];
      s2 += p2[d]; l2 += p2[32];
    }
    av1[a][d] = s1 / l1;
    av2[a][d] = s2 / l2;
  }
  if (t < 16) {
    float dw = 0.f, db = 0.f;
    const float* agp = agent_buf + (((size_t)b * NH + h) * NA + t) * HD;
#pragma unroll
    for (int d = 0; d < HD; ++d) {
      const float ad = agp[d];
      dw += ad * q_w[h * HD + d];
      db += ad * q_b[h * HD + d];
    }
    dotW[t] = dw * SCALE;
    dotB[t] = db * SCALE;
  }
  __syncthreads();
  const float gv = g[(size_t)b * NPOS + pos];
  const float* abp = agent_bias + ((size_t)h * NPOS + pos) * NA;
  float s[16];
  float m = -1e30f;
#pragma unroll
  for (int a = 0; a < 16; ++a) {
    s[a] = gv * dotW[a] + dotB[a] + abp[a];
    m = fmaxf(m, s[a]);
  }
  float l = 0.f;
#pragma unroll
  for (int a = 0; a < 16; ++a) {
    s[a] = __expf(s[a] - m);
    l += s[a];
  }
  const float inv = 1.0f / l;
  float o1[32] = {}, o2[32] = {};
#pragma unroll
  for (int a = 0; a < 16; ++a) {
    const float pa = s[a] * inv;
#pragma unroll
    for (int d = 0; d < 32; ++d) {
      o1[d] += pa * av1[a][d];
      o2[d] += pa * av2[a][d];
    }
  }
  u16* o1p = o1s + ((size_t)b * NPOS + pos) * C_ + h * HD;
  u16* o2p = o2s + ((size_t)b * NPOS + pos) * C_ + h * HD;
#pragma unroll
  for (int blk = 0; blk < 4; ++blk) {
    unsigned int w1[4], w2[4];
#pragma unroll
    for (int q = 0; q < 4; ++q) {
      w1[q] = (unsigned int)f2bfbits(o1[blk * 8 + 2 * q]) | ((unsigned int)f2bfbits(o1[blk * 8 + 2 * q + 1]) << 16);
      w2[q] = (unsigned int)f2bfbits(o2[blk * 8 + 2 * q]) | ((unsigned int)f2bfbits(o2[blk * 8 + 2 * q + 1]) << 16);
    }
    *(uint4*)(o1p + blk * 8) = make_uint4(w1[0], w1[1], w1[2], w1[3]);
    *(uint4*)(o2p + blk * 8) = make_uint4(w2[0], w2[1], w2[2], w2[3]);
  }
}

// ---------------- depthwise 3x3 conv (bf16 V, bf16 RMW output) ----------------
__global__ __launch_bounds__(256) void k_dwconv(const u16* __restrict__ kv1, const u16* __restrict__ kv2,
                                                const float* __restrict__ dwc_w, const float* __restrict__ dwc_b,
                                                u16* __restrict__ o1s, u16* __restrict__ o2s) {
  const u16* kv = blockIdx.z ? kv2 : kv1;
  u16* out = blockIdx.z ? o2s : o1s;
  const int b = blockIdx.y;
  const int ci = threadIdx.x;
  const int pos0 = blockIdx.x << 3;
  float w[9];
#pragma unroll
  for (int q = 0; q < 9; ++q) w[q] = dwc_w[ci * 9 + q];
  const float bias = dwc_b[ci];
  const u16* vb = kv + (size_t)b * NPOS * 512 + 256 + ci;
  for (int pp = 0; pp < 8; ++pp) {
    const int pos = pos0 + pp;
    const int y = pos >> 6, x = pos & 63;
    float acc = bias;
#pragma unroll
    for (int dy = -1; dy <= 1; ++dy) {
      const int yy = y + dy;
      if (yy < 0 || yy > 63) continue;
#pragma unroll
      for (int dx = -1; dx <= 1; ++dx) {
        const int xx = x + dx;
        if (xx < 0 || xx > 63) continue;
        acc += w[(dy + 1) * 3 + (dx + 1)] * bfbits2f(vb[(size_t)(yy * 64 + xx) * 512]);
      }
    }
    const size_t oidx = ((size_t)b * NPOS + pos) * C_ + ci;
    out[oidx] = f2bfbits(bfbits2f(out[oidx]) + acc);
  }
}

// ---------------- output projection, bf16 MFMA: D[pos,co] + bias + residual -> (b,c,n) f32 ----------------
__global__ __launch_bounds__(256) void k_proj_mfma(const u16* __restrict__ o1s, const u16* __restrict__ o2s,
                                                   const u16* __restrict__ Pwt, const float* __restrict__ proj_b,
                                                   const float* __restrict__ in1, const float* __restrict__ in2,
                                                   float* __restrict__ out1, float* __restrict__ out2) {
  const int z = blockIdx.z;
  const int src = z >> 3, b = z & 7;
  const u16* S = src ? o2s : o1s;
  const float* inp = src ? in2 : in1;
  float* outp = src ? out2 : out1;
  const int pos0 = blockIdx.x * 128;
  const int co0 = blockIdx.y * 128;

  __shared__ u16 Abuf[2][128 * 64];
  __shared__ u16 Bbuf[2][128 * 64];

  const int t = threadIdx.x;
  const int wave = t >> 6, lane = t & 63;
  const int wm = wave >> 1, wn = wave & 1;

  const u16* Ag = S + ((size_t)b * NPOS + pos0) * C_;
  const u16* Bg = Pwt + (size_t)co0 * C_;

  f32x4 acc[4][4];
#pragma unroll
  for (int m = 0; m < 4; ++m)
#pragma unroll
    for (int n = 0; n < 4; ++n) { acc[m][n][0] = 0.f; acc[m][n][1] = 0.f; acc[m][n][2] = 0.f; acc[m][n][3] = 0.f; }

  uint4 ra[4], rb[4];
#pragma unroll
  for (int i = 0; i < 4; ++i) {
    const int u = t + 256 * i, r = u >> 3, s = u & 7;
    ra[i] = *(const uint4*)(Ag + (size_t)r * C_ + s * 8);
    rb[i] = *(const uint4*)(Bg + (size_t)r * C_ + s * 8);
  }

  for (int kt = 0; kt < 4; ++kt) {
    u16* Ab = Abuf[kt & 1];
    u16* Bb = Bbuf[kt & 1];
#pragma unroll
    for (int i = 0; i < 4; ++i) {
      const int u = t + 256 * i, r = u >> 3, s = u & 7;
      const int sw = (s ^ (r & 7)) << 3;
      *(uint4*)(Ab + r * 64 + sw) = ra[i];
      *(uint4*)(Bb + r * 64 + sw) = rb[i];
    }
    if (kt < 3) {
      const int k0 = (kt + 1) * 64;
#pragma unroll
      for (int i = 0; i < 4; ++i) {
        const int u = t + 256 * i, r = u >> 3, s = u & 7;
        ra[i] = *(const uint4*)(Ag + (size_t)r * C_ + k0 + s * 8);
        rb[i] = *(const uint4*)(Bg + (size_t)r * C_ + k0 + s * 8);
      }
    }
    __syncthreads();
#pragma unroll
    for (int kk = 0; kk < 2; ++kk) {
      bf16x8 af[4], bfr[4];
      const int g = lane >> 4;
#pragma unroll
      for (int m = 0; m < 4; ++m) {
        const int r = wm * 64 + m * 16 + (lane & 15);
        const int slot = (kk * 4 + g) ^ (r & 7);
        af[m] = *(const bf16x8*)(Ab + r * 64 + slot * 8);
      }
#pragma unroll
      for (int n = 0; n < 4; ++n) {
        const int c = wn * 64 + n * 16 + (lane & 15);
        const int slot = (kk * 4 + g) ^ (c & 7);
        bfr[n] = *(const bf16x8*)(Bb + c * 64 + slot * 8);
      }
#pragma unroll
      for (int m = 0; m < 4; ++m)
#pragma unroll
        for (int n = 0; n < 4; ++n)
          acc[m][n] = __builtin_amdgcn_mfma_f32_16x16x32_bf16(af[m], bfr[n], acc[m][n], 0, 0, 0);
    }
  }

  // epilogue: lane holds 4 consecutive pos (rows) at fixed co (col)
#pragma unroll
  for (int m = 0; m < 4; ++m) {
    const int posb = pos0 + wm * 64 + m * 16 + (lane >> 4) * 4;
#pragma unroll
    for (int n = 0; n < 4; ++n) {
      const int co = co0 + wn * 64 + n * 16 + (lane & 15);
      const float pb = proj_b[co];
      const size_t base = ((size_t)b * C_ + co) * NPOS + posb;
      const float4 res = *(const float4*)(inp + base);
      const f32x4 a = acc[m][n];
      *(float4*)(outp + base) = make_float4(a[0] + pb + res.x, a[1] + pb + res.y,
                                            a[2] + pb + res.z, a[3] + pb + res.w);
    }
  }
}

extern "C" void kernel_launch(void* const* d_in, const int* in_sizes, int n_in,
                              void* d_out, int out_size, void* d_ws, size_t ws_size,
                              hipStream_t stream) {
  const float* input1 = (const float*)d_in[0];
  const float* input2 = (const float*)d_in[1];
  const float* guid   = (const float*)d_in[2];
  const float* kv_w   = (const float*)d_in[3];
  const float* kv_b   = (const float*)d_in[4];
  const float* q_w    = (const float*)d_in[5];
  const float* q_b    = (const float*)d_in[6];
  const float* proj_w = (const float*)d_in[7];
  const float* proj_b = (const float*)d_in[8];
  const float* dwc_w  = (const float*)d_in[9];
  const float* dwc_b  = (const float*)d_in[10];
  const float* an_b   = (const float*)d_in[11];
  const float* na_b   = (const float*)d_in[12];
  const float* ah_b   = (const float*)d_in[13];
  const float* aw_b   = (const float*)d_in[14];
  const float* ha_b   = (const float*)d_in[15];
  const float* wa_b   = (const float*)d_in[16];

  char* W = (char*)d_ws;
  u16* At1 = (u16*)W;            W += (size_t)B_ * NPOS * C_ * 2;
  u16* At2 = (u16*)W;            W += (size_t)B_ * NPOS * C_ * 2;
  u16* kv1 = (u16*)W;            W += (size_t)B_ * NPOS * 512 * 2;
  u16* kv2 = (u16*)W;            W += (size_t)B_ * NPOS * 512 * 2;
  u16* o1s = (u16*)W;            W += (size_t)B_ * NPOS * C_ * 2;
  u16* o2s = (u16*)W;            W += (size_t)B_ * NPOS * C_ * 2;
  u16* Wkt = (u16*)W;            W += (size_t)512 * C_ * 2;
  u16* Pwt = (u16*)W;            W += (size_t)C_ * C_ * 2;
  float* posb = (float*)W;       W += (size_t)NH * NA * NPOS * 4;
  float* agb  = (float*)W;       W += (size_t)NH * NPOS * NA * 4;
  float* agentb = (float*)W;     W += (size_t)B_ * NH * NA * HD * 4;
  float* pav    = (float*)W;     W += (size_t)2 * B_ * NH * NCHUNK * NA * 33 * 4;

  float* out1 = (float*)d_out;
  float* out2 = out1 + (size_t)B_ * C_ * NPOS;

  hipLaunchKernelGGL(k_agent, dim3(B_), dim3(256), 0, stream, guid, q_w, q_b, agentb);
  hipLaunchKernelGGL(k_bias, dim3((NH * NA * NPOS) / 256), dim3(256), 0, stream,
                     an_b, na_b, ah_b, aw_b, ha_b, wa_b, posb, agb);
  hipLaunchKernelGGL(k_prep_w, dim3(48), dim3(256), 0, stream, kv_w, proj_w, Wkt, Pwt);
  hipLaunchKernelGGL(k_prep_in, dim3(64, 4, 16), dim3(256), 0, stream, input1, input2, At1, At2);
  hipLaunchKernelGGL(k_kv_mfma, dim3(32, 4, 16), dim3(256), 0, stream,
                     At1, At2, Wkt, kv_b, kv1, kv2);
  hipLaunchKernelGGL(k_agent_attn, dim3(NCHUNK, B_ * NH, 2), dim3(512), 0, stream,
                     kv1, kv2, agentb, posb, pav);
  hipLaunchKernelGGL(k_qattn, dim3(NPOS / 256, NH, B_), dim3(256), 0, stream,
                     guid, q_w, q_b, agentb, pav, agb, o1s, o2s);
  hipLaunchKernelGGL(k_dwconv, dim3(NPOS / 8, B_, 2), dim3(256), 0, stream,
                     kv1, kv2, dwc_w, dwc_b, o1s, o2s);
  hipLaunchKernelGGL(k_proj_mfma, dim3(32, 2, 16), dim3(256), 0, stream,
                     o1s, o2s, Pwt, proj_b, input1, input2, out1, out2);
}

// Round 4
// 417.395 us; speedup vs baseline: 1.6954x; 1.0042x over previous
//
#include <hip/hip_runtime.h>
#include <hip/hip_bf16.h>
#include <cstddef>

#define B_   8
#define C_   256
#define HH   64
#define WW   64
#define NPOS 4096
#define NH   8
#define HD   32
#define NA   16
#define NCHUNK 2
#define SCALE 0.17677669529663687f

typedef unsigned short u16;
typedef __attribute__((ext_vector_type(8))) short bf16x8;
typedef __attribute__((ext_vector_type(4))) float f32x4;

__device__ __forceinline__ float bfbits2f(u16 u) {
  union { unsigned int i; float f; } x; x.i = ((unsigned int)u) << 16; return x.f;
}
__device__ __forceinline__ u16 f2bfbits(float f) {
  union { float f; unsigned int i; } x; x.f = f;
  unsigned int r = x.i + 0x7fffu + ((x.i >> 16) & 1u);
  return (u16)(r >> 16);
}
__device__ __forceinline__ void unpack8(const uint4 v, float* f) {
  f[0] = bfbits2f((u16)(v.x & 0xffff)); f[1] = bfbits2f((u16)(v.x >> 16));
  f[2] = bfbits2f((u16)(v.y & 0xffff)); f[3] = bfbits2f((u16)(v.y >> 16));
  f[4] = bfbits2f((u16)(v.z & 0xffff)); f[5] = bfbits2f((u16)(v.z >> 16));
  f[6] = bfbits2f((u16)(v.w & 0xffff)); f[7] = bfbits2f((u16)(v.w >> 16));
}

// ---------------- agent pooling + agent vectors ----------------
__global__ __launch_bounds__(256) void k_agent(const float* __restrict__ g,
                                               const float* __restrict__ q_w,
                                               const float* __restrict__ q_b,
                                               float* __restrict__ agent_buf) {
  const int b = blockIdx.x;
  const int t = threadIdx.x;
  __shared__ float red[256];
  __shared__ float gb[16];
  const int ag = t >> 4, sub = t & 15;
  const int p1 = ag >> 2, p2 = ag & 3;
  const int y = p1 * 16 + sub, x0 = p2 * 16;
  const float* gp = g + (size_t)b * NPOS + y * WW + x0;
  float s = 0.f;
#pragma unroll
  for (int i = 0; i < 16; ++i) s += gp[i];
  red[t] = s;
  __syncthreads();
  if (sub == 0) {
    float tot = 0.f;
    for (int i = 0; i < 16; ++i) tot += red[(ag << 4) + i];
    gb[ag] = tot * (1.0f / 256.0f);
  }
  __syncthreads();
  for (int idx = t; idx < NA * C_; idx += 256) {
    const int a = idx >> 8, ci = idx & 255;
    const int h = ci >> 5, d = ci & 31;
    agent_buf[(((size_t)b * NH + h) * NA + a) * HD + d] = gb[a] * q_w[ci] + q_b[ci];
  }
}

// ---------------- position / agent biases ----------------
__global__ __launch_bounds__(256) void k_bias(const float* __restrict__ an_b, const float* __restrict__ na_b,
                                              const float* __restrict__ ah_b, const float* __restrict__ aw_b,
                                              const float* __restrict__ ha_b, const float* __restrict__ wa_b,
                                              float* __restrict__ posb, float* __restrict__ agb) {
  const int idx = blockIdx.x * 256 + threadIdx.x;
  const int pos = idx & (NPOS - 1);
  const int ha_i = idx >> 12;
  const int h = ha_i >> 4, a = ha_i & 15;
  const int y = pos >> 6, x = pos & 63;
  const float sy = (y + 0.5f) * 0.0625f - 0.5f;
  const float sx = (x + 0.5f) * 0.0625f - 0.5f;
  const int y0 = (int)floorf(sy);
  const int x0 = (int)floorf(sx);
  const float wy = sy - (float)y0, wx = sx - (float)x0;
  const int y0c = min(max(y0, 0), 3), y1c = min(max(y0 + 1, 0), 3);
  const int x0c = min(max(x0, 0), 3), x1c = min(max(x0 + 1, 0), 3);
  const float* an4 = an_b + ((size_t)h * NA + a) * 16;
  const float* na4 = na_b + ((size_t)h * NA + a) * 16;
  const float pa_ = (1.f - wy) * ((1.f - wx) * an4[y0c * 4 + x0c] + wx * an4[y0c * 4 + x1c]) +
                    wy * ((1.f - wx) * an4[y1c * 4 + x0c] + wx * an4[y1c * 4 + x1c]);
  const float nv_ = (1.f - wy) * ((1.f - wx) * na4[y0c * 4 + x0c] + wx * na4[y0c * 4 + x1c]) +
                    wy * ((1.f - wx) * na4[y1c * 4 + x0c] + wx * na4[y1c * 4 + x1c]);
  posb[idx] = pa_ + ah_b[((size_t)h * NA + a) * HH + y] + aw_b[((size_t)h * NA + a) * WW + x];
  agb[((size_t)h * NPOS + pos) * NA + a] =
      nv_ + ha_b[((size_t)h * HH + y) * NA + a] + wa_b[((size_t)h * WW + x) * NA + a];
}

// ---------------- transpose+convert inputs: in (b,c,n) f32 -> At (b,n,c) bf16 ----------------
__global__ __launch_bounds__(256) void k_prep_in(const float* __restrict__ in1, const float* __restrict__ in2,
                                                 u16* __restrict__ At1, u16* __restrict__ At2) {
  const int z = blockIdx.z;
  const int src = z >> 3, b = z & 7;
  const float* in = src ? in2 : in1;
  u16* At = src ? At2 : At1;
  const int pos0 = blockIdx.x * 64;
  const int ci0 = blockIdx.y * 64;
  __shared__ float tile[64][68];
  const int t = threadIdx.x;
  const int rpos = (t & 15) << 2, rci = t >> 4;
#pragma unroll
  for (int i = 0; i < 4; ++i) {
    const int ci_l = rci + 16 * i;
    const float4 v = *(const float4*)(in + ((size_t)b * C_ + ci0 + ci_l) * NPOS + pos0 + rpos);
    tile[ci_l][rpos + 0] = v.x; tile[ci_l][rpos + 1] = v.y;
    tile[ci_l][rpos + 2] = v.z; tile[ci_l][rpos + 3] = v.w;
  }
  __syncthreads();
#pragma unroll
  for (int i = 0; i < 2; ++i) {
    const int u = t + 256 * i;
    const int p = u >> 3, s = u & 7;
    unsigned int w[4];
#pragma unroll
    for (int q = 0; q < 4; ++q) {
      const u16 lo = f2bfbits(tile[s * 8 + 2 * q][p]);
      const u16 hi = f2bfbits(tile[s * 8 + 2 * q + 1][p]);
      w[q] = (unsigned int)lo | ((unsigned int)hi << 16);
    }
    uint4 pk = make_uint4(w[0], w[1], w[2], w[3]);
    *(uint4*)(At + ((size_t)(pos0 + p)) * C_ + (size_t)b * NPOS * C_ + ci0 + s * 8) = pk;
  }
}

// ---------------- transpose+convert weights ----------------
__global__ __launch_bounds__(256) void k_prep_w(const float* __restrict__ kv_w, const float* __restrict__ proj_w,
                                                u16* __restrict__ Wkt, u16* __restrict__ Pwt) {
  const int x = blockIdx.x;
  const float* W; u16* T; int j0, ci0, ncols;
  if (x < 32) { W = kv_w;  T = Wkt; j0 = (x & 7) * 64; ci0 = (x >> 3) * 64; ncols = 512; }
  else        { W = proj_w; T = Pwt; j0 = ((x - 32) & 3) * 64; ci0 = ((x - 32) >> 2) * 64; ncols = 256; }
  __shared__ float tile[64][68];
  const int t = threadIdx.x;
  const int rj = (t & 15) << 2, rci = t >> 4;
#pragma unroll
  for (int i = 0; i < 4; ++i) {
    const int ci_l = rci + 16 * i;
    const float4 v = *(const float4*)(W + (size_t)(ci0 + ci_l) * ncols + j0 + rj);
    tile[ci_l][rj + 0] = v.x; tile[ci_l][rj + 1] = v.y;
    tile[ci_l][rj + 2] = v.z; tile[ci_l][rj + 3] = v.w;
  }
  __syncthreads();
#pragma unroll
  for (int i = 0; i < 2; ++i) {
    const int u = t + 256 * i;
    const int p = u >> 3, s = u & 7;
    unsigned int w[4];
#pragma unroll
    for (int q = 0; q < 4; ++q) {
      const u16 lo = f2bfbits(tile[s * 8 + 2 * q][p]);
      const u16 hi = f2bfbits(tile[s * 8 + 2 * q + 1][p]);
      w[q] = (unsigned int)lo | ((unsigned int)hi << 16);
    }
    *(uint4*)(T + (size_t)(j0 + p) * C_ + ci0 + s * 8) = make_uint4(w[0], w[1], w[2], w[3]);
  }
}

// ---------------- kv projection, bf16 MFMA ----------------
__global__ __launch_bounds__(256) void k_kv_mfma(const u16* __restrict__ At1, const u16* __restrict__ At2,
                                                 const u16* __restrict__ Wkt, const float* __restrict__ kv_b,
                                                 u16* __restrict__ kv1, u16* __restrict__ kv2) {
  const int z = blockIdx.z;
  const int src = z >> 3, b = z & 7;
  const u16* At = src ? At2 : At1;
  u16* kvout = src ? kv2 : kv1;
  const int pos0 = blockIdx.x * 128;
  const int j0 = blockIdx.y * 128;

  __shared__ u16 Abuf[2][128 * 64];
  __shared__ u16 Bbuf[2][128 * 64];

  const int t = threadIdx.x;
  const int wave = t >> 6, lane = t & 63;
  const int wm = wave >> 1, wn = wave & 1;

  const u16* Ag = Wkt + (size_t)j0 * C_;
  const u16* Bg = At + ((size_t)b * NPOS + pos0) * C_;

  f32x4 acc[4][4];
#pragma unroll
  for (int m = 0; m < 4; ++m)
#pragma unroll
    for (int n = 0; n < 4; ++n) { acc[m][n][0] = 0.f; acc[m][n][1] = 0.f; acc[m][n][2] = 0.f; acc[m][n][3] = 0.f; }

  uint4 ra[4], rb[4];
#pragma unroll
  for (int i = 0; i < 4; ++i) {
    const int u = t + 256 * i, r = u >> 3, s = u & 7;
    ra[i] = *(const uint4*)(Ag + (size_t)r * C_ + s * 8);
    rb[i] = *(const uint4*)(Bg + (size_t)r * C_ + s * 8);
  }

  for (int kt = 0; kt < 4; ++kt) {
    u16* Ab = Abuf[kt & 1];
    u16* Bb = Bbuf[kt & 1];
#pragma unroll
    for (int i = 0; i < 4; ++i) {
      const int u = t + 256 * i, r = u >> 3, s = u & 7;
      const int sw = (s ^ (r & 7)) << 3;
      *(uint4*)(Ab + r * 64 + sw) = ra[i];
      *(uint4*)(Bb + r * 64 + sw) = rb[i];
    }
    if (kt < 3) {
      const int k0 = (kt + 1) * 64;
#pragma unroll
      for (int i = 0; i < 4; ++i) {
        const int u = t + 256 * i, r = u >> 3, s = u & 7;
        ra[i] = *(const uint4*)(Ag + (size_t)r * C_ + k0 + s * 8);
        rb[i] = *(const uint4*)(Bg + (size_t)r * C_ + k0 + s * 8);
      }
    }
    __syncthreads();
#pragma unroll
    for (int kk = 0; kk < 2; ++kk) {
      bf16x8 af[4], bfr[4];
      const int g = lane >> 4;
#pragma unroll
      for (int m = 0; m < 4; ++m) {
        const int r = wm * 64 + m * 16 + (lane & 15);
        const int slot = (kk * 4 + g) ^ (r & 7);
        af[m] = *(const bf16x8*)(Ab + r * 64 + slot * 8);
      }
#pragma unroll
      for (int n = 0; n < 4; ++n) {
        const int c = wn * 64 + n * 16 + (lane & 15);
        const int slot = (kk * 4 + g) ^ (c & 7);
        bfr[n] = *(const bf16x8*)(Bb + c * 64 + slot * 8);
      }
#pragma unroll
      for (int m = 0; m < 4; ++m)
#pragma unroll
        for (int n = 0; n < 4; ++n)
          acc[m][n] = __builtin_amdgcn_mfma_f32_16x16x32_bf16(af[m], bfr[n], acc[m][n], 0, 0, 0);
    }
  }

#pragma unroll
  for (int m = 0; m < 4; ++m) {
    const int jb = j0 + wm * 64 + m * 16 + (lane >> 4) * 4;
    const float4 bv = *(const float4*)(kv_b + jb);
#pragma unroll
    for (int n = 0; n < 4; ++n) {
      const int pos = pos0 + wn * 64 + n * 16 + (lane & 15);
      const f32x4 a = acc[m][n];
      ushort4 st;
      st.x = f2bfbits(a[0] + bv.x); st.y = f2bfbits(a[1] + bv.y);
      st.z = f2bfbits(a[2] + bv.z); st.w = f2bfbits(a[3] + bv.w);
      *(ushort4*)(kvout + ((size_t)b * NPOS + pos) * 512 + jb) = st;
    }
  }
}

// ---------------- agent attention v3: 16 waves, 1 agent/wave, slot-major LDS ----------------
// grid (NCHUNK, b*h, src), block 1024. Chunk = 2048 pos, tiles of 256.
__global__ __launch_bounds__(1024) void k_agent_attn(const u16* __restrict__ kv1, const u16* __restrict__ kv2,
                                                     const float* __restrict__ agent_buf,
                                                     const float* __restrict__ pos_bias,
                                                     float* __restrict__ pav) {
  const int chunk = blockIdx.x;
  const int bh = blockIdx.y;
  const int src = blockIdx.z;
  const int b = bh >> 3, h = bh & 7;
  const u16* kv = src ? kv2 : kv1;

  __shared__ uint4 Kt[4 * 256];  // [slot][pos]
  __shared__ uint4 Vt[4 * 256];

  const int t = threadIdx.x;
  const int wave = t >> 6, lane = t & 63;
  const int a = wave;  // one agent per wave

  float ag[32];
  {
    const float* agp = agent_buf + (((size_t)b * NH + h) * NA + a) * HD;
#pragma unroll
    for (int d = 0; d < 32; ++d) ag[d] = agp[d] * SCALE;
  }

  const size_t rowbase = (size_t)b * NPOS * 512 + h * HD;
  const float* pb = pos_bias + ((size_t)h * NA + a) * NPOS;

  float acc[32] = {};
  float lsum = 0.f;

  // staging indices: thread t covers (p = t>>2, s = t&3)
  const int sp = t >> 2, ss = t & 3;
  const int pos0 = chunk * (NPOS / NCHUNK);

  uint4 rk, rv;
  {
    const u16* gp = kv + rowbase + (size_t)(pos0 + sp) * 512 + ss * 8;
    rk = *(const uint4*)gp;
    rv = *(const uint4*)(gp + 256);
  }

  for (int tile = 0; tile < (NPOS / NCHUNK) / 256; ++tile) {
    __syncthreads();
    Kt[ss * 256 + sp] = rk;
    Vt[ss * 256 + sp] = rv;
    __syncthreads();
    if (tile < (NPOS / NCHUNK) / 256 - 1) {
      const u16* gp = kv + rowbase + (size_t)(pos0 + (tile + 1) * 256 + sp) * 512 + ss * 8;
      rk = *(const uint4*)gp;
      rv = *(const uint4*)(gp + 256);
    }
    const int gbase = pos0 + tile * 256;
#pragma unroll
    for (int j = 0; j < 4; ++j) {
      const int p = j * 64 + lane;
      float s0 = pb[gbase + p];
      float f8[8];
#pragma unroll
      for (int s = 0; s < 4; ++s) {
        unpack8(Kt[s * 256 + p], f8);
#pragma unroll
        for (int e = 0; e < 8; ++e) s0 += ag[s * 8 + e] * f8[e];
      }
      const float e0 = __expf(s0);
      lsum += e0;
#pragma unroll
      for (int s = 0; s < 4; ++s) {
        unpack8(Vt[s * 256 + p], f8);
#pragma unroll
        for (int e = 0; e < 8; ++e) acc[s * 8 + e] += e0 * f8[e];
      }
    }
  }

  // cross-lane reduce within the wave
#pragma unroll
  for (int off = 32; off; off >>= 1) lsum += __shfl_xor(lsum, off);
#pragma unroll
  for (int d = 0; d < 32; ++d) {
    float v = acc[d];
#pragma unroll
    for (int off = 32; off; off >>= 1) v += __shfl_xor(v, off);
    acc[d] = v;
  }
  if (lane == 0) {
    float* outp = pav + (((((size_t)src * B_ + b) * NH + h) * NCHUNK + chunk) * NA + a) * 33;
#pragma unroll
    for (int d = 0; d < 32; ++d) outp[d] = acc[d];
    outp[32] = lsum;
  }
}

// ---------------- query attention over 16 agents, bf16 outputs ----------------
__global__ __launch_bounds__(256) void k_qattn(const float* __restrict__ g,
                                               const float* __restrict__ q_w, const float* __restrict__ q_b,
                                               const float* __restrict__ agent_buf,
                                               const float* __restrict__ pav,
                                               const float* __restrict__ agent_bias,
                                               u16* __restrict__ o1s, u16* __restrict__ o2s) {
  const int h = blockIdx.y, b = blockIdx.z;
  const int t = threadIdx.x;
  const int pos = blockIdx.x * 256 + t;
  __shared__ float dotW[16], dotB[16];
  __shared__ float av1[16][32], av2[16][32];
  for (int idx = t; idx < 512; idx += 256) {
    const int a = idx >> 5, d = idx & 31;
    float s1 = 0.f, l1 = 0.f, s2 = 0.f, l2 = 0.f;
#pragma unroll
    for (int ch = 0; ch < NCHUNK; ++ch) {
      const float* p1 = pav + (((((size_t)0 * B_ + b) * NH + h) * NCHUNK + ch) * NA + a) * 33;
      const float* p2 = pav + (((((size_t)1 * B_ + b) * NH + h) * NCHUNK + ch) * NA + a) * 33;
      s1 += p1[d]; l1 += p1[32];
      s2 += p2[d]; l2 += p2[32];
    }
    av1[a][d] = s1 / l1;
    av2[a][d] = s2 / l2;
  }
  if (t < 16) {
    float dw = 0.f, db = 0.f;
    const float* agp = agent_buf + (((size_t)b * NH + h) * NA + t) * HD;
#pragma unroll
    for (int d = 0; d < HD; ++d) {
      const float ad = agp[d];
      dw += ad * q_w[h * HD + d];
      db += ad * q_b[h * HD + d];
    }
    dotW[t] = dw * SCALE;
    dotB[t] = db * SCALE;
  }
  __syncthreads();
  const float gv = g[(size_t)b * NPOS + pos];
  const float* abp = agent_bias + ((size_t)h * NPOS + pos) * NA;
  float s[16];
  float m = -1e30f;
#pragma unroll
  for (int a = 0; a < 16; ++a) {
    s[a] = gv * dotW[a] + dotB[a] + abp[a];
    m = fmaxf(m, s[a]);
  }
  float l = 0.f;
#pragma unroll
  for (int a = 0; a < 16; ++a) {
    s[a] = __expf(s[a] - m);
    l += s[a];
  }
  const float inv = 1.0f / l;
  float o1[32] = {}, o2[32] = {};
#pragma unroll
  for (int a = 0; a < 16; ++a) {
    const float pa = s[a] * inv;
#pragma unroll
    for (int d = 0; d < 32; ++d) {
      o1[d] += pa * av1[a][d];
      o2[d] += pa * av2[a][d];
    }
  }
  u16* o1p = o1s + ((size_t)b * NPOS + pos) * C_ + h * HD;
  u16* o2p = o2s + ((size_t)b * NPOS + pos) * C_ + h * HD;
#pragma unroll
  for (int blk = 0; blk < 4; ++blk) {
    unsigned int w1[4], w2[4];
#pragma unroll
    for (int q = 0; q < 4; ++q) {
      w1[q] = (unsigned int)f2bfbits(o1[blk * 8 + 2 * q]) | ((unsigned int)f2bfbits(o1[blk * 8 + 2 * q + 1]) << 16);
      w2[q] = (unsigned int)f2bfbits(o2[blk * 8 + 2 * q]) | ((unsigned int)f2bfbits(o2[blk * 8 + 2 * q + 1]) << 16);
    }
    *(uint4*)(o1p + blk * 8) = make_uint4(w1[0], w1[1], w1[2], w1[3]);
    *(uint4*)(o2p + blk * 8) = make_uint4(w2[0], w2[1], w2[2], w2[3]);
  }
}

// ---------------- depthwise 3x3 conv (bf16 V, bf16 RMW output) ----------------
__global__ __launch_bounds__(256) void k_dwconv(const u16* __restrict__ kv1, const u16* __restrict__ kv2,
                                                const float* __restrict__ dwc_w, const float* __restrict__ dwc_b,
                                                u16* __restrict__ o1s, u16* __restrict__ o2s) {
  const u16* kv = blockIdx.z ? kv2 : kv1;
  u16* out = blockIdx.z ? o2s : o1s;
  const int b = blockIdx.y;
  const int ci = threadIdx.x;
  const int pos0 = blockIdx.x << 3;
  float w[9];
#pragma unroll
  for (int q = 0; q < 9; ++q) w[q] = dwc_w[ci * 9 + q];
  const float bias = dwc_b[ci];
  const u16* vb = kv + (size_t)b * NPOS * 512 + 256 + ci;
  for (int pp = 0; pp < 8; ++pp) {
    const int pos = pos0 + pp;
    const int y = pos >> 6, x = pos & 63;
    float acc = bias;
#pragma unroll
    for (int dy = -1; dy <= 1; ++dy) {
      const int yy = y + dy;
      if (yy < 0 || yy > 63) continue;
#pragma unroll
      for (int dx = -1; dx <= 1; ++dx) {
        const int xx = x + dx;
        if (xx < 0 || xx > 63) continue;
        acc += w[(dy + 1) * 3 + (dx + 1)] * bfbits2f(vb[(size_t)(yy * 64 + xx) * 512]);
      }
    }
    const size_t oidx = ((size_t)b * NPOS + pos) * C_ + ci;
    out[oidx] = f2bfbits(bfbits2f(out[oidx]) + acc);
  }
}

// ---------------- output projection, bf16 MFMA -> (b,c,n) f32 + bias + residual ----------------
__global__ __launch_bounds__(256) void k_proj_mfma(const u16* __restrict__ o1s, const u16* __restrict__ o2s,
                                                   const u16* __restrict__ Pwt, const float* __restrict__ proj_b,
                                                   const float* __restrict__ in1, const float* __restrict__ in2,
                                                   float* __restrict__ out1, float* __restrict__ out2) {
  const int z = blockIdx.z;
  const int src = z >> 3, b = z & 7;
  const u16* S = src ? o2s : o1s;
  const float* inp = src ? in2 : in1;
  float* outp = src ? out2 : out1;
  const int pos0 = blockIdx.x * 128;
  const int co0 = blockIdx.y * 128;

  __shared__ u16 Abuf[2][128 * 64];
  __shared__ u16 Bbuf[2][128 * 64];

  const int t = threadIdx.x;
  const int wave = t >> 6, lane = t & 63;
  const int wm = wave >> 1, wn = wave & 1;

  const u16* Ag = S + ((size_t)b * NPOS + pos0) * C_;
  const u16* Bg = Pwt + (size_t)co0 * C_;

  f32x4 acc[4][4];
#pragma unroll
  for (int m = 0; m < 4; ++m)
#pragma unroll
    for (int n = 0; n < 4; ++n) { acc[m][n][0] = 0.f; acc[m][n][1] = 0.f; acc[m][n][2] = 0.f; acc[m][n][3] = 0.f; }

  uint4 ra[4], rb[4];
#pragma unroll
  for (int i = 0; i < 4; ++i) {
    const int u = t + 256 * i, r = u >> 3, s = u & 7;
    ra[i] = *(const uint4*)(Ag + (size_t)r * C_ + s * 8);
    rb[i] = *(const uint4*)(Bg + (size_t)r * C_ + s * 8);
  }

  for (int kt = 0; kt < 4; ++kt) {
    u16* Ab = Abuf[kt & 1];
    u16* Bb = Bbuf[kt & 1];
#pragma unroll
    for (int i = 0; i < 4; ++i) {
      const int u = t + 256 * i, r = u >> 3, s = u & 7;
      const int sw = (s ^ (r & 7)) << 3;
      *(uint4*)(Ab + r * 64 + sw) = ra[i];
      *(uint4*)(Bb + r * 64 + sw) = rb[i];
    }
    if (kt < 3) {
      const int k0 = (kt + 1) * 64;
#pragma unroll
      for (int i = 0; i < 4; ++i) {
        const int u = t + 256 * i, r = u >> 3, s = u & 7;
        ra[i] = *(const uint4*)(Ag + (size_t)r * C_ + k0 + s * 8);
        rb[i] = *(const uint4*)(Bg + (size_t)r * C_ + k0 + s * 8);
      }
    }
    __syncthreads();
#pragma unroll
    for (int kk = 0; kk < 2; ++kk) {
      bf16x8 af[4], bfr[4];
      const int g = lane >> 4;
#pragma unroll
      for (int m = 0; m < 4; ++m) {
        const int r = wm * 64 + m * 16 + (lane & 15);
        const int slot = (kk * 4 + g) ^ (r & 7);
        af[m] = *(const bf16x8*)(Ab + r * 64 + slot * 8);
      }
#pragma unroll
      for (int n = 0; n < 4; ++n) {
        const int c = wn * 64 + n * 16 + (lane & 15);
        const int slot = (kk * 4 + g) ^ (c & 7);
        bfr[n] = *(const bf16x8*)(Bb + c * 64 + slot * 8);
      }
#pragma unroll
      for (int m = 0; m < 4; ++m)
#pragma unroll
        for (int n = 0; n < 4; ++n)
          acc[m][n] = __builtin_amdgcn_mfma_f32_16x16x32_bf16(af[m], bfr[n], acc[m][n], 0, 0, 0);
    }
  }

#pragma unroll
  for (int m = 0; m < 4; ++m) {
    const int posb = pos0 + wm * 64 + m * 16 + (lane >> 4) * 4;
#pragma unroll
    for (int n = 0; n < 4; ++n) {
      const int co = co0 + wn * 64 + n * 16 + (lane & 15);
      const float pb = proj_b[co];
      const size_t base = ((size_t)b * C_ + co) * NPOS + posb;
      const float4 res = *(const float4*)(inp + base);
      const f32x4 a = acc[m][n];
      *(float4*)(outp + base) = make_float4(a[0] + pb + res.x, a[1] + pb + res.y,
                                            a[2] + pb + res.z, a[3] + pb + res.w);
    }
  }
}

extern "C" void kernel_launch(void* const* d_in, const int* in_sizes, int n_in,
                              void* d_out, int out_size, void* d_ws, size_t ws_size,
                              hipStream_t stream) {
  const float* input1 = (const float*)d_in[0];
  const float* input2 = (const float*)d_in[1];
  const float* guid   = (const float*)d_in[2];
  const float* kv_w   = (const float*)d_in[3];
  const float* kv_b   = (const float*)d_in[4];
  const float* q_w    = (const float*)d_in[5];
  const float* q_b    = (const float*)d_in[6];
  const float* proj_w = (const float*)d_in[7];
  const float* proj_b = (const float*)d_in[8];
  const float* dwc_w  = (const float*)d_in[9];
  const float* dwc_b  = (const float*)d_in[10];
  const float* an_b   = (const float*)d_in[11];
  const float* na_b   = (const float*)d_in[12];
  const float* ah_b   = (const float*)d_in[13];
  const float* aw_b   = (const float*)d_in[14];
  const float* ha_b   = (const float*)d_in[15];
  const float* wa_b   = (const float*)d_in[16];

  char* W = (char*)d_ws;
  u16* At1 = (u16*)W;            W += (size_t)B_ * NPOS * C_ * 2;
  u16* At2 = (u16*)W;            W += (size_t)B_ * NPOS * C_ * 2;
  u16* kv1 = (u16*)W;            W += (size_t)B_ * NPOS * 512 * 2;
  u16* kv2 = (u16*)W;            W += (size_t)B_ * NPOS * 512 * 2;
  u16* o1s = (u16*)W;            W += (size_t)B_ * NPOS * C_ * 2;
  u16* o2s = (u16*)W;            W += (size_t)B_ * NPOS * C_ * 2;
  u16* Wkt = (u16*)W;            W += (size_t)512 * C_ * 2;
  u16* Pwt = (u16*)W;            W += (size_t)C_ * C_ * 2;
  float* posb = (float*)W;       W += (size_t)NH * NA * NPOS * 4;
  float* agb  = (float*)W;       W += (size_t)NH * NPOS * NA * 4;
  float* agentb = (float*)W;     W += (size_t)B_ * NH * NA * HD * 4;
  float* pav    = (float*)W;     W += (size_t)2 * B_ * NH * NCHUNK * NA * 33 * 4;

  float* out1 = (float*)d_out;
  float* out2 = out1 + (size_t)B_ * C_ * NPOS;

  hipLaunchKernelGGL(k_agent, dim3(B_), dim3(256), 0, stream, guid, q_w, q_b, agentb);
  hipLaunchKernelGGL(k_bias, dim3((NH * NA * NPOS) / 256), dim3(256), 0, stream,
                     an_b, na_b, ah_b, aw_b, ha_b, wa_b, posb, agb);
  hipLaunchKernelGGL(k_prep_w, dim3(48), dim3(256), 0, stream, kv_w, proj_w, Wkt, Pwt);
  hipLaunchKernelGGL(k_prep_in, dim3(64, 4, 16), dim3(256), 0, stream, input1, input2, At1, At2);
  hipLaunchKernelGGL(k_kv_mfma, dim3(32, 4, 16), dim3(256), 0, stream,
                     At1, At2, Wkt, kv_b, kv1, kv2);
  hipLaunchKernelGGL(k_agent_attn, dim3(NCHUNK, B_ * NH, 2), dim3(1024), 0, stream,
                     kv1, kv2, agentb, posb, pav);
  hipLaunchKernelGGL(k_qattn, dim3(NPOS / 256, NH, B_), dim3(256), 0, stream,
                     guid, q_w, q_b, agentb, pav, agb, o1s, o2s);
  hipLaunchKernelGGL(k_dwconv, dim3(NPOS / 8, B_, 2), dim3(256), 0, stream,
                     kv1, kv2, dwc_w, dwc_b, o1s, o2s);
  hipLaunchKernelGGL(k_proj_mfma, dim3(32, 2, 16), dim3(256), 0, stream,
                     o1s, o2s, Pwt, proj_b, input1, input2, out1, out2);
}

// Round 5
// 308.769 us; speedup vs baseline: 2.2919x; 1.3518x over previous
//
#include <hip/hip_runtime.h>
#include <hip/hip_bf16.h>
#include <cstddef>

#define B_   8
#define C_   256
#define HH   64
#define WW   64
#define NPOS 4096
#define NH   8
#define HD   32
#define NA   16
#define NCHUNK 2
#define SCALE 0.17677669529663687f

typedef unsigned short u16;
typedef __attribute__((ext_vector_type(8))) short bf16x8;
typedef __attribute__((ext_vector_type(4))) float f32x4;

__device__ __forceinline__ float bfbits2f(u16 u) {
  union { unsigned int i; float f; } x; x.i = ((unsigned int)u) << 16; return x.f;
}
__device__ __forceinline__ u16 f2bfbits(float f) {
  union { float f; unsigned int i; } x; x.f = f;
  unsigned int r = x.i + 0x7fffu + ((x.i >> 16) & 1u);
  return (u16)(r >> 16);
}
__device__ __forceinline__ void unpack8(const uint4 v, float* f) {
  f[0] = bfbits2f((u16)(v.x & 0xffff)); f[1] = bfbits2f((u16)(v.x >> 16));
  f[2] = bfbits2f((u16)(v.y & 0xffff)); f[3] = bfbits2f((u16)(v.y >> 16));
  f[4] = bfbits2f((u16)(v.z & 0xffff)); f[5] = bfbits2f((u16)(v.z >> 16));
  f[6] = bfbits2f((u16)(v.w & 0xffff)); f[7] = bfbits2f((u16)(v.w >> 16));
}

// ---------------- agent pooling + agent vectors ----------------
__global__ __launch_bounds__(256) void k_agent(const float* __restrict__ g,
                                               const float* __restrict__ q_w,
                                               const float* __restrict__ q_b,
                                               float* __restrict__ agent_buf) {
  const int b = blockIdx.x;
  const int t = threadIdx.x;
  __shared__ float red[256];
  __shared__ float gb[16];
  const int ag = t >> 4, sub = t & 15;
  const int p1 = ag >> 2, p2 = ag & 3;
  const int y = p1 * 16 + sub, x0 = p2 * 16;
  const float* gp = g + (size_t)b * NPOS + y * WW + x0;
  float s = 0.f;
#pragma unroll
  for (int i = 0; i < 16; ++i) s += gp[i];
  red[t] = s;
  __syncthreads();
  if (sub == 0) {
    float tot = 0.f;
    for (int i = 0; i < 16; ++i) tot += red[(ag << 4) + i];
    gb[ag] = tot * (1.0f / 256.0f);
  }
  __syncthreads();
  for (int idx = t; idx < NA * C_; idx += 256) {
    const int a = idx >> 8, ci = idx & 255;
    const int h = ci >> 5, d = ci & 31;
    agent_buf[(((size_t)b * NH + h) * NA + a) * HD + d] = gb[a] * q_w[ci] + q_b[ci];
  }
}

// ---------------- position / agent biases ----------------
__global__ __launch_bounds__(256) void k_bias(const float* __restrict__ an_b, const float* __restrict__ na_b,
                                              const float* __restrict__ ah_b, const float* __restrict__ aw_b,
                                              const float* __restrict__ ha_b, const float* __restrict__ wa_b,
                                              float* __restrict__ posb, float* __restrict__ agb) {
  const int idx = blockIdx.x * 256 + threadIdx.x;
  const int pos = idx & (NPOS - 1);
  const int ha_i = idx >> 12;
  const int h = ha_i >> 4, a = ha_i & 15;
  const int y = pos >> 6, x = pos & 63;
  const float sy = (y + 0.5f) * 0.0625f - 0.5f;
  const float sx = (x + 0.5f) * 0.0625f - 0.5f;
  const int y0 = (int)floorf(sy);
  const int x0 = (int)floorf(sx);
  const float wy = sy - (float)y0, wx = sx - (float)x0;
  const int y0c = min(max(y0, 0), 3), y1c = min(max(y0 + 1, 0), 3);
  const int x0c = min(max(x0, 0), 3), x1c = min(max(x0 + 1, 0), 3);
  const float* an4 = an_b + ((size_t)h * NA + a) * 16;
  const float* na4 = na_b + ((size_t)h * NA + a) * 16;
  const float pa_ = (1.f - wy) * ((1.f - wx) * an4[y0c * 4 + x0c] + wx * an4[y0c * 4 + x1c]) +
                    wy * ((1.f - wx) * an4[y1c * 4 + x0c] + wx * an4[y1c * 4 + x1c]);
  const float nv_ = (1.f - wy) * ((1.f - wx) * na4[y0c * 4 + x0c] + wx * na4[y0c * 4 + x1c]) +
                    wy * ((1.f - wx) * na4[y1c * 4 + x0c] + wx * na4[y1c * 4 + x1c]);
  posb[idx] = pa_ + ah_b[((size_t)h * NA + a) * HH + y] + aw_b[((size_t)h * NA + a) * WW + x];
  agb[((size_t)h * NPOS + pos) * NA + a] =
      nv_ + ha_b[((size_t)h * HH + y) * NA + a] + wa_b[((size_t)h * WW + x) * NA + a];
}

// ---------------- transpose+convert inputs: in (b,c,n) f32 -> At (b,n,c) bf16 ----------------
__global__ __launch_bounds__(256) void k_prep_in(const float* __restrict__ in1, const float* __restrict__ in2,
                                                 u16* __restrict__ At1, u16* __restrict__ At2) {
  const int z = blockIdx.z;
  const int src = z >> 3, b = z & 7;
  const float* in = src ? in2 : in1;
  u16* At = src ? At2 : At1;
  const int pos0 = blockIdx.x * 64;
  const int ci0 = blockIdx.y * 64;
  __shared__ float tile[64][68];
  const int t = threadIdx.x;
  const int rpos = (t & 15) << 2, rci = t >> 4;
#pragma unroll
  for (int i = 0; i < 4; ++i) {
    const int ci_l = rci + 16 * i;
    const float4 v = *(const float4*)(in + ((size_t)b * C_ + ci0 + ci_l) * NPOS + pos0 + rpos);
    tile[ci_l][rpos + 0] = v.x; tile[ci_l][rpos + 1] = v.y;
    tile[ci_l][rpos + 2] = v.z; tile[ci_l][rpos + 3] = v.w;
  }
  __syncthreads();
#pragma unroll
  for (int i = 0; i < 2; ++i) {
    const int u = t + 256 * i;
    const int p = u >> 3, s = u & 7;
    unsigned int w[4];
#pragma unroll
    for (int q = 0; q < 4; ++q) {
      const u16 lo = f2bfbits(tile[s * 8 + 2 * q][p]);
      const u16 hi = f2bfbits(tile[s * 8 + 2 * q + 1][p]);
      w[q] = (unsigned int)lo | ((unsigned int)hi << 16);
    }
    uint4 pk = make_uint4(w[0], w[1], w[2], w[3]);
    *(uint4*)(At + ((size_t)(pos0 + p)) * C_ + (size_t)b * NPOS * C_ + ci0 + s * 8) = pk;
  }
}

// ---------------- transpose+convert weights ----------------
__global__ __launch_bounds__(256) void k_prep_w(const float* __restrict__ kv_w, const float* __restrict__ proj_w,
                                                u16* __restrict__ Wkt, u16* __restrict__ Pwt) {
  const int x = blockIdx.x;
  const float* W; u16* T; int j0, ci0, ncols;
  if (x < 32) { W = kv_w;  T = Wkt; j0 = (x & 7) * 64; ci0 = (x >> 3) * 64; ncols = 512; }
  else        { W = proj_w; T = Pwt; j0 = ((x - 32) & 3) * 64; ci0 = ((x - 32) >> 2) * 64; ncols = 256; }
  __shared__ float tile[64][68];
  const int t = threadIdx.x;
  const int rj = (t & 15) << 2, rci = t >> 4;
#pragma unroll
  for (int i = 0; i < 4; ++i) {
    const int ci_l = rci + 16 * i;
    const float4 v = *(const float4*)(W + (size_t)(ci0 + ci_l) * ncols + j0 + rj);
    tile[ci_l][rj + 0] = v.x; tile[ci_l][rj + 1] = v.y;
    tile[ci_l][rj + 2] = v.z; tile[ci_l][rj + 3] = v.w;
  }
  __syncthreads();
#pragma unroll
  for (int i = 0; i < 2; ++i) {
    const int u = t + 256 * i;
    const int p = u >> 3, s = u & 7;
    unsigned int w[4];
#pragma unroll
    for (int q = 0; q < 4; ++q) {
      const u16 lo = f2bfbits(tile[s * 8 + 2 * q][p]);
      const u16 hi = f2bfbits(tile[s * 8 + 2 * q + 1][p]);
      w[q] = (unsigned int)lo | ((unsigned int)hi << 16);
    }
    *(uint4*)(T + (size_t)(j0 + p) * C_ + ci0 + s * 8) = make_uint4(w[0], w[1], w[2], w[3]);
  }
}

// ---------------- kv projection, bf16 MFMA ----------------
__global__ __launch_bounds__(256) void k_kv_mfma(const u16* __restrict__ At1, const u16* __restrict__ At2,
                                                 const u16* __restrict__ Wkt, const float* __restrict__ kv_b,
                                                 u16* __restrict__ kv1, u16* __restrict__ kv2) {
  const int z = blockIdx.z;
  const int src = z >> 3, b = z & 7;
  const u16* At = src ? At2 : At1;
  u16* kvout = src ? kv2 : kv1;
  const int pos0 = blockIdx.x * 128;
  const int j0 = blockIdx.y * 128;

  __shared__ u16 Abuf[2][128 * 64];
  __shared__ u16 Bbuf[2][128 * 64];

  const int t = threadIdx.x;
  const int wave = t >> 6, lane = t & 63;
  const int wm = wave >> 1, wn = wave & 1;

  const u16* Ag = Wkt + (size_t)j0 * C_;
  const u16* Bg = At + ((size_t)b * NPOS + pos0) * C_;

  f32x4 acc[4][4];
#pragma unroll
  for (int m = 0; m < 4; ++m)
#pragma unroll
    for (int n = 0; n < 4; ++n) { acc[m][n][0] = 0.f; acc[m][n][1] = 0.f; acc[m][n][2] = 0.f; acc[m][n][3] = 0.f; }

  uint4 ra[4], rb[4];
#pragma unroll
  for (int i = 0; i < 4; ++i) {
    const int u = t + 256 * i, r = u >> 3, s = u & 7;
    ra[i] = *(const uint4*)(Ag + (size_t)r * C_ + s * 8);
    rb[i] = *(const uint4*)(Bg + (size_t)r * C_ + s * 8);
  }

  for (int kt = 0; kt < 4; ++kt) {
    u16* Ab = Abuf[kt & 1];
    u16* Bb = Bbuf[kt & 1];
#pragma unroll
    for (int i = 0; i < 4; ++i) {
      const int u = t + 256 * i, r = u >> 3, s = u & 7;
      const int sw = (s ^ (r & 7)) << 3;
      *(uint4*)(Ab + r * 64 + sw) = ra[i];
      *(uint4*)(Bb + r * 64 + sw) = rb[i];
    }
    if (kt < 3) {
      const int k0 = (kt + 1) * 64;
#pragma unroll
      for (int i = 0; i < 4; ++i) {
        const int u = t + 256 * i, r = u >> 3, s = u & 7;
        ra[i] = *(const uint4*)(Ag + (size_t)r * C_ + k0 + s * 8);
        rb[i] = *(const uint4*)(Bg + (size_t)r * C_ + k0 + s * 8);
      }
    }
    __syncthreads();
#pragma unroll
    for (int kk = 0; kk < 2; ++kk) {
      bf16x8 af[4], bfr[4];
      const int g = lane >> 4;
#pragma unroll
      for (int m = 0; m < 4; ++m) {
        const int r = wm * 64 + m * 16 + (lane & 15);
        const int slot = (kk * 4 + g) ^ (r & 7);
        af[m] = *(const bf16x8*)(Ab + r * 64 + slot * 8);
      }
#pragma unroll
      for (int n = 0; n < 4; ++n) {
        const int c = wn * 64 + n * 16 + (lane & 15);
        const int slot = (kk * 4 + g) ^ (c & 7);
        bfr[n] = *(const bf16x8*)(Bb + c * 64 + slot * 8);
      }
#pragma unroll
      for (int m = 0; m < 4; ++m)
#pragma unroll
        for (int n = 0; n < 4; ++n)
          acc[m][n] = __builtin_amdgcn_mfma_f32_16x16x32_bf16(af[m], bfr[n], acc[m][n], 0, 0, 0);
    }
  }

#pragma unroll
  for (int m = 0; m < 4; ++m) {
    const int jb = j0 + wm * 64 + m * 16 + (lane >> 4) * 4;
    const float4 bv = *(const float4*)(kv_b + jb);
#pragma unroll
    for (int n = 0; n < 4; ++n) {
      const int pos = pos0 + wn * 64 + n * 16 + (lane & 15);
      const f32x4 a = acc[m][n];
      ushort4 st;
      st.x = f2bfbits(a[0] + bv.x); st.y = f2bfbits(a[1] + bv.y);
      st.z = f2bfbits(a[2] + bv.z); st.w = f2bfbits(a[3] + bv.w);
      *(ushort4*)(kvout + ((size_t)b * NPOS + pos) * 512 + jb) = st;
    }
  }
}

// ---------------- agent attention v4: 8 waves x 2 agents, d-split across lane halves ----------------
// grid (NCHUNK, b*h, src), block 512. Lane: posIdx=lane&31, half=lane>>5 (d 16*half..16*half+15).
// Registers: ag[2][16] + acc[2][16] = 64 VGPR -> no spill at 128 cap.
__global__ __launch_bounds__(512) void k_agent_attn(const u16* __restrict__ kv1, const u16* __restrict__ kv2,
                                                    const float* __restrict__ agent_buf,
                                                    const float* __restrict__ pos_bias,
                                                    float* __restrict__ pav) {
  const int chunk = blockIdx.x;
  const int bh = blockIdx.y;
  const int src = blockIdx.z;
  const int b = bh >> 3, h = bh & 7;
  const u16* kv = src ? kv2 : kv1;

  __shared__ uint4 Kt[4 * 256];  // [slot s][pos p]
  __shared__ uint4 Vt[4 * 256];

  const int t = threadIdx.x;
  const int wave = t >> 6, lane = t & 63;
  const int a0 = wave * 2;
  const int pI = lane & 31;
  const int half = lane >> 5;

  float ag[2][16];
  {
    const float* agp = agent_buf + (((size_t)b * NH + h) * NA + a0) * HD + half * 16;
#pragma unroll
    for (int a = 0; a < 2; ++a)
#pragma unroll
      for (int d = 0; d < 16; ++d) ag[a][d] = agp[a * HD + d] * SCALE;
  }

  const size_t rowbase = (size_t)b * NPOS * 512 + h * HD;
  const float* pb0 = pos_bias + ((size_t)h * NA + a0) * NPOS;
  const float* pb1 = pb0 + NPOS;

  float acc[2][16] = {};
  float lsum[2] = {0.f, 0.f};

  // staging: tile = 256 pos x 4 slots (uint4) for K and V; 512 thr x 2 each
  const int sp = t >> 2, ss = t & 3;  // i=0: p=t>>2; i=1: p=128+(t>>2)
  const int pos0 = chunk * (NPOS / NCHUNK);

  uint4 rk[2], rv[2];
#pragma unroll
  for (int i = 0; i < 2; ++i) {
    const u16* gp = kv + rowbase + (size_t)(pos0 + sp + 128 * i) * 512 + ss * 8;
    rk[i] = *(const uint4*)gp;
    rv[i] = *(const uint4*)(gp + 256);
  }

  const int NT = (NPOS / NCHUNK) / 256;
  for (int tile = 0; tile < NT; ++tile) {
    __syncthreads();
#pragma unroll
    for (int i = 0; i < 2; ++i) {
      Kt[ss * 256 + sp + 128 * i] = rk[i];
      Vt[ss * 256 + sp + 128 * i] = rv[i];
    }
    __syncthreads();
    if (tile < NT - 1) {
      const int nb = pos0 + (tile + 1) * 256;
#pragma unroll
      for (int i = 0; i < 2; ++i) {
        const u16* gp = kv + rowbase + (size_t)(nb + sp + 128 * i) * 512 + ss * 8;
        rk[i] = *(const uint4*)gp;
        rv[i] = *(const uint4*)(gp + 256);
      }
    }
    const int gbase = pos0 + tile * 256;
#pragma unroll
    for (int j = 0; j < 8; ++j) {
      const int p = j * 32 + pI;
      float f8[8];
      // QK partial over this lane's 16 dims
      float part0 = 0.f, part1 = 0.f;
      unpack8(Kt[(2 * half) * 256 + p], f8);
#pragma unroll
      for (int e = 0; e < 8; ++e) { part0 += ag[0][e] * f8[e]; part1 += ag[1][e] * f8[e]; }
      unpack8(Kt[(2 * half + 1) * 256 + p], f8);
#pragma unroll
      for (int e = 0; e < 8; ++e) { part0 += ag[0][8 + e] * f8[e]; part1 += ag[1][8 + e] * f8[e]; }
      part0 += __shfl_xor(part0, 32);
      part1 += __shfl_xor(part1, 32);
      const float e0 = __expf(part0 + pb0[gbase + p]);
      const float e1 = __expf(part1 + pb1[gbase + p]);
      lsum[0] += e0;
      lsum[1] += e1;
      // PV on this lane's 16 dims
      unpack8(Vt[(2 * half) * 256 + p], f8);
#pragma unroll
      for (int e = 0; e < 8; ++e) { acc[0][e] += e0 * f8[e]; acc[1][e] += e1 * f8[e]; }
      unpack8(Vt[(2 * half + 1) * 256 + p], f8);
#pragma unroll
      for (int e = 0; e < 8; ++e) { acc[0][8 + e] += e0 * f8[e]; acc[1][8 + e] += e1 * f8[e]; }
    }
  }

  // reduce within 32-lane half-group
#pragma unroll
  for (int a = 0; a < 2; ++a) {
    float l = lsum[a];
#pragma unroll
    for (int off = 16; off; off >>= 1) l += __shfl_xor(l, off);
    lsum[a] = l;
#pragma unroll
    for (int d = 0; d < 16; ++d) {
      float v = acc[a][d];
#pragma unroll
      for (int off = 16; off; off >>= 1) v += __shfl_xor(v, off);
      acc[a][d] = v;
    }
  }
  if (pI == 0) {
    float* outp = pav + (((((size_t)src * B_ + b) * NH + h) * NCHUNK + chunk) * NA + a0) * 33;
#pragma unroll
    for (int a = 0; a < 2; ++a) {
#pragma unroll
      for (int d = 0; d < 16; ++d) outp[a * 33 + half * 16 + d] = acc[a][d];
      if (half == 0) outp[a * 33 + 32] = lsum[a];
    }
  }
}

// ---------------- query attention over 16 agents, bf16 outputs ----------------
__global__ __launch_bounds__(256) void k_qattn(const float* __restrict__ g,
                                               const float* __restrict__ q_w, const float* __restrict__ q_b,
                                               const float* __restrict__ agent_buf,
                                               const float* __restrict__ pav,
                                               const float* __restrict__ agent_bias,
                                               u16* __restrict__ o1s, u16* __restrict__ o2s) {
  const int h = blockIdx.y, b = blockIdx.z;
  const int t = threadIdx.x;
  const int pos = blockIdx.x * 256 + t;
  __shared__ float dotW[16], dotB[16];
  __shared__ float av1[16][32], av2[16][32];
  for (int idx = t; idx < 512; idx += 256) {
    const int a = idx >> 5, d = idx & 31;
    float s1 = 0.f, l1 = 0.f, s2 = 0.f, l2 = 0.f;
#pragma unroll
    for (int ch = 0; ch < NCHUNK; ++ch) {
      const float* p1 = pav + (((((size_t)0 * B_ + b) * NH + h) * NCHUNK + ch) * NA + a) * 33;
      const float* p2 = pav + (((((size_t)1 * B_ + b) * NH + h) * NCHUNK + ch) * NA + a) * 33;
      s1 += p1[d]; l1 += p1[32];
      s2 += p2[d]; l2 += p2[32];
    }
    av1[a][d] = s1 / l1;
    av2[a][d] = s2 / l2;
  }
  if (t < 16) {
    float dw = 0.f, db = 0.f;
    const float* agp = agent_buf + (((size_t)b * NH + h) * NA + t) * HD;
#pragma unroll
    for (int d = 0; d < HD; ++d) {
      const float ad = agp[d];
      dw += ad * q_w[h * HD + d];
      db += ad * q_b[h * HD + d];
    }
    dotW[t] = dw * SCALE;
    dotB[t] = db * SCALE;
  }
  __syncthreads();
  const float gv = g[(size_t)b * NPOS + pos];
  const float* abp = agent_bias + ((size_t)h * NPOS + pos) * NA;
  float s[16];
  float m = -1e30f;
#pragma unroll
  for (int a = 0; a < 16; ++a) {
    s[a] = gv * dotW[a] + dotB[a] + abp[a];
    m = fmaxf(m, s[a]);
  }
  float l = 0.f;
#pragma unroll
  for (int a = 0; a < 16; ++a) {
    s[a] = __expf(s[a] - m);
    l += s[a];
  }
  const float inv = 1.0f / l;
  float o1[32] = {}, o2[32] = {};
#pragma unroll
  for (int a = 0; a < 16; ++a) {
    const float pa = s[a] * inv;
#pragma unroll
    for (int d = 0; d < 32; ++d) {
      o1[d] += pa * av1[a][d];
      o2[d] += pa * av2[a][d];
    }
  }
  u16* o1p = o1s + ((size_t)b * NPOS + pos) * C_ + h * HD;
  u16* o2p = o2s + ((size_t)b * NPOS + pos) * C_ + h * HD;
#pragma unroll
  for (int blk = 0; blk < 4; ++blk) {
    unsigned int w1[4], w2[4];
#pragma unroll
    for (int q = 0; q < 4; ++q) {
      w1[q] = (unsigned int)f2bfbits(o1[blk * 8 + 2 * q]) | ((unsigned int)f2bfbits(o1[blk * 8 + 2 * q + 1]) << 16);
      w2[q] = (unsigned int)f2bfbits(o2[blk * 8 + 2 * q]) | ((unsigned int)f2bfbits(o2[blk * 8 + 2 * q + 1]) << 16);
    }
    *(uint4*)(o1p + blk * 8) = make_uint4(w1[0], w1[1], w1[2], w1[3]);
    *(uint4*)(o2p + blk * 8) = make_uint4(w2[0], w2[1], w2[2], w2[3]);
  }
}

// ---------------- depthwise 3x3 conv (bf16 V, bf16 RMW output) ----------------
__global__ __launch_bounds__(256) void k_dwconv(const u16* __restrict__ kv1, const u16* __restrict__ kv2,
                                                const float* __restrict__ dwc_w, const float* __restrict__ dwc_b,
                                                u16* __restrict__ o1s, u16* __restrict__ o2s) {
  const u16* kv = blockIdx.z ? kv2 : kv1;
  u16* out = blockIdx.z ? o2s : o1s;
  const int b = blockIdx.y;
  const int ci = threadIdx.x;
  const int pos0 = blockIdx.x << 3;
  float w[9];
#pragma unroll
  for (int q = 0; q < 9; ++q) w[q] = dwc_w[ci * 9 + q];
  const float bias = dwc_b[ci];
  const u16* vb = kv + (size_t)b * NPOS * 512 + 256 + ci;
  for (int pp = 0; pp < 8; ++pp) {
    const int pos = pos0 + pp;
    const int y = pos >> 6, x = pos & 63;
    float acc = bias;
#pragma unroll
    for (int dy = -1; dy <= 1; ++dy) {
      const int yy = y + dy;
      if (yy < 0 || yy > 63) continue;
#pragma unroll
      for (int dx = -1; dx <= 1; ++dx) {
        const int xx = x + dx;
        if (xx < 0 || xx > 63) continue;
        acc += w[(dy + 1) * 3 + (dx + 1)] * bfbits2f(vb[(size_t)(yy * 64 + xx) * 512]);
      }
    }
    const size_t oidx = ((size_t)b * NPOS + pos) * C_ + ci;
    out[oidx] = f2bfbits(bfbits2f(out[oidx]) + acc);
  }
}

// ---------------- output projection, bf16 MFMA -> (b,c,n) f32 + bias + residual ----------------
__global__ __launch_bounds__(256) void k_proj_mfma(const u16* __restrict__ o1s, const u16* __restrict__ o2s,
                                                   const u16* __restrict__ Pwt, const float* __restrict__ proj_b,
                                                   const float* __restrict__ in1, const float* __restrict__ in2,
                                                   float* __restrict__ out1, float* __restrict__ out2) {
  const int z = blockIdx.z;
  const int src = z >> 3, b = z & 7;
  const u16* S = src ? o2s : o1s;
  const float* inp = src ? in2 : in1;
  float* outp = src ? out2 : out1;
  const int pos0 = blockIdx.x * 128;
  const int co0 = blockIdx.y * 128;

  __shared__ u16 Abuf[2][128 * 64];
  __shared__ u16 Bbuf[2][128 * 64];

  const int t = threadIdx.x;
  const int wave = t >> 6, lane = t & 63;
  const int wm = wave >> 1, wn = wave & 1;

  const u16* Ag = S + ((size_t)b * NPOS + pos0) * C_;
  const u16* Bg = Pwt + (size_t)co0 * C_;

  f32x4 acc[4][4];
#pragma unroll
  for (int m = 0; m < 4; ++m)
#pragma unroll
    for (int n = 0; n < 4; ++n) { acc[m][n][0] = 0.f; acc[m][n][1] = 0.f; acc[m][n][2] = 0.f; acc[m][n][3] = 0.f; }

  uint4 ra[4], rb[4];
#pragma unroll
  for (int i = 0; i < 4; ++i) {
    const int u = t + 256 * i, r = u >> 3, s = u & 7;
    ra[i] = *(const uint4*)(Ag + (size_t)r * C_ + s * 8);
    rb[i] = *(const uint4*)(Bg + (size_t)r * C_ + s * 8);
  }

  for (int kt = 0; kt < 4; ++kt) {
    u16* Ab = Abuf[kt & 1];
    u16* Bb = Bbuf[kt & 1];
#pragma unroll
    for (int i = 0; i < 4; ++i) {
      const int u = t + 256 * i, r = u >> 3, s = u & 7;
      const int sw = (s ^ (r & 7)) << 3;
      *(uint4*)(Ab + r * 64 + sw) = ra[i];
      *(uint4*)(Bb + r * 64 + sw) = rb[i];
    }
    if (kt < 3) {
      const int k0 = (kt + 1) * 64;
#pragma unroll
      for (int i = 0; i < 4; ++i) {
        const int u = t + 256 * i, r = u >> 3, s = u & 7;
        ra[i] = *(const uint4*)(Ag + (size_t)r * C_ + k0 + s * 8);
        rb[i] = *(const uint4*)(Bg + (size_t)r * C_ + k0 + s * 8);
      }
    }
    __syncthreads();
#pragma unroll
    for (int kk = 0; kk < 2; ++kk) {
      bf16x8 af[4], bfr[4];
      const int g = lane >> 4;
#pragma unroll
      for (int m = 0; m < 4; ++m) {
        const int r = wm * 64 + m * 16 + (lane & 15);
        const int slot = (kk * 4 + g) ^ (r & 7);
        af[m] = *(const bf16x8*)(Ab + r * 64 + slot * 8);
      }
#pragma unroll
      for (int n = 0; n < 4; ++n) {
        const int c = wn * 64 + n * 16 + (lane & 15);
        const int slot = (kk * 4 + g) ^ (c & 7);
        bfr[n] = *(const bf16x8*)(Bb + c * 64 + slot * 8);
      }
#pragma unroll
      for (int m = 0; m < 4; ++m)
#pragma unroll
        for (int n = 0; n < 4; ++n)
          acc[m][n] = __builtin_amdgcn_mfma_f32_16x16x32_bf16(af[m], bfr[n], acc[m][n], 0, 0, 0);
    }
  }

#pragma unroll
  for (int m = 0; m < 4; ++m) {
    const int posb = pos0 + wm * 64 + m * 16 + (lane >> 4) * 4;
#pragma unroll
    for (int n = 0; n < 4; ++n) {
      const int co = co0 + wn * 64 + n * 16 + (lane & 15);
      const float pb = proj_b[co];
      const size_t base = ((size_t)b * C_ + co) * NPOS + posb;
      const float4 res = *(const float4*)(inp + base);
      const f32x4 a = acc[m][n];
      *(float4*)(outp + base) = make_float4(a[0] + pb + res.x, a[1] + pb + res.y,
                                            a[2] + pb + res.z, a[3] + pb + res.w);
    }
  }
}

extern "C" void kernel_launch(void* const* d_in, const int* in_sizes, int n_in,
                              void* d_out, int out_size, void* d_ws, size_t ws_size,
                              hipStream_t stream) {
  const float* input1 = (const float*)d_in[0];
  const float* input2 = (const float*)d_in[1];
  const float* guid   = (const float*)d_in[2];
  const float* kv_w   = (const float*)d_in[3];
  const float* kv_b   = (const float*)d_in[4];
  const float* q_w    = (const float*)d_in[5];
  const float* q_b    = (const float*)d_in[6];
  const float* proj_w = (const float*)d_in[7];
  const float* proj_b = (const float*)d_in[8];
  const float* dwc_w  = (const float*)d_in[9];
  const float* dwc_b  = (const float*)d_in[10];
  const float* an_b   = (const float*)d_in[11];
  const float* na_b   = (const float*)d_in[12];
  const float* ah_b   = (const float*)d_in[13];
  const float* aw_b   = (const float*)d_in[14];
  const float* ha_b   = (const float*)d_in[15];
  const float* wa_b   = (const float*)d_in[16];

  char* W = (char*)d_ws;
  u16* At1 = (u16*)W;            W += (size_t)B_ * NPOS * C_ * 2;
  u16* At2 = (u16*)W;            W += (size_t)B_ * NPOS * C_ * 2;
  u16* kv1 = (u16*)W;            W += (size_t)B_ * NPOS * 512 * 2;
  u16* kv2 = (u16*)W;            W += (size_t)B_ * NPOS * 512 * 2;
  u16* o1s = (u16*)W;            W += (size_t)B_ * NPOS * C_ * 2;
  u16* o2s = (u16*)W;            W += (size_t)B_ * NPOS * C_ * 2;
  u16* Wkt = (u16*)W;            W += (size_t)512 * C_ * 2;
  u16* Pwt = (u16*)W;            W += (size_t)C_ * C_ * 2;
  float* posb = (float*)W;       W += (size_t)NH * NA * NPOS * 4;
  float* agb  = (float*)W;       W += (size_t)NH * NPOS * NA * 4;
  float* agentb = (float*)W;     W += (size_t)B_ * NH * NA * HD * 4;
  float* pav    = (float*)W;     W += (size_t)2 * B_ * NH * NCHUNK * NA * 33 * 4;

  float* out1 = (float*)d_out;
  float* out2 = out1 + (size_t)B_ * C_ * NPOS;

  hipLaunchKernelGGL(k_agent, dim3(B_), dim3(256), 0, stream, guid, q_w, q_b, agentb);
  hipLaunchKernelGGL(k_bias, dim3((NH * NA * NPOS) / 256), dim3(256), 0, stream,
                     an_b, na_b, ah_b, aw_b, ha_b, wa_b, posb, agb);
  hipLaunchKernelGGL(k_prep_w, dim3(48), dim3(256), 0, stream, kv_w, proj_w, Wkt, Pwt);
  hipLaunchKernelGGL(k_prep_in, dim3(64, 4, 16), dim3(256), 0, stream, input1, input2, At1, At2);
  hipLaunchKernelGGL(k_kv_mfma, dim3(32, 4, 16), dim3(256), 0, stream,
                     At1, At2, Wkt, kv_b, kv1, kv2);
  hipLaunchKernelGGL(k_agent_attn, dim3(NCHUNK, B_ * NH, 2), dim3(512), 0, stream,
                     kv1, kv2, agentb, posb, pav);
  hipLaunchKernelGGL(k_qattn, dim3(NPOS / 256, NH, B_), dim3(256), 0, stream,
                     guid, q_w, q_b, agentb, pav, agb, o1s, o2s);
  hipLaunchKernelGGL(k_dwconv, dim3(NPOS / 8, B_, 2), dim3(256), 0, stream,
                     kv1, kv2, dwc_w, dwc_b, o1s, o2s);
  hipLaunchKernelGGL(k_proj_mfma, dim3(32, 2, 16), dim3(256), 0, stream,
                     o1s, o2s, Pwt, proj_b, input1, input2, out1, out2);
}

// Round 6
// 304.354 us; speedup vs baseline: 2.3251x; 1.0145x over previous
//
#include <hip/hip_runtime.h>
#include <hip/hip_bf16.h>
#include <cstddef>

#define B_   8
#define C_   256
#define HH   64
#define WW   64
#define NPOS 4096
#define NH   8
#define HD   32
#define NA   16
#define NCHUNK 2
#define SCALE 0.17677669529663687f

typedef unsigned short u16;
typedef __attribute__((ext_vector_type(8))) short bf16x8;
typedef __attribute__((ext_vector_type(4))) float f32x4;

__device__ __forceinline__ float bfbits2f(u16 u) {
  union { unsigned int i; float f; } x; x.i = ((unsigned int)u) << 16; return x.f;
}
__device__ __forceinline__ u16 f2bfbits(float f) {
  union { float f; unsigned int i; } x; x.f = f;
  unsigned int r = x.i + 0x7fffu + ((x.i >> 16) & 1u);
  return (u16)(r >> 16);
}
__device__ __forceinline__ void unpack8(const uint4 v, float* f) {
  f[0] = bfbits2f((u16)(v.x & 0xffff)); f[1] = bfbits2f((u16)(v.x >> 16));
  f[2] = bfbits2f((u16)(v.y & 0xffff)); f[3] = bfbits2f((u16)(v.y >> 16));
  f[4] = bfbits2f((u16)(v.z & 0xffff)); f[5] = bfbits2f((u16)(v.z >> 16));
  f[6] = bfbits2f((u16)(v.w & 0xffff)); f[7] = bfbits2f((u16)(v.w >> 16));
}

// ---------------- agent pooling + agent vectors ----------------
__global__ __launch_bounds__(256) void k_agent(const float* __restrict__ g,
                                               const float* __restrict__ q_w,
                                               const float* __restrict__ q_b,
                                               float* __restrict__ agent_buf) {
  const int b = blockIdx.x;
  const int t = threadIdx.x;
  __shared__ float red[256];
  __shared__ float gb[16];
  const int ag = t >> 4, sub = t & 15;
  const int p1 = ag >> 2, p2 = ag & 3;
  const int y = p1 * 16 + sub, x0 = p2 * 16;
  const float* gp = g + (size_t)b * NPOS + y * WW + x0;
  float s = 0.f;
#pragma unroll
  for (int i = 0; i < 16; ++i) s += gp[i];
  red[t] = s;
  __syncthreads();
  if (sub == 0) {
    float tot = 0.f;
    for (int i = 0; i < 16; ++i) tot += red[(ag << 4) + i];
    gb[ag] = tot * (1.0f / 256.0f);
  }
  __syncthreads();
  for (int idx = t; idx < NA * C_; idx += 256) {
    const int a = idx >> 8, ci = idx & 255;
    const int h = ci >> 5, d = ci & 31;
    agent_buf[(((size_t)b * NH + h) * NA + a) * HD + d] = gb[a] * q_w[ci] + q_b[ci];
  }
}

// ---------------- position / agent biases ----------------
__global__ __launch_bounds__(256) void k_bias(const float* __restrict__ an_b, const float* __restrict__ na_b,
                                              const float* __restrict__ ah_b, const float* __restrict__ aw_b,
                                              const float* __restrict__ ha_b, const float* __restrict__ wa_b,
                                              float* __restrict__ posb, float* __restrict__ agb) {
  const int idx = blockIdx.x * 256 + threadIdx.x;
  const int pos = idx & (NPOS - 1);
  const int ha_i = idx >> 12;
  const int h = ha_i >> 4, a = ha_i & 15;
  const int y = pos >> 6, x = pos & 63;
  const float sy = (y + 0.5f) * 0.0625f - 0.5f;
  const float sx = (x + 0.5f) * 0.0625f - 0.5f;
  const int y0 = (int)floorf(sy);
  const int x0 = (int)floorf(sx);
  const float wy = sy - (float)y0, wx = sx - (float)x0;
  const int y0c = min(max(y0, 0), 3), y1c = min(max(y0 + 1, 0), 3);
  const int x0c = min(max(x0, 0), 3), x1c = min(max(x0 + 1, 0), 3);
  const float* an4 = an_b + ((size_t)h * NA + a) * 16;
  const float* na4 = na_b + ((size_t)h * NA + a) * 16;
  const float pa_ = (1.f - wy) * ((1.f - wx) * an4[y0c * 4 + x0c] + wx * an4[y0c * 4 + x1c]) +
                    wy * ((1.f - wx) * an4[y1c * 4 + x0c] + wx * an4[y1c * 4 + x1c]);
  const float nv_ = (1.f - wy) * ((1.f - wx) * na4[y0c * 4 + x0c] + wx * na4[y0c * 4 + x1c]) +
                    wy * ((1.f - wx) * na4[y1c * 4 + x0c] + wx * na4[y1c * 4 + x1c]);
  posb[idx] = pa_ + ah_b[((size_t)h * NA + a) * HH + y] + aw_b[((size_t)h * NA + a) * WW + x];
  agb[((size_t)h * NPOS + pos) * NA + a] =
      nv_ + ha_b[((size_t)h * HH + y) * NA + a] + wa_b[((size_t)h * WW + x) * NA + a];
}

// ---------------- transpose+convert inputs: in (b,c,n) f32 -> At (b,n,c) bf16 ----------------
__global__ __launch_bounds__(256) void k_prep_in(const float* __restrict__ in1, const float* __restrict__ in2,
                                                 u16* __restrict__ At1, u16* __restrict__ At2) {
  const int z = blockIdx.z;
  const int src = z >> 3, b = z & 7;
  const float* in = src ? in2 : in1;
  u16* At = src ? At2 : At1;
  const int pos0 = blockIdx.x * 64;
  const int ci0 = blockIdx.y * 64;
  __shared__ float tile[64][68];
  const int t = threadIdx.x;
  const int rpos = (t & 15) << 2, rci = t >> 4;
#pragma unroll
  for (int i = 0; i < 4; ++i) {
    const int ci_l = rci + 16 * i;
    const float4 v = *(const float4*)(in + ((size_t)b * C_ + ci0 + ci_l) * NPOS + pos0 + rpos);
    tile[ci_l][rpos + 0] = v.x; tile[ci_l][rpos + 1] = v.y;
    tile[ci_l][rpos + 2] = v.z; tile[ci_l][rpos + 3] = v.w;
  }
  __syncthreads();
#pragma unroll
  for (int i = 0; i < 2; ++i) {
    const int u = t + 256 * i;
    const int p = u >> 3, s = u & 7;
    unsigned int w[4];
#pragma unroll
    for (int q = 0; q < 4; ++q) {
      const u16 lo = f2bfbits(tile[s * 8 + 2 * q][p]);
      const u16 hi = f2bfbits(tile[s * 8 + 2 * q + 1][p]);
      w[q] = (unsigned int)lo | ((unsigned int)hi << 16);
    }
    uint4 pk = make_uint4(w[0], w[1], w[2], w[3]);
    *(uint4*)(At + ((size_t)(pos0 + p)) * C_ + (size_t)b * NPOS * C_ + ci0 + s * 8) = pk;
  }
}

// ---------------- transpose+convert weights ----------------
__global__ __launch_bounds__(256) void k_prep_w(const float* __restrict__ kv_w, const float* __restrict__ proj_w,
                                                u16* __restrict__ Wkt, u16* __restrict__ Pwt) {
  const int x = blockIdx.x;
  const float* W; u16* T; int j0, ci0, ncols;
  if (x < 32) { W = kv_w;  T = Wkt; j0 = (x & 7) * 64; ci0 = (x >> 3) * 64; ncols = 512; }
  else        { W = proj_w; T = Pwt; j0 = ((x - 32) & 3) * 64; ci0 = ((x - 32) >> 2) * 64; ncols = 256; }
  __shared__ float tile[64][68];
  const int t = threadIdx.x;
  const int rj = (t & 15) << 2, rci = t >> 4;
#pragma unroll
  for (int i = 0; i < 4; ++i) {
    const int ci_l = rci + 16 * i;
    const float4 v = *(const float4*)(W + (size_t)(ci0 + ci_l) * ncols + j0 + rj);
    tile[ci_l][rj + 0] = v.x; tile[ci_l][rj + 1] = v.y;
    tile[ci_l][rj + 2] = v.z; tile[ci_l][rj + 3] = v.w;
  }
  __syncthreads();
#pragma unroll
  for (int i = 0; i < 2; ++i) {
    const int u = t + 256 * i;
    const int p = u >> 3, s = u & 7;
    unsigned int w[4];
#pragma unroll
    for (int q = 0; q < 4; ++q) {
      const u16 lo = f2bfbits(tile[s * 8 + 2 * q][p]);
      const u16 hi = f2bfbits(tile[s * 8 + 2 * q + 1][p]);
      w[q] = (unsigned int)lo | ((unsigned int)hi << 16);
    }
    *(uint4*)(T + (size_t)(j0 + p) * C_ + ci0 + s * 8) = make_uint4(w[0], w[1], w[2], w[3]);
  }
}

// ---------------- kv projection, bf16 MFMA v2: single 32KB LDS, repack epilogue ----------------
// D[j,pos]: A=Wkt rows j (128), B=At rows pos (128), K=256, BK=64 x4.
__global__ __launch_bounds__(256) void k_kv_mfma(const u16* __restrict__ At1, const u16* __restrict__ At2,
                                                 const u16* __restrict__ Wkt, const float* __restrict__ kv_b,
                                                 u16* __restrict__ kv1, u16* __restrict__ kv2) {
  const int z = blockIdx.z;
  const int src = z >> 3, b = z & 7;
  const u16* At = src ? At2 : At1;
  u16* kvout = src ? kv2 : kv1;
  const int pos0 = blockIdx.x * 128;
  const int j0 = blockIdx.y * 128;

  __shared__ __align__(16) u16 SM[16384];  // 32KB: A[0..8191], B[8192..16383]
  u16* Ab = SM;
  u16* Bb = SM + 8192;

  const int t = threadIdx.x;
  const int wave = t >> 6, lane = t & 63;
  const int wm = wave >> 1, wn = wave & 1;
  const int g = lane >> 4;

  const u16* Ag = Wkt + (size_t)j0 * C_;
  const u16* Bg = At + ((size_t)b * NPOS + pos0) * C_;

  f32x4 acc[4][4];
#pragma unroll
  for (int m = 0; m < 4; ++m)
#pragma unroll
    for (int n = 0; n < 4; ++n) { acc[m][n][0] = 0.f; acc[m][n][1] = 0.f; acc[m][n][2] = 0.f; acc[m][n][3] = 0.f; }

  uint4 ra[4], rb[4];
#define KV_LOAD(KT)                                                        \
  _Pragma("unroll") for (int i = 0; i < 4; ++i) {                          \
    const int u = t + 256 * i, rr = u >> 3, ss = u & 7;                    \
    ra[i] = *(const uint4*)(Ag + (size_t)rr * C_ + (KT) * 64 + ss * 8);    \
    rb[i] = *(const uint4*)(Bg + (size_t)rr * C_ + (KT) * 64 + ss * 8);    \
  }
#define KV_WRITE()                                                         \
  _Pragma("unroll") for (int i = 0; i < 4; ++i) {                          \
    const int u = t + 256 * i, rr = u >> 3, ss = u & 7;                    \
    const int sw = ((ss ^ (rr & 7)) << 3);                                 \
    *(uint4*)(Ab + rr * 64 + sw) = ra[i];                                  \
    *(uint4*)(Bb + rr * 64 + sw) = rb[i];                                  \
  }

  KV_LOAD(0);
  KV_WRITE();
  KV_LOAD(1);
  __syncthreads();

  for (int kt = 0; kt < 4; ++kt) {
#pragma unroll
    for (int kk = 0; kk < 2; ++kk) {
      bf16x8 af[4], bfr[4];
#pragma unroll
      for (int m = 0; m < 4; ++m) {
        const int r = wm * 64 + m * 16 + (lane & 15);
        const int slot = (kk * 4 + g) ^ (r & 7);
        af[m] = *(const bf16x8*)(Ab + r * 64 + slot * 8);
      }
#pragma unroll
      for (int n = 0; n < 4; ++n) {
        const int c = wn * 64 + n * 16 + (lane & 15);
        const int slot = (kk * 4 + g) ^ (c & 7);
        bfr[n] = *(const bf16x8*)(Bb + c * 64 + slot * 8);
      }
#pragma unroll
      for (int m = 0; m < 4; ++m)
#pragma unroll
        for (int n = 0; n < 4; ++n)
          acc[m][n] = __builtin_amdgcn_mfma_f32_16x16x32_bf16(af[m], bfr[n], acc[m][n], 0, 0, 0);
    }
    if (kt < 3) {
      __syncthreads();
      KV_WRITE();
      if (kt < 2) KV_LOAD(kt + 2);
      __syncthreads();
    }
  }
#undef KV_LOAD
#undef KV_WRITE

  // repack tile [pos 0..127][j 0..127] bf16 into SM (32KB), bias folded
  __syncthreads();
#pragma unroll
  for (int m = 0; m < 4; ++m) {
    const int jl = wm * 64 + m * 16 + (lane >> 4) * 4;
    const float4 bv = *(const float4*)(kv_b + j0 + jl);
#pragma unroll
    for (int n = 0; n < 4; ++n) {
      const int pos_l = wn * 64 + n * 16 + (lane & 15);
      const f32x4 a = acc[m][n];
      ushort4 st;
      st.x = f2bfbits(a[0] + bv.x); st.y = f2bfbits(a[1] + bv.y);
      st.z = f2bfbits(a[2] + bv.z); st.w = f2bfbits(a[3] + bv.w);
      const int slot = (jl >> 3) ^ (pos_l & 7);           // 16 slots of 16B per row
      *(ushort4*)(SM + pos_l * 128 + slot * 8 + (jl & 7)) = st;
    }
  }
  __syncthreads();
  // coalesced store: 128 rows x 16 uint4
#pragma unroll
  for (int i = 0; i < 8; ++i) {
    const int idx = t + 256 * i;
    const int row = idx >> 4, sl = idx & 15;
    const uint4 v = *(const uint4*)(SM + row * 128 + ((sl ^ (row & 7)) << 3));
    *(uint4*)(kvout + ((size_t)b * NPOS + pos0 + row) * 512 + j0 + sl * 8) = v;
  }
}

// ---------------- agent attention v4 (unchanged) ----------------
__global__ __launch_bounds__(512) void k_agent_attn(const u16* __restrict__ kv1, const u16* __restrict__ kv2,
                                                    const float* __restrict__ agent_buf,
                                                    const float* __restrict__ pos_bias,
                                                    float* __restrict__ pav) {
  const int chunk = blockIdx.x;
  const int bh = blockIdx.y;
  const int src = blockIdx.z;
  const int b = bh >> 3, h = bh & 7;
  const u16* kv = src ? kv2 : kv1;

  __shared__ uint4 Kt[4 * 256];
  __shared__ uint4 Vt[4 * 256];

  const int t = threadIdx.x;
  const int wave = t >> 6, lane = t & 63;
  const int a0 = wave * 2;
  const int pI = lane & 31;
  const int half = lane >> 5;

  float ag[2][16];
  {
    const float* agp = agent_buf + (((size_t)b * NH + h) * NA + a0) * HD + half * 16;
#pragma unroll
    for (int a = 0; a < 2; ++a)
#pragma unroll
      for (int d = 0; d < 16; ++d) ag[a][d] = agp[a * HD + d] * SCALE;
  }

  const size_t rowbase = (size_t)b * NPOS * 512 + h * HD;
  const float* pb0 = pos_bias + ((size_t)h * NA + a0) * NPOS;
  const float* pb1 = pb0 + NPOS;

  float acc[2][16] = {};
  float lsum[2] = {0.f, 0.f};

  const int sp = t >> 2, ss = t & 3;
  const int pos0 = chunk * (NPOS / NCHUNK);

  uint4 rk[2], rv[2];
#pragma unroll
  for (int i = 0; i < 2; ++i) {
    const u16* gp = kv + rowbase + (size_t)(pos0 + sp + 128 * i) * 512 + ss * 8;
    rk[i] = *(const uint4*)gp;
    rv[i] = *(const uint4*)(gp + 256);
  }

  const int NT = (NPOS / NCHUNK) / 256;
  for (int tile = 0; tile < NT; ++tile) {
    __syncthreads();
#pragma unroll
    for (int i = 0; i < 2; ++i) {
      Kt[ss * 256 + sp + 128 * i] = rk[i];
      Vt[ss * 256 + sp + 128 * i] = rv[i];
    }
    __syncthreads();
    if (tile < NT - 1) {
      const int nb = pos0 + (tile + 1) * 256;
#pragma unroll
      for (int i = 0; i < 2; ++i) {
        const u16* gp = kv + rowbase + (size_t)(nb + sp + 128 * i) * 512 + ss * 8;
        rk[i] = *(const uint4*)gp;
        rv[i] = *(const uint4*)(gp + 256);
      }
    }
    const int gbase = pos0 + tile * 256;
#pragma unroll
    for (int j = 0; j < 8; ++j) {
      const int p = j * 32 + pI;
      float f8[8];
      float part0 = 0.f, part1 = 0.f;
      unpack8(Kt[(2 * half) * 256 + p], f8);
#pragma unroll
      for (int e = 0; e < 8; ++e) { part0 += ag[0][e] * f8[e]; part1 += ag[1][e] * f8[e]; }
      unpack8(Kt[(2 * half + 1) * 256 + p], f8);
#pragma unroll
      for (int e = 0; e < 8; ++e) { part0 += ag[0][8 + e] * f8[e]; part1 += ag[1][8 + e] * f8[e]; }
      part0 += __shfl_xor(part0, 32);
      part1 += __shfl_xor(part1, 32);
      const float e0 = __expf(part0 + pb0[gbase + p]);
      const float e1 = __expf(part1 + pb1[gbase + p]);
      lsum[0] += e0;
      lsum[1] += e1;
      unpack8(Vt[(2 * half) * 256 + p], f8);
#pragma unroll
      for (int e = 0; e < 8; ++e) { acc[0][e] += e0 * f8[e]; acc[1][e] += e1 * f8[e]; }
      unpack8(Vt[(2 * half + 1) * 256 + p], f8);
#pragma unroll
      for (int e = 0; e < 8; ++e) { acc[0][8 + e] += e0 * f8[e]; acc[1][8 + e] += e1 * f8[e]; }
    }
  }

#pragma unroll
  for (int a = 0; a < 2; ++a) {
    float l = lsum[a];
#pragma unroll
    for (int off = 16; off; off >>= 1) l += __shfl_xor(l, off);
    lsum[a] = l;
#pragma unroll
    for (int d = 0; d < 16; ++d) {
      float v = acc[a][d];
#pragma unroll
      for (int off = 16; off; off >>= 1) v += __shfl_xor(v, off);
      acc[a][d] = v;
    }
  }
  if (pI == 0) {
    float* outp = pav + (((((size_t)src * B_ + b) * NH + h) * NCHUNK + chunk) * NA + a0) * 33;
#pragma unroll
    for (int a = 0; a < 2; ++a) {
#pragma unroll
      for (int d = 0; d < 16; ++d) outp[a * 33 + half * 16 + d] = acc[a][d];
      if (half == 0) outp[a * 33 + 32] = lsum[a];
    }
  }
}

// ---------------- query attention over 16 agents, bf16 outputs ----------------
__global__ __launch_bounds__(256) void k_qattn(const float* __restrict__ g,
                                               const float* __restrict__ q_w, const float* __restrict__ q_b,
                                               const float* __restrict__ agent_buf,
                                               const float* __restrict__ pav,
                                               const float* __restrict__ agent_bias,
                                               u16* __restrict__ o1s, u16* __restrict__ o2s) {
  const int h = blockIdx.y, b = blockIdx.z;
  const int t = threadIdx.x;
  const int pos = blockIdx.x * 256 + t;
  __shared__ float dotW[16], dotB[16];
  __shared__ float av1[16][32], av2[16][32];
  for (int idx = t; idx < 512; idx += 256) {
    const int a = idx >> 5, d = idx & 31;
    float s1 = 0.f, l1 = 0.f, s2 = 0.f, l2 = 0.f;
#pragma unroll
    for (int ch = 0; ch < NCHUNK; ++ch) {
      const float* p1 = pav + (((((size_t)0 * B_ + b) * NH + h) * NCHUNK + ch) * NA + a) * 33;
      const float* p2 = pav + (((((size_t)1 * B_ + b) * NH + h) * NCHUNK + ch) * NA + a) * 33;
      s1 += p1[d]; l1 += p1[32];
      s2 += p2[d]; l2 += p2[32];
    }
    av1[a][d] = s1 / l1;
    av2[a][d] = s2 / l2;
  }
  if (t < 16) {
    float dw = 0.f, db = 0.f;
    const float* agp = agent_buf + (((size_t)b * NH + h) * NA + t) * HD;
#pragma unroll
    for (int d = 0; d < HD; ++d) {
      const float ad = agp[d];
      dw += ad * q_w[h * HD + d];
      db += ad * q_b[h * HD + d];
    }
    dotW[t] = dw * SCALE;
    dotB[t] = db * SCALE;
  }
  __syncthreads();
  const float gv = g[(size_t)b * NPOS + pos];
  const float* abp = agent_bias + ((size_t)h * NPOS + pos) * NA;
  float s[16];
  float m = -1e30f;
#pragma unroll
  for (int a = 0; a < 16; ++a) {
    s[a] = gv * dotW[a] + dotB[a] + abp[a];
    m = fmaxf(m, s[a]);
  }
  float l = 0.f;
#pragma unroll
  for (int a = 0; a < 16; ++a) {
    s[a] = __expf(s[a] - m);
    l += s[a];
  }
  const float inv = 1.0f / l;
  float o1[32] = {}, o2[32] = {};
#pragma unroll
  for (int a = 0; a < 16; ++a) {
    const float pa = s[a] * inv;
#pragma unroll
    for (int d = 0; d < 32; ++d) {
      o1[d] += pa * av1[a][d];
      o2[d] += pa * av2[a][d];
    }
  }
  u16* o1p = o1s + ((size_t)b * NPOS + pos) * C_ + h * HD;
  u16* o2p = o2s + ((size_t)b * NPOS + pos) * C_ + h * HD;
#pragma unroll
  for (int blk = 0; blk < 4; ++blk) {
    unsigned int w1[4], w2[4];
#pragma unroll
    for (int q = 0; q < 4; ++q) {
      w1[q] = (unsigned int)f2bfbits(o1[blk * 8 + 2 * q]) | ((unsigned int)f2bfbits(o1[blk * 8 + 2 * q + 1]) << 16);
      w2[q] = (unsigned int)f2bfbits(o2[blk * 8 + 2 * q]) | ((unsigned int)f2bfbits(o2[blk * 8 + 2 * q + 1]) << 16);
    }
    *(uint4*)(o1p + blk * 8) = make_uint4(w1[0], w1[1], w1[2], w1[3]);
    *(uint4*)(o2p + blk * 8) = make_uint4(w2[0], w2[1], w2[2], w2[3]);
  }
}

// ---------------- depthwise 3x3 conv (bf16 V, bf16 RMW output) ----------------
__global__ __launch_bounds__(256) void k_dwconv(const u16* __restrict__ kv1, const u16* __restrict__ kv2,
                                                const float* __restrict__ dwc_w, const float* __restrict__ dwc_b,
                                                u16* __restrict__ o1s, u16* __restrict__ o2s) {
  const u16* kv = blockIdx.z ? kv2 : kv1;
  u16* out = blockIdx.z ? o2s : o1s;
  const int b = blockIdx.y;
  const int ci = threadIdx.x;
  const int pos0 = blockIdx.x << 3;
  float w[9];
#pragma unroll
  for (int q = 0; q < 9; ++q) w[q] = dwc_w[ci * 9 + q];
  const float bias = dwc_b[ci];
  const u16* vb = kv + (size_t)b * NPOS * 512 + 256 + ci;
  for (int pp = 0; pp < 8; ++pp) {
    const int pos = pos0 + pp;
    const int y = pos >> 6, x = pos & 63;
    float acc = bias;
#pragma unroll
    for (int dy = -1; dy <= 1; ++dy) {
      const int yy = y + dy;
      if (yy < 0 || yy > 63) continue;
#pragma unroll
      for (int dx = -1; dx <= 1; ++dx) {
        const int xx = x + dx;
        if (xx < 0 || xx > 63) continue;
        acc += w[(dy + 1) * 3 + (dx + 1)] * bfbits2f(vb[(size_t)(yy * 64 + xx) * 512]);
      }
    }
    const size_t oidx = ((size_t)b * NPOS + pos) * C_ + ci;
    out[oidx] = f2bfbits(bfbits2f(out[oidx]) + acc);
  }
}

// ---------------- output projection, bf16 MFMA v2: single 32KB LDS, repack epilogue ----------------
// D[pos,co]: A=S rows pos (128), B=Pwt rows co (128), K=256.
__global__ __launch_bounds__(256) void k_proj_mfma(const u16* __restrict__ o1s, const u16* __restrict__ o2s,
                                                   const u16* __restrict__ Pwt, const float* __restrict__ proj_b,
                                                   const float* __restrict__ in1, const float* __restrict__ in2,
                                                   float* __restrict__ out1, float* __restrict__ out2) {
  const int z = blockIdx.z;
  const int src = z >> 3, b = z & 7;
  const u16* S = src ? o2s : o1s;
  const float* inp = src ? in2 : in1;
  float* outp = src ? out2 : out1;
  const int pos0 = blockIdx.x * 128;
  const int co0 = blockIdx.y * 128;

  __shared__ __align__(16) u16 SM[16384];  // 32KB
  u16* Ab = SM;
  u16* Bb = SM + 8192;
  float* SMF = (float*)SM;                 // 8192 f32 for repack halves

  const int t = threadIdx.x;
  const int wave = t >> 6, lane = t & 63;
  const int wm = wave >> 1, wn = wave & 1;
  const int g = lane >> 4;

  const u16* Ag = S + ((size_t)b * NPOS + pos0) * C_;
  const u16* Bg = Pwt + (size_t)co0 * C_;

  f32x4 acc[4][4];
#pragma unroll
  for (int m = 0; m < 4; ++m)
#pragma unroll
    for (int n = 0; n < 4; ++n) { acc[m][n][0] = 0.f; acc[m][n][1] = 0.f; acc[m][n][2] = 0.f; acc[m][n][3] = 0.f; }

  uint4 ra[4], rb[4];
#define PJ_LOAD(KT)                                                        \
  _Pragma("unroll") for (int i = 0; i < 4; ++i) {                          \
    const int u = t + 256 * i, rr = u >> 3, ss = u & 7;                    \
    ra[i] = *(const uint4*)(Ag + (size_t)rr * C_ + (KT) * 64 + ss * 8);    \
    rb[i] = *(const uint4*)(Bg + (size_t)rr * C_ + (KT) * 64 + ss * 8);    \
  }
#define PJ_WRITE()                                                         \
  _Pragma("unroll") for (int i = 0; i < 4; ++i) {                          \
    const int u = t + 256 * i, rr = u >> 3, ss = u & 7;                    \
    const int sw = ((ss ^ (rr & 7)) << 3);                                 \
    *(uint4*)(Ab + rr * 64 + sw) = ra[i];                                  \
    *(uint4*)(Bb + rr * 64 + sw) = rb[i];                                  \
  }

  PJ_LOAD(0);
  PJ_WRITE();
  PJ_LOAD(1);
  __syncthreads();

  for (int kt = 0; kt < 4; ++kt) {
#pragma unroll
    for (int kk = 0; kk < 2; ++kk) {
      bf16x8 af[4], bfr[4];
#pragma unroll
      for (int m = 0; m < 4; ++m) {
        const int r = wm * 64 + m * 16 + (lane & 15);
        const int slot = (kk * 4 + g) ^ (r & 7);
        af[m] = *(const bf16x8*)(Ab + r * 64 + slot * 8);
      }
#pragma unroll
      for (int n = 0; n < 4; ++n) {
        const int c = wn * 64 + n * 16 + (lane & 15);
        const int slot = (kk * 4 + g) ^ (c & 7);
        bfr[n] = *(const bf16x8*)(Bb + c * 64 + slot * 8);
      }
#pragma unroll
      for (int m = 0; m < 4; ++m)
#pragma unroll
        for (int n = 0; n < 4; ++n)
          acc[m][n] = __builtin_amdgcn_mfma_f32_16x16x32_bf16(af[m], bfr[n], acc[m][n], 0, 0, 0);
    }
    if (kt < 3) {
      __syncthreads();
      PJ_WRITE();
      if (kt < 2) PJ_LOAD(kt + 2);
      __syncthreads();
    }
  }
#undef PJ_LOAD
#undef PJ_WRITE

  // two half-passes through 32KB LDS: [co 0..63][pos 0..127] f32 each
#pragma unroll
  for (int hf = 0; hf < 2; ++hf) {
    __syncthreads();
    if (wn == hf) {
#pragma unroll
      for (int n = 0; n < 4; ++n) {
        const int co_l = n * 16 + (lane & 15);            // 0..63 within half
#pragma unroll
        for (int m = 0; m < 4; ++m) {
          const int pos_l = wm * 64 + m * 16 + (lane >> 4) * 4;
          const int slot = (pos_l >> 2) ^ (co_l & 7);     // 32 slots of 16B per row
          const f32x4 a = acc[m][n];
          *(float4*)(SMF + co_l * 128 + slot * 4) = make_float4(a[0], a[1], a[2], a[3]);
        }
      }
    }
    __syncthreads();
    // coalesced store with bias + residual: 64 rows x 32 float4
#pragma unroll
    for (int i = 0; i < 8; ++i) {
      const int idx = t + 256 * i;
      const int row = idx >> 5, sl = idx & 31;
      const float4 v = *(const float4*)(SMF + row * 128 + ((sl ^ (row & 7)) << 2));
      const int co = co0 + hf * 64 + row;
      const float pb = proj_b[co];
      const size_t base = ((size_t)b * C_ + co) * NPOS + pos0 + sl * 4;
      const float4 res = *(const float4*)(inp + base);
      *(float4*)(outp + base) = make_float4(v.x + pb + res.x, v.y + pb + res.y,
                                            v.z + pb + res.z, v.w + pb + res.w);
    }
  }
}

extern "C" void kernel_launch(void* const* d_in, const int* in_sizes, int n_in,
                              void* d_out, int out_size, void* d_ws, size_t ws_size,
                              hipStream_t stream) {
  const float* input1 = (const float*)d_in[0];
  const float* input2 = (const float*)d_in[1];
  const float* guid   = (const float*)d_in[2];
  const float* kv_w   = (const float*)d_in[3];
  const float* kv_b   = (const float*)d_in[4];
  const float* q_w    = (const float*)d_in[5];
  const float* q_b    = (const float*)d_in[6];
  const float* proj_w = (const float*)d_in[7];
  const float* proj_b = (const float*)d_in[8];
  const float* dwc_w  = (const float*)d_in[9];
  const float* dwc_b  = (const float*)d_in[10];
  const float* an_b   = (const float*)d_in[11];
  const float* na_b   = (const float*)d_in[12];
  const float* ah_b   = (const float*)d_in[13];
  const float* aw_b   = (const float*)d_in[14];
  const float* ha_b   = (const float*)d_in[15];
  const float* wa_b   = (const float*)d_in[16];

  char* W = (char*)d_ws;
  u16* At1 = (u16*)W;            W += (size_t)B_ * NPOS * C_ * 2;
  u16* At2 = (u16*)W;            W += (size_t)B_ * NPOS * C_ * 2;
  u16* kv1 = (u16*)W;            W += (size_t)B_ * NPOS * 512 * 2;
  u16* kv2 = (u16*)W;            W += (size_t)B_ * NPOS * 512 * 2;
  u16* o1s = (u16*)W;            W += (size_t)B_ * NPOS * C_ * 2;
  u16* o2s = (u16*)W;            W += (size_t)B_ * NPOS * C_ * 2;
  u16* Wkt = (u16*)W;            W += (size_t)512 * C_ * 2;
  u16* Pwt = (u16*)W;            W += (size_t)C_ * C_ * 2;
  float* posb = (float*)W;       W += (size_t)NH * NA * NPOS * 4;
  float* agb  = (float*)W;       W += (size_t)NH * NPOS * NA * 4;
  float* agentb = (float*)W;     W += (size_t)B_ * NH * NA * HD * 4;
  float* pav    = (float*)W;     W += (size_t)2 * B_ * NH * NCHUNK * NA * 33 * 4;

  float* out1 = (float*)d_out;
  float* out2 = out1 + (size_t)B_ * C_ * NPOS;

  hipLaunchKernelGGL(k_agent, dim3(B_), dim3(256), 0, stream, guid, q_w, q_b, agentb);
  hipLaunchKernelGGL(k_bias, dim3((NH * NA * NPOS) / 256), dim3(256), 0, stream,
                     an_b, na_b, ah_b, aw_b, ha_b, wa_b, posb, agb);
  hipLaunchKernelGGL(k_prep_w, dim3(48), dim3(256), 0, stream, kv_w, proj_w, Wkt, Pwt);
  hipLaunchKernelGGL(k_prep_in, dim3(64, 4, 16), dim3(256), 0, stream, input1, input2, At1, At2);
  hipLaunchKernelGGL(k_kv_mfma, dim3(32, 4, 16), dim3(256), 0, stream,
                     At1, At2, Wkt, kv_b, kv1, kv2);
  hipLaunchKernelGGL(k_agent_attn, dim3(NCHUNK, B_ * NH, 2), dim3(512), 0, stream,
                     kv1, kv2, agentb, posb, pav);
  hipLaunchKernelGGL(k_qattn, dim3(NPOS / 256, NH, B_), dim3(256), 0, stream,
                     guid, q_w, q_b, agentb, pav, agb, o1s, o2s);
  hipLaunchKernelGGL(k_dwconv, dim3(NPOS / 8, B_, 2), dim3(256), 0, stream,
                     kv1, kv2, dwc_w, dwc_b, o1s, o2s);
  hipLaunchKernelGGL(k_proj_mfma, dim3(32, 2, 16), dim3(256), 0, stream,
                     o1s, o2s, Pwt, proj_b, input1, input2, out1, out2);
}

// Round 7
// 293.525 us; speedup vs baseline: 2.4109x; 1.0369x over previous
//
#include <hip/hip_runtime.h>
#include <hip/hip_bf16.h>
#include <cstddef>

#define B_   8
#define C_   256
#define HH   64
#define WW   64
#define NPOS 4096
#define NH   8
#define HD   32
#define NA   16
#define NHA  128      // NH*NA
#define SCALE 0.17677669529663687f

typedef unsigned short u16;
typedef __attribute__((ext_vector_type(8))) short bf16x8;
typedef __attribute__((ext_vector_type(4))) float f32x4;

__device__ __forceinline__ float bfbits2f(u16 u) {
  union { unsigned int i; float f; } x; x.i = ((unsigned int)u) << 16; return x.f;
}
__device__ __forceinline__ u16 f2bfbits(float f) {
  union { float f; unsigned int i; } x; x.f = f;
  unsigned int r = x.i + 0x7fffu + ((x.i >> 16) & 1u);
  return (u16)(r >> 16);
}

// ---------------- agent pooling + agent vectors ----------------
__global__ __launch_bounds__(256) void k_agent(const float* __restrict__ g,
                                               const float* __restrict__ q_w,
                                               const float* __restrict__ q_b,
                                               float* __restrict__ agent_buf) {
  const int b = blockIdx.x;
  const int t = threadIdx.x;
  __shared__ float red[256];
  __shared__ float gb[16];
  const int ag = t >> 4, sub = t & 15;
  const int p1 = ag >> 2, p2 = ag & 3;
  const int y = p1 * 16 + sub, x0 = p2 * 16;
  const float* gp = g + (size_t)b * NPOS + y * WW + x0;
  float s = 0.f;
#pragma unroll
  for (int i = 0; i < 16; ++i) s += gp[i];
  red[t] = s;
  __syncthreads();
  if (sub == 0) {
    float tot = 0.f;
    for (int i = 0; i < 16; ++i) tot += red[(ag << 4) + i];
    gb[ag] = tot * (1.0f / 256.0f);
  }
  __syncthreads();
  for (int idx = t; idx < NA * C_; idx += 256) {
    const int a = idx >> 8, ci = idx & 255;
    const int h = ci >> 5, d = ci & 31;
    agent_buf[(((size_t)b * NH + h) * NA + a) * HD + d] = gb[a] * q_w[ci] + q_b[ci];
  }
}

// ---------------- w~ = SCALE * (W_K agent), + kv_b-dot constant ----------------
// grid (h, b), 256 thr. wt[b*128+ha][256ci] bf16, kvbD[b*128+ha] f32.
__global__ __launch_bounds__(256) void k_wtilde(const u16* __restrict__ Wkt, const float* __restrict__ kv_b,
                                                const float* __restrict__ agent_buf,
                                                u16* __restrict__ wt, float* __restrict__ kvbD) {
  const int h = blockIdx.x, b = blockIdx.y;
  const int t = threadIdx.x;
  __shared__ u16 Wk[32 * 256];
  __shared__ float ags[16][32];
#pragma unroll
  for (int i = 0; i < 4; ++i) {
    const int idx = t + 256 * i;
    const int r = idx >> 5, sl = idx & 31;
    *(uint4*)(Wk + r * 256 + sl * 8) = *(const uint4*)(Wkt + (size_t)(h * 32 + r) * C_ + sl * 8);
  }
#pragma unroll
  for (int i = 0; i < 2; ++i) {
    const int idx = t + 256 * i;
    const int a = idx >> 5, d = idx & 31;
    ags[a][d] = agent_buf[(((size_t)b * NH + h) * NA + a) * HD + d] * SCALE;
  }
  __syncthreads();
  const int a = t >> 4, cb = (t & 15) * 16;
  float o[16];
#pragma unroll
  for (int k = 0; k < 16; ++k) o[k] = 0.f;
  for (int d = 0; d < 32; ++d) {
    const float av = ags[a][d];
#pragma unroll
    for (int k = 0; k < 16; ++k) o[k] += av * bfbits2f(Wk[d * 256 + cb + k]);
  }
  unsigned int w[8];
#pragma unroll
  for (int q = 0; q < 8; ++q)
    w[q] = (unsigned int)f2bfbits(o[2 * q]) | ((unsigned int)f2bfbits(o[2 * q + 1]) << 16);
  u16* op = wt + ((size_t)(b * NHA + h * 16 + a)) * C_ + cb;
  *(uint4*)op = make_uint4(w[0], w[1], w[2], w[3]);
  *(uint4*)(op + 8) = make_uint4(w[4], w[5], w[6], w[7]);
  if ((t & 15) == 0) {
    float s = 0.f;
#pragma unroll
    for (int d = 0; d < 32; ++d) s += ags[a][d] * kv_b[h * 32 + d];
    kvbD[b * NHA + h * 16 + a] = s;
  }
}

// ---------------- biases: posbT (pos, ha) f32 + agb (h,pos,a) f32 ----------------
__global__ __launch_bounds__(256) void k_bias(const float* __restrict__ an_b, const float* __restrict__ na_b,
                                              const float* __restrict__ ah_b, const float* __restrict__ aw_b,
                                              const float* __restrict__ ha_b, const float* __restrict__ wa_b,
                                              float* __restrict__ posbT, float* __restrict__ agb) {
  const int idx = blockIdx.x * 256 + threadIdx.x;  // total 128*4096
  const int ha = idx & 127;
  const int pos = idx >> 7;
  const int h = ha >> 4, a = ha & 15;
  const int y = pos >> 6, x = pos & 63;
  const float sy = (y + 0.5f) * 0.0625f - 0.5f;
  const float sx = (x + 0.5f) * 0.0625f - 0.5f;
  const int y0 = (int)floorf(sy);
  const int x0 = (int)floorf(sx);
  const float wy = sy - (float)y0, wx = sx - (float)x0;
  const int y0c = min(max(y0, 0), 3), y1c = min(max(y0 + 1, 0), 3);
  const int x0c = min(max(x0, 0), 3), x1c = min(max(x0 + 1, 0), 3);
  const float* an4 = an_b + ((size_t)h * NA + a) * 16;
  const float* na4 = na_b + ((size_t)h * NA + a) * 16;
  const float pa_ = (1.f - wy) * ((1.f - wx) * an4[y0c * 4 + x0c] + wx * an4[y0c * 4 + x1c]) +
                    wy * ((1.f - wx) * an4[y1c * 4 + x0c] + wx * an4[y1c * 4 + x1c]);
  const float nv_ = (1.f - wy) * ((1.f - wx) * na4[y0c * 4 + x0c] + wx * na4[y0c * 4 + x1c]) +
                    wy * ((1.f - wx) * na4[y1c * 4 + x0c] + wx * na4[y1c * 4 + x1c]);
  posbT[(size_t)pos * NHA + ha] = pa_ + ah_b[((size_t)h * NA + a) * HH + y] + aw_b[((size_t)h * NA + a) * WW + x];
  agb[((size_t)h * NPOS + pos) * NA + a] =
      nv_ + ha_b[((size_t)h * HH + y) * NA + a] + wa_b[((size_t)h * WW + x) * NA + a];
}

// ---------------- transpose+convert inputs: in (b,c,n) f32 -> At (b,n,c) bf16 ----------------
__global__ __launch_bounds__(256) void k_prep_in(const float* __restrict__ in1, const float* __restrict__ in2,
                                                 u16* __restrict__ At1, u16* __restrict__ At2) {
  const int z = blockIdx.z;
  const int src = z >> 3, b = z & 7;
  const float* in = src ? in2 : in1;
  u16* At = src ? At2 : At1;
  const int pos0 = blockIdx.x * 64;
  const int ci0 = blockIdx.y * 64;
  __shared__ float tile[64][68];
  const int t = threadIdx.x;
  const int rpos = (t & 15) << 2, rci = t >> 4;
#pragma unroll
  for (int i = 0; i < 4; ++i) {
    const int ci_l = rci + 16 * i;
    const float4 v = *(const float4*)(in + ((size_t)b * C_ + ci0 + ci_l) * NPOS + pos0 + rpos);
    tile[ci_l][rpos + 0] = v.x; tile[ci_l][rpos + 1] = v.y;
    tile[ci_l][rpos + 2] = v.z; tile[ci_l][rpos + 3] = v.w;
  }
  __syncthreads();
#pragma unroll
  for (int i = 0; i < 2; ++i) {
    const int u = t + 256 * i;
    const int p = u >> 3, s = u & 7;
    unsigned int w[4];
#pragma unroll
    for (int q = 0; q < 4; ++q) {
      const u16 lo = f2bfbits(tile[s * 8 + 2 * q][p]);
      const u16 hi = f2bfbits(tile[s * 8 + 2 * q + 1][p]);
      w[q] = (unsigned int)lo | ((unsigned int)hi << 16);
    }
    *(uint4*)(At + ((size_t)(pos0 + p)) * C_ + (size_t)b * NPOS * C_ + ci0 + s * 8) =
        make_uint4(w[0], w[1], w[2], w[3]);
  }
}

// ---------------- transpose+convert weights ----------------
__global__ __launch_bounds__(256) void k_prep_w(const float* __restrict__ kv_w, const float* __restrict__ proj_w,
                                                u16* __restrict__ Wkt, u16* __restrict__ Pwt) {
  const int x = blockIdx.x;
  const float* W; u16* T; int j0, ci0, ncols;
  if (x < 32) { W = kv_w;  T = Wkt; j0 = (x & 7) * 64; ci0 = (x >> 3) * 64; ncols = 512; }
  else        { W = proj_w; T = Pwt; j0 = ((x - 32) & 3) * 64; ci0 = ((x - 32) >> 2) * 64; ncols = 256; }
  __shared__ float tile[64][68];
  const int t = threadIdx.x;
  const int rj = (t & 15) << 2, rci = t >> 4;
#pragma unroll
  for (int i = 0; i < 4; ++i) {
    const int ci_l = rci + 16 * i;
    const float4 v = *(const float4*)(W + (size_t)(ci0 + ci_l) * ncols + j0 + rj);
    tile[ci_l][rj + 0] = v.x; tile[ci_l][rj + 1] = v.y;
    tile[ci_l][rj + 2] = v.z; tile[ci_l][rj + 3] = v.w;
  }
  __syncthreads();
#pragma unroll
  for (int i = 0; i < 2; ++i) {
    const int u = t + 256 * i;
    const int p = u >> 3, s = u & 7;
    unsigned int w[4];
#pragma unroll
    for (int q = 0; q < 4; ++q) {
      const u16 lo = f2bfbits(tile[s * 8 + 2 * q][p]);
      const u16 hi = f2bfbits(tile[s * 8 + 2 * q + 1][p]);
      w[q] = (unsigned int)lo | ((unsigned int)hi << 16);
    }
    *(uint4*)(T + (size_t)(j0 + p) * C_ + ci0 + s * 8) = make_uint4(w[0], w[1], w[2], w[3]);
  }
}

// ---------------- V projection only: V[b,pos,256] = At @ Wv + bv ----------------
__global__ __launch_bounds__(256) void k_v_mfma(const u16* __restrict__ At1, const u16* __restrict__ At2,
                                                const u16* __restrict__ Wkt, const float* __restrict__ kv_b,
                                                u16* __restrict__ v1, u16* __restrict__ v2) {
  const int z = blockIdx.z;
  const int src = z >> 3, b = z & 7;
  const u16* At = src ? At2 : At1;
  u16* vout = src ? v2 : v1;
  const int pos0 = blockIdx.x * 128;
  const int j0 = blockIdx.y * 128;

  __shared__ __align__(16) u16 SM[16384];
  u16* Ab = SM;
  u16* Bb = SM + 8192;

  const int t = threadIdx.x;
  const int wave = t >> 6, lane = t & 63;
  const int wm = wave >> 1, wn = wave & 1;
  const int g = lane >> 4;

  const u16* Ag = Wkt + (size_t)(256 + j0) * C_;
  const u16* Bg = At + ((size_t)b * NPOS + pos0) * C_;

  f32x4 acc[4][4];
#pragma unroll
  for (int m = 0; m < 4; ++m)
#pragma unroll
    for (int n = 0; n < 4; ++n) { acc[m][n][0]=0.f; acc[m][n][1]=0.f; acc[m][n][2]=0.f; acc[m][n][3]=0.f; }

  uint4 ra[4], rb[4];
#define V_LOAD(KT)                                                         \
  _Pragma("unroll") for (int i = 0; i < 4; ++i) {                          \
    const int u = t + 256 * i, rr = u >> 3, ss = u & 7;                    \
    ra[i] = *(const uint4*)(Ag + (size_t)rr * C_ + (KT) * 64 + ss * 8);    \
    rb[i] = *(const uint4*)(Bg + (size_t)rr * C_ + (KT) * 64 + ss * 8);    \
  }
#define V_WRITE()                                                          \
  _Pragma("unroll") for (int i = 0; i < 4; ++i) {                          \
    const int u = t + 256 * i, rr = u >> 3, ss = u & 7;                    \
    const int sw = ((ss ^ (rr & 7)) << 3);                                 \
    *(uint4*)(Ab + rr * 64 + sw) = ra[i];                                  \
    *(uint4*)(Bb + rr * 64 + sw) = rb[i];                                  \
  }

  V_LOAD(0);
  V_WRITE();
  V_LOAD(1);
  __syncthreads();

  for (int kt = 0; kt < 4; ++kt) {
#pragma unroll
    for (int kk = 0; kk < 2; ++kk) {
      bf16x8 af[4], bfr[4];
#pragma unroll
      for (int m = 0; m < 4; ++m) {
        const int r = wm * 64 + m * 16 + (lane & 15);
        af[m] = *(const bf16x8*)(Ab + r * 64 + (((kk * 4 + g) ^ (r & 7)) << 3));
      }
#pragma unroll
      for (int n = 0; n < 4; ++n) {
        const int c = wn * 64 + n * 16 + (lane & 15);
        bfr[n] = *(const bf16x8*)(Bb + c * 64 + (((kk * 4 + g) ^ (c & 7)) << 3));
      }
#pragma unroll
      for (int m = 0; m < 4; ++m)
#pragma unroll
        for (int n = 0; n < 4; ++n)
          acc[m][n] = __builtin_amdgcn_mfma_f32_16x16x32_bf16(af[m], bfr[n], acc[m][n], 0, 0, 0);
    }
    if (kt < 3) {
      __syncthreads();
      V_WRITE();
      if (kt < 2) V_LOAD(kt + 2);
      __syncthreads();
    }
  }
#undef V_LOAD
#undef V_WRITE

  __syncthreads();
#pragma unroll
  for (int m = 0; m < 4; ++m) {
    const int jl = wm * 64 + m * 16 + (lane >> 4) * 4;
    const float4 bv = *(const float4*)(kv_b + 256 + j0 + jl);
#pragma unroll
    for (int n = 0; n < 4; ++n) {
      const int pos_l = wn * 64 + n * 16 + (lane & 15);
      const f32x4 a = acc[m][n];
      ushort4 st;
      st.x = f2bfbits(a[0] + bv.x); st.y = f2bfbits(a[1] + bv.y);
      st.z = f2bfbits(a[2] + bv.z); st.w = f2bfbits(a[3] + bv.w);
      const int slot = (jl >> 3) ^ (pos_l & 7);
      *(ushort4*)(SM + pos_l * 128 + slot * 8 + (jl & 7)) = st;
    }
  }
  __syncthreads();
#pragma unroll
  for (int i = 0; i < 8; ++i) {
    const int idx = t + 256 * i;
    const int row = idx >> 4, sl = idx & 15;
    const uint4 v = *(const uint4*)(SM + row * 128 + ((sl ^ (row & 7)) << 3));
    *(uint4*)(vout + ((size_t)b * NPOS + pos0 + row) * C_ + j0 + sl * 8) = v;
  }
}

// ---------------- score GEMM: E[sb,ha,pos] = exp(At @ wt^T + posbT + kvbD) bf16, + row sums ----------------
// A = At rows pos (M=128), B = wt rows ha (N=128), K=256.
__global__ __launch_bounds__(256) void k_score(const u16* __restrict__ At1, const u16* __restrict__ At2,
                                               const u16* __restrict__ wt, const float* __restrict__ posbT,
                                               const float* __restrict__ kvbD,
                                               u16* __restrict__ E, float* __restrict__ lsumP) {
  const int z = blockIdx.z;
  const int src = z >> 3, b = z & 7;
  const int sb = src * 8 + b;
  const u16* At = src ? At2 : At1;
  const int pos0 = blockIdx.x * 128;

  __shared__ __align__(16) u16 SM[16384];
  __shared__ float lsum_sm[2][128];
  u16* Ab = SM;
  u16* Bb = SM + 8192;

  const int t = threadIdx.x;
  const int wave = t >> 6, lane = t & 63;
  const int wm = wave >> 1, wn = wave & 1;
  const int g = lane >> 4;

  const u16* Ag = At + ((size_t)b * NPOS + pos0) * C_;
  const u16* Bg = wt + (size_t)b * NHA * C_;

  f32x4 acc[4][4];
#pragma unroll
  for (int m = 0; m < 4; ++m)
#pragma unroll
    for (int n = 0; n < 4; ++n) { acc[m][n][0]=0.f; acc[m][n][1]=0.f; acc[m][n][2]=0.f; acc[m][n][3]=0.f; }

  uint4 ra[4], rb[4];
#define S_LOAD(KT)                                                         \
  _Pragma("unroll") for (int i = 0; i < 4; ++i) {                          \
    const int u = t + 256 * i, rr = u >> 3, ss = u & 7;                    \
    ra[i] = *(const uint4*)(Ag + (size_t)rr * C_ + (KT) * 64 + ss * 8);    \
    rb[i] = *(const uint4*)(Bg + (size_t)rr * C_ + (KT) * 64 + ss * 8);    \
  }
#define S_WRITE()                                                          \
  _Pragma("unroll") for (int i = 0; i < 4; ++i) {                          \
    const int u = t + 256 * i, rr = u >> 3, ss = u & 7;                    \
    const int sw = ((ss ^ (rr & 7)) << 3);                                 \
    *(uint4*)(Ab + rr * 64 + sw) = ra[i];                                  \
    *(uint4*)(Bb + rr * 64 + sw) = rb[i];                                  \
  }

  S_LOAD(0);
  S_WRITE();
  S_LOAD(1);
  __syncthreads();

  for (int kt = 0; kt < 4; ++kt) {
#pragma unroll
    for (int kk = 0; kk < 2; ++kk) {
      bf16x8 af[4], bfr[4];
#pragma unroll
      for (int m = 0; m < 4; ++m) {
        const int r = wm * 64 + m * 16 + (lane & 15);
        af[m] = *(const bf16x8*)(Ab + r * 64 + (((kk * 4 + g) ^ (r & 7)) << 3));
      }
#pragma unroll
      for (int n = 0; n < 4; ++n) {
        const int c = wn * 64 + n * 16 + (lane & 15);
        bfr[n] = *(const bf16x8*)(Bb + c * 64 + (((kk * 4 + g) ^ (c & 7)) << 3));
      }
#pragma unroll
      for (int m = 0; m < 4; ++m)
#pragma unroll
        for (int n = 0; n < 4; ++n)
          acc[m][n] = __builtin_amdgcn_mfma_f32_16x16x32_bf16(af[m], bfr[n], acc[m][n], 0, 0, 0);
    }
    if (kt < 3) {
      __syncthreads();
      S_WRITE();
      if (kt < 2) S_LOAD(kt + 2);
      __syncthreads();
    }
  }
#undef S_LOAD
#undef S_WRITE

  // epilogue: +posbT +kvbD, exp, bf16 into SM as E_sm[ha][128 pos] (swizzled 16B slots), row sums
  __syncthreads();
  float ls[4] = {0.f, 0.f, 0.f, 0.f};
#pragma unroll
  for (int n = 0; n < 4; ++n) {
    const int ha_l = wn * 64 + n * 16 + (lane & 15);
    const float kb = kvbD[b * NHA + ha_l];
#pragma unroll
    for (int m = 0; m < 4; ++m) {
      const int pos_l = wm * 64 + m * 16 + (lane >> 4) * 4;
      float e[4];
#pragma unroll
      for (int j = 0; j < 4; ++j) {
        const float s = acc[m][n][j] + posbT[(size_t)(pos0 + pos_l + j) * NHA + ha_l] + kb;
        e[j] = __expf(s);
        ls[n] += e[j];
      }
      ushort4 st;
      st.x = f2bfbits(e[0]); st.y = f2bfbits(e[1]); st.z = f2bfbits(e[2]); st.w = f2bfbits(e[3]);
      const int sw = (pos_l >> 3) ^ (ha_l & 15);
      *(ushort4*)(SM + ha_l * 128 + sw * 8 + (pos_l & 7)) = st;
    }
  }
  // reduce row sums over lane>>4 groups
#pragma unroll
  for (int n = 0; n < 4; ++n) {
    float v = ls[n];
    v += __shfl_xor(v, 16);
    v += __shfl_xor(v, 32);
    ls[n] = v;
  }
  if (lane < 16) {
#pragma unroll
    for (int n = 0; n < 4; ++n) lsum_sm[wm][wn * 64 + n * 16 + lane] = ls[n];
  }
  __syncthreads();
  if (t < 128)
    lsumP[((size_t)sb * 32 + blockIdx.x) * NHA + t] = lsum_sm[0][t] + lsum_sm[1][t];
  // coalesced E store: 128 ha rows x 16 uint4 (8 pos each)
#pragma unroll
  for (int i = 0; i < 8; ++i) {
    const int idx = t + 256 * i;
    const int row = idx >> 4, sl = idx & 15;
    const uint4 v = *(const uint4*)(SM + row * 128 + ((sl ^ (row & 15)) << 3));
    *(uint4*)(E + ((size_t)sb * NHA + row) * NPOS + pos0 + sl * 8) = v;
  }
}

// ---------------- PV GEMM: T_p[sb,kc,ha,ci] = sum_pos in[ci,pos] * E[ha,pos] ----------------
// A = in f32 rows ci (cvt to bf16), B = E rows ha, K = 512 per kc (8 kt of 64).
__global__ __launch_bounds__(256) void k_pv(const float* __restrict__ in1, const float* __restrict__ in2,
                                            const u16* __restrict__ E, float* __restrict__ T_p) {
  const int kc = blockIdx.x;            // 0..7
  const int ci0 = blockIdx.y * 128;     // 0 or 128
  const int sb = blockIdx.z;
  const int src = sb >> 3, b = sb & 7;
  const float* in = src ? in2 : in1;
  const int kpos0 = kc * 512;

  __shared__ __align__(16) u16 As[8192];
  __shared__ __align__(16) u16 Bs[8192];

  const int t = threadIdx.x;
  const int wave = t >> 6, lane = t & 63;
  const int wm = wave >> 1, wn = wave & 1;
  const int g = lane >> 4;

  const float* Ain = in + (size_t)b * C_ * NPOS;
  const u16* Eg = E + (size_t)sb * NHA * NPOS;

  f32x4 acc[4][4];
#pragma unroll
  for (int m = 0; m < 4; ++m)
#pragma unroll
    for (int n = 0; n < 4; ++n) { acc[m][n][0]=0.f; acc[m][n][1]=0.f; acc[m][n][2]=0.f; acc[m][n][3]=0.f; }

  float4 pa[8];
  uint4 pb[4];
#define PV_LOAD(KT)                                                            \
  _Pragma("unroll") for (int i = 0; i < 8; ++i) {                              \
    const int idx = t + 256 * i, rr = idx >> 4, fq = idx & 15;                 \
    pa[i] = *(const float4*)(Ain + (size_t)(ci0 + rr) * NPOS + kpos0 + (KT) * 64 + fq * 4); \
  }                                                                            \
  _Pragma("unroll") for (int i = 0; i < 4; ++i) {                              \
    const int idx = t + 256 * i, rr = idx >> 3, ss = idx & 7;                  \
    pb[i] = *(const uint4*)(Eg + (size_t)rr * NPOS + kpos0 + (KT) * 64 + ss * 8); \
  }
#define PV_WRITE()                                                             \
  _Pragma("unroll") for (int i = 0; i < 8; ++i) {                              \
    const int idx = t + 256 * i, rr = idx >> 4, fq = idx & 15;                 \
    ushort4 st;                                                                \
    st.x = f2bfbits(pa[i].x); st.y = f2bfbits(pa[i].y);                        \
    st.z = f2bfbits(pa[i].z); st.w = f2bfbits(pa[i].w);                        \
    const int sw = ((fq >> 1) ^ (rr & 7));                                     \
    *(ushort4*)(As + rr * 64 + sw * 8 + (fq & 1) * 4) = st;                    \
  }                                                                            \
  _Pragma("unroll") for (int i = 0; i < 4; ++i) {                              \
    const int idx = t + 256 * i, rr = idx >> 3, ss = idx & 7;                  \
    *(uint4*)(Bs + rr * 64 + ((ss ^ (rr & 7)) << 3)) = pb[i];                  \
  }

  PV_LOAD(0);
  PV_WRITE();
  PV_LOAD(1);
  __syncthreads();

  for (int kt = 0; kt < 8; ++kt) {
#pragma unroll
    for (int kk = 0; kk < 2; ++kk) {
      bf16x8 af[4], bfr[4];
#pragma unroll
      for (int m = 0; m < 4; ++m) {
        const int r = wm * 64 + m * 16 + (lane & 15);
        af[m] = *(const bf16x8*)(As + r * 64 + (((kk * 4 + g) ^ (r & 7)) << 3));
      }
#pragma unroll
      for (int n = 0; n < 4; ++n) {
        const int c = wn * 64 + n * 16 + (lane & 15);
        bfr[n] = *(const bf16x8*)(Bs + c * 64 + (((kk * 4 + g) ^ (c & 7)) << 3));
      }
#pragma unroll
      for (int m = 0; m < 4; ++m)
#pragma unroll
        for (int n = 0; n < 4; ++n)
          acc[m][n] = __builtin_amdgcn_mfma_f32_16x16x32_bf16(af[m], bfr[n], acc[m][n], 0, 0, 0);
    }
    if (kt < 7) {
      __syncthreads();
      PV_WRITE();
      if (kt < 6) PV_LOAD(kt + 2);
      __syncthreads();
    }
  }
#undef PV_LOAD
#undef PV_WRITE

  // store T partials (ha-major, ci contiguous): float4 along ci
#pragma unroll
  for (int m = 0; m < 4; ++m) {
    const int ci_l = wm * 64 + m * 16 + (lane >> 4) * 4;
#pragma unroll
    for (int n = 0; n < 4; ++n) {
      const int ha_l = wn * 64 + n * 16 + (lane & 15);
      const f32x4 a = acc[m][n];
      *(float4*)(T_p + (((size_t)sb * 8 + kc) * NHA + ha_l) * C_ + ci0 + ci_l) =
          make_float4(a[0], a[1], a[2], a[3]);
    }
  }
}

// ---------------- agent_v = (sum_kc T)/lsum @ Wv + bv ----------------
// grid (h, sb), 256 thr.
__global__ __launch_bounds__(256) void k_agentv(const float* __restrict__ T_p, const float* __restrict__ lsumP,
                                                const u16* __restrict__ Wkt, const float* __restrict__ kv_b,
                                                float* __restrict__ agent_v) {
  const int h = blockIdx.x, sb = blockIdx.y;
  const int t = threadIdx.x;
  __shared__ float Tred[16 * 256];
  __shared__ u16 Wv[32 * 256];
  __shared__ float lsum_s[16];
#pragma unroll
  for (int i = 0; i < 4; ++i) {
    const int idx = t + 256 * i;
    const int r = idx >> 5, sl = idx & 31;
    *(uint4*)(Wv + r * 256 + sl * 8) = *(const uint4*)(Wkt + (size_t)(256 + h * 32 + r) * C_ + sl * 8);
  }
#pragma unroll
  for (int i = 0; i < 16; ++i) {
    const int idx = t + 256 * i;
    const int a = idx >> 8, ci = idx & 255;
    float s = 0.f;
#pragma unroll
    for (int kc = 0; kc < 8; ++kc)
      s += T_p[(((size_t)sb * 8 + kc) * NHA + h * 16 + a) * C_ + ci];
    Tred[a * 256 + ci] = s;
  }
  if (t < 16) {
    float s = 0.f;
#pragma unroll
    for (int pt = 0; pt < 32; ++pt) s += lsumP[((size_t)sb * 32 + pt) * NHA + h * 16 + t];
    lsum_s[t] = s;
  }
  __syncthreads();
  const int a = t >> 4, dp = (t & 15) * 2;
  float o0 = 0.f, o1 = 0.f;
  const float* Tr = Tred + a * 256;
  for (int ci = 0; ci < 256; ++ci) {
    const float tv = Tr[ci];
    o0 += tv * bfbits2f(Wv[dp * 256 + ci]);
    o1 += tv * bfbits2f(Wv[(dp + 1) * 256 + ci]);
  }
  const float inv = 1.0f / lsum_s[a];
  float* op = agent_v + (size_t)sb * NHA * HD + (h * 16 + a) * HD + dp;
  op[0] = o0 * inv + kv_b[256 + h * 32 + dp];
  op[1] = o1 * inv + kv_b[256 + h * 32 + dp + 1];
}

// ---------------- query attention over 16 agents, bf16 outputs ----------------
__global__ __launch_bounds__(256) void k_qattn(const float* __restrict__ g,
                                               const float* __restrict__ q_w, const float* __restrict__ q_b,
                                               const float* __restrict__ agent_buf,
                                               const float* __restrict__ agent_v,
                                               const float* __restrict__ agb,
                                               u16* __restrict__ o1s, u16* __restrict__ o2s) {
  const int h = blockIdx.y, b = blockIdx.z;
  const int t = threadIdx.x;
  const int pos = blockIdx.x * 256 + t;
  __shared__ float dotW[16], dotB[16];
  __shared__ float av1[16][32], av2[16][32];
  for (int idx = t; idx < 512; idx += 256) {
    const int a = idx >> 5, d = idx & 31;
    av1[a][d] = agent_v[(size_t)b * NHA * HD + (h * 16 + a) * HD + d];
    av2[a][d] = agent_v[(size_t)(8 + b) * NHA * HD + (h * 16 + a) * HD + d];
  }
  if (t < 16) {
    float dw = 0.f, db = 0.f;
    const float* agp = agent_buf + (((size_t)b * NH + h) * NA + t) * HD;
#pragma unroll
    for (int d = 0; d < HD; ++d) {
      const float ad = agp[d];
      dw += ad * q_w[h * HD + d];
      db += ad * q_b[h * HD + d];
    }
    dotW[t] = dw * SCALE;
    dotB[t] = db * SCALE;
  }
  __syncthreads();
  const float gv = g[(size_t)b * NPOS + pos];
  const float* abp = agb + ((size_t)h * NPOS + pos) * NA;
  float s[16];
  float m = -1e30f;
#pragma unroll
  for (int a = 0; a < 16; ++a) {
    s[a] = gv * dotW[a] + dotB[a] + abp[a];
    m = fmaxf(m, s[a]);
  }
  float l = 0.f;
#pragma unroll
  for (int a = 0; a < 16; ++a) {
    s[a] = __expf(s[a] - m);
    l += s[a];
  }
  const float inv = 1.0f / l;
  float o1[32] = {}, o2[32] = {};
#pragma unroll
  for (int a = 0; a < 16; ++a) {
    const float pa = s[a] * inv;
#pragma unroll
    for (int d = 0; d < 32; ++d) {
      o1[d] += pa * av1[a][d];
      o2[d] += pa * av2[a][d];
    }
  }
  u16* o1p = o1s + ((size_t)b * NPOS + pos) * C_ + h * HD;
  u16* o2p = o2s + ((size_t)b * NPOS + pos) * C_ + h * HD;
#pragma unroll
  for (int blk = 0; blk < 4; ++blk) {
    unsigned int w1[4], w2[4];
#pragma unroll
    for (int q = 0; q < 4; ++q) {
      w1[q] = (unsigned int)f2bfbits(o1[blk * 8 + 2 * q]) | ((unsigned int)f2bfbits(o1[blk * 8 + 2 * q + 1]) << 16);
      w2[q] = (unsigned int)f2bfbits(o2[blk * 8 + 2 * q]) | ((unsigned int)f2bfbits(o2[blk * 8 + 2 * q + 1]) << 16);
    }
    *(uint4*)(o1p + blk * 8) = make_uint4(w1[0], w1[1], w1[2], w1[3]);
    *(uint4*)(o2p + blk * 8) = make_uint4(w2[0], w2[1], w2[2], w2[3]);
  }
}

// ---------------- depthwise 3x3 conv on V (b,pos,256) bf16, RMW o1s/o2s ----------------
__global__ __launch_bounds__(256) void k_dwconv(const u16* __restrict__ v1, const u16* __restrict__ v2,
                                                const float* __restrict__ dwc_w, const float* __restrict__ dwc_b,
                                                u16* __restrict__ o1s, u16* __restrict__ o2s) {
  const u16* V = blockIdx.z ? v2 : v1;
  u16* out = blockIdx.z ? o2s : o1s;
  const int b = blockIdx.y;
  const int ci = threadIdx.x;
  const int pos0 = blockIdx.x << 3;
  float w[9];
#pragma unroll
  for (int q = 0; q < 9; ++q) w[q] = dwc_w[ci * 9 + q];
  const float bias = dwc_b[ci];
  const u16* vb = V + (size_t)b * NPOS * C_ + ci;
  for (int pp = 0; pp < 8; ++pp) {
    const int pos = pos0 + pp;
    const int y = pos >> 6, x = pos & 63;
    float acc = bias;
#pragma unroll
    for (int dy = -1; dy <= 1; ++dy) {
      const int yy = y + dy;
      if (yy < 0 || yy > 63) continue;
#pragma unroll
      for (int dx = -1; dx <= 1; ++dx) {
        const int xx = x + dx;
        if (xx < 0 || xx > 63) continue;
        acc += w[(dy + 1) * 3 + (dx + 1)] * bfbits2f(vb[(size_t)(yy * 64 + xx) * C_]);
      }
    }
    const size_t oidx = ((size_t)b * NPOS + pos) * C_ + ci;
    out[oidx] = f2bfbits(bfbits2f(out[oidx]) + acc);
  }
}

// ---------------- output projection, bf16 MFMA -> (b,c,n) f32 + bias + residual ----------------
__global__ __launch_bounds__(256) void k_proj_mfma(const u16* __restrict__ o1s, const u16* __restrict__ o2s,
                                                   const u16* __restrict__ Pwt, const float* __restrict__ proj_b,
                                                   const float* __restrict__ in1, const float* __restrict__ in2,
                                                   float* __restrict__ out1, float* __restrict__ out2) {
  const int z = blockIdx.z;
  const int src = z >> 3, b = z & 7;
  const u16* S = src ? o2s : o1s;
  const float* inp = src ? in2 : in1;
  float* outp = src ? out2 : out1;
  const int pos0 = blockIdx.x * 128;
  const int co0 = blockIdx.y * 128;

  __shared__ __align__(16) u16 SM[16384];
  u16* Ab = SM;
  u16* Bb = SM + 8192;
  float* SMF = (float*)SM;

  const int t = threadIdx.x;
  const int wave = t >> 6, lane = t & 63;
  const int wm = wave >> 1, wn = wave & 1;
  const int g = lane >> 4;

  const u16* Ag = S + ((size_t)b * NPOS + pos0) * C_;
  const u16* Bg = Pwt + (size_t)co0 * C_;

  f32x4 acc[4][4];
#pragma unroll
  for (int m = 0; m < 4; ++m)
#pragma unroll
    for (int n = 0; n < 4; ++n) { acc[m][n][0]=0.f; acc[m][n][1]=0.f; acc[m][n][2]=0.f; acc[m][n][3]=0.f; }

  uint4 ra[4], rb[4];
#define PJ_LOAD(KT)                                                        \
  _Pragma("unroll") for (int i = 0; i < 4; ++i) {                          \
    const int u = t + 256 * i, rr = u >> 3, ss = u & 7;                    \
    ra[i] = *(const uint4*)(Ag + (size_t)rr * C_ + (KT) * 64 + ss * 8);    \
    rb[i] = *(const uint4*)(Bg + (size_t)rr * C_ + (KT) * 64 + ss * 8);    \
  }
#define PJ_WRITE()                                                         \
  _Pragma("unroll") for (int i = 0; i < 4; ++i) {                          \
    const int u = t + 256 * i, rr = u >> 3, ss = u & 7;                    \
    const int sw = ((ss ^ (rr & 7)) << 3);                                 \
    *(uint4*)(Ab + rr * 64 + sw) = ra[i];                                  \
    *(uint4*)(Bb + rr * 64 + sw) = rb[i];                                  \
  }

  PJ_LOAD(0);
  PJ_WRITE();
  PJ_LOAD(1);
  __syncthreads();

  for (int kt = 0; kt < 4; ++kt) {
#pragma unroll
    for (int kk = 0; kk < 2; ++kk) {
      bf16x8 af[4], bfr[4];
#pragma unroll
      for (int m = 0; m < 4; ++m) {
        const int r = wm * 64 + m * 16 + (lane & 15);
        af[m] = *(const bf16x8*)(Ab + r * 64 + (((kk * 4 + g) ^ (r & 7)) << 3));
      }
#pragma unroll
      for (int n = 0; n < 4; ++n) {
        const int c = wn * 64 + n * 16 + (lane & 15);
        bfr[n] = *(const bf16x8*)(Bb + c * 64 + (((kk * 4 + g) ^ (c & 7)) << 3));
      }
#pragma unroll
      for (int m = 0; m < 4; ++m)
#pragma unroll
        for (int n = 0; n < 4; ++n)
          acc[m][n] = __builtin_amdgcn_mfma_f32_16x16x32_bf16(af[m], bfr[n], acc[m][n], 0, 0, 0);
    }
    if (kt < 3) {
      __syncthreads();
      PJ_WRITE();
      if (kt < 2) PJ_LOAD(kt + 2);
      __syncthreads();
    }
  }
#undef PJ_LOAD
#undef PJ_WRITE

#pragma unroll
  for (int hf = 0; hf < 2; ++hf) {
    __syncthreads();
    if (wn == hf) {
#pragma unroll
      for (int n = 0; n < 4; ++n) {
        const int co_l = n * 16 + (lane & 15);
#pragma unroll
        for (int m = 0; m < 4; ++m) {
          const int pos_l = wm * 64 + m * 16 + (lane >> 4) * 4;
          const int slot = (pos_l >> 2) ^ (co_l & 7);
          const f32x4 a = acc[m][n];
          *(float4*)(SMF + co_l * 128 + slot * 4) = make_float4(a[0], a[1], a[2], a[3]);
        }
      }
    }
    __syncthreads();
#pragma unroll
    for (int i = 0; i < 8; ++i) {
      const int idx = t + 256 * i;
      const int row = idx >> 5, sl = idx & 31;
      const float4 v = *(const float4*)(SMF + row * 128 + ((sl ^ (row & 7)) << 2));
      const int co = co0 + hf * 64 + row;
      const float pb = proj_b[co];
      const size_t base = ((size_t)b * C_ + co) * NPOS + pos0 + sl * 4;
      const float4 res = *(const float4*)(inp + base);
      *(float4*)(outp + base) = make_float4(v.x + pb + res.x, v.y + pb + res.y,
                                            v.z + pb + res.z, v.w + pb + res.w);
    }
  }
}

extern "C" void kernel_launch(void* const* d_in, const int* in_sizes, int n_in,
                              void* d_out, int out_size, void* d_ws, size_t ws_size,
                              hipStream_t stream) {
  const float* input1 = (const float*)d_in[0];
  const float* input2 = (const float*)d_in[1];
  const float* guid   = (const float*)d_in[2];
  const float* kv_w   = (const float*)d_in[3];
  const float* kv_b   = (const float*)d_in[4];
  const float* q_w    = (const float*)d_in[5];
  const float* q_b    = (const float*)d_in[6];
  const float* proj_w = (const float*)d_in[7];
  const float* proj_b = (const float*)d_in[8];
  const float* dwc_w  = (const float*)d_in[9];
  const float* dwc_b  = (const float*)d_in[10];
  const float* an_b   = (const float*)d_in[11];
  const float* na_b   = (const float*)d_in[12];
  const float* ah_b   = (const float*)d_in[13];
  const float* aw_b   = (const float*)d_in[14];
  const float* ha_b   = (const float*)d_in[15];
  const float* wa_b   = (const float*)d_in[16];

  char* W = (char*)d_ws;
  u16* At1 = (u16*)W;        W += (size_t)B_ * NPOS * C_ * 2;       // 16.8MB
  u16* At2 = (u16*)W;        W += (size_t)B_ * NPOS * C_ * 2;
  u16* v1  = (u16*)W;        W += (size_t)B_ * NPOS * C_ * 2;
  u16* v2  = (u16*)W;        W += (size_t)B_ * NPOS * C_ * 2;
  u16* o1s = (u16*)W;        W += (size_t)B_ * NPOS * C_ * 2;
  u16* o2s = (u16*)W;        W += (size_t)B_ * NPOS * C_ * 2;
  u16* E   = (u16*)W;        W += (size_t)16 * NHA * NPOS * 2;      // 16.8MB
  float* T_p = (float*)W;    W += (size_t)16 * 8 * NHA * C_ * 4;    // 16.8MB
  u16* Wkt = (u16*)W;        W += (size_t)512 * C_ * 2;
  u16* Pwt = (u16*)W;        W += (size_t)C_ * C_ * 2;
  u16* wt  = (u16*)W;        W += (size_t)B_ * NHA * C_ * 2;
  float* posbT = (float*)W;  W += (size_t)NPOS * NHA * 4;
  float* agb   = (float*)W;  W += (size_t)NH * NPOS * NA * 4;
  float* agentb = (float*)W; W += (size_t)B_ * NH * NA * HD * 4;
  float* kvbD   = (float*)W; W += (size_t)B_ * NHA * 4;
  float* lsumP  = (float*)W; W += (size_t)16 * 32 * NHA * 4;
  float* agent_v = (float*)W; W += (size_t)16 * NHA * HD * 4;

  float* out1 = (float*)d_out;
  float* out2 = out1 + (size_t)B_ * C_ * NPOS;

  hipLaunchKernelGGL(k_agent, dim3(B_), dim3(256), 0, stream, guid, q_w, q_b, agentb);
  hipLaunchKernelGGL(k_bias, dim3((NHA * NPOS) / 256), dim3(256), 0, stream,
                     an_b, na_b, ah_b, aw_b, ha_b, wa_b, posbT, agb);
  hipLaunchKernelGGL(k_prep_w, dim3(48), dim3(256), 0, stream, kv_w, proj_w, Wkt, Pwt);
  hipLaunchKernelGGL(k_wtilde, dim3(NH, B_), dim3(256), 0, stream, Wkt, kv_b, agentb, wt, kvbD);
  hipLaunchKernelGGL(k_prep_in, dim3(64, 4, 16), dim3(256), 0, stream, input1, input2, At1, At2);
  hipLaunchKernelGGL(k_v_mfma, dim3(32, 2, 16), dim3(256), 0, stream,
                     At1, At2, Wkt, kv_b, v1, v2);
  hipLaunchKernelGGL(k_score, dim3(32, 1, 16), dim3(256), 0, stream,
                     At1, At2, wt, posbT, kvbD, E, lsumP);
  hipLaunchKernelGGL(k_pv, dim3(8, 2, 16), dim3(256), 0, stream, input1, input2, E, T_p);
  hipLaunchKernelGGL(k_agentv, dim3(NH, 16), dim3(256), 0, stream, T_p, lsumP, Wkt, kv_b, agent_v);
  hipLaunchKernelGGL(k_qattn, dim3(NPOS / 256, NH, B_), dim3(256), 0, stream,
                     guid, q_w, q_b, agentb, agent_v, agb, o1s, o2s);
  hipLaunchKernelGGL(k_dwconv, dim3(NPOS / 8, B_, 2), dim3(256), 0, stream,
                     v1, v2, dwc_w, dwc_b, o1s, o2s);
  hipLaunchKernelGGL(k_proj_mfma, dim3(32, 2, 16), dim3(256), 0, stream,
                     o1s, o2s, Pwt, proj_b, input1, input2, out1, out2);
}

// Round 8
// 271.620 us; speedup vs baseline: 2.6054x; 1.0806x over previous
//
#include <hip/hip_runtime.h>
#include <hip/hip_bf16.h>
#include <cstddef>

#define B_   8
#define C_   256
#define HH   64
#define WW   64
#define NPOS 4096
#define NH   8
#define HD   32
#define NA   16
#define NHA  128      // NH*NA
#define SCALE 0.17677669529663687f

typedef unsigned short u16;
typedef __attribute__((ext_vector_type(8))) short bf16x8;
typedef __attribute__((ext_vector_type(4))) float f32x4;

__device__ __forceinline__ float bfbits2f(u16 u) {
  union { unsigned int i; float f; } x; x.i = ((unsigned int)u) << 16; return x.f;
}
__device__ __forceinline__ u16 f2bfbits(float f) {
  union { float f; unsigned int i; } x; x.f = f;
  unsigned int r = x.i + 0x7fffu + ((x.i >> 16) & 1u);
  return (u16)(r >> 16);
}
__device__ __forceinline__ void unpack8(const uint4 v, float* f) {
  f[0] = bfbits2f((u16)(v.x & 0xffff)); f[1] = bfbits2f((u16)(v.x >> 16));
  f[2] = bfbits2f((u16)(v.y & 0xffff)); f[3] = bfbits2f((u16)(v.y >> 16));
  f[4] = bfbits2f((u16)(v.z & 0xffff)); f[5] = bfbits2f((u16)(v.z >> 16));
  f[6] = bfbits2f((u16)(v.w & 0xffff)); f[7] = bfbits2f((u16)(v.w >> 16));
}

// ---------------- agent pooling + agent vectors ----------------
__global__ __launch_bounds__(256) void k_agent(const float* __restrict__ g,
                                               const float* __restrict__ q_w,
                                               const float* __restrict__ q_b,
                                               float* __restrict__ agent_buf) {
  const int b = blockIdx.x;
  const int t = threadIdx.x;
  __shared__ float red[256];
  __shared__ float gb[16];
  const int ag = t >> 4, sub = t & 15;
  const int p1 = ag >> 2, p2 = ag & 3;
  const int y = p1 * 16 + sub, x0 = p2 * 16;
  const float* gp = g + (size_t)b * NPOS + y * WW + x0;
  float s = 0.f;
#pragma unroll
  for (int i = 0; i < 16; ++i) s += gp[i];
  red[t] = s;
  __syncthreads();
  if (sub == 0) {
    float tot = 0.f;
    for (int i = 0; i < 16; ++i) tot += red[(ag << 4) + i];
    gb[ag] = tot * (1.0f / 256.0f);
  }
  __syncthreads();
  for (int idx = t; idx < NA * C_; idx += 256) {
    const int a = idx >> 8, ci = idx & 255;
    const int h = ci >> 5, d = ci & 31;
    agent_buf[(((size_t)b * NH + h) * NA + a) * HD + d] = gb[a] * q_w[ci] + q_b[ci];
  }
}

// ---------------- w~ = SCALE * (W_K agent), + kv_b-dot constant ----------------
__global__ __launch_bounds__(256) void k_wtilde(const u16* __restrict__ Wkt, const float* __restrict__ kv_b,
                                                const float* __restrict__ agent_buf,
                                                u16* __restrict__ wt, float* __restrict__ kvbD) {
  const int h = blockIdx.x, b = blockIdx.y;
  const int t = threadIdx.x;
  __shared__ u16 Wk[32 * 256];
  __shared__ float ags[16][32];
#pragma unroll
  for (int i = 0; i < 4; ++i) {
    const int idx = t + 256 * i;
    const int r = idx >> 5, sl = idx & 31;
    *(uint4*)(Wk + r * 256 + sl * 8) = *(const uint4*)(Wkt + (size_t)(h * 32 + r) * C_ + sl * 8);
  }
#pragma unroll
  for (int i = 0; i < 2; ++i) {
    const int idx = t + 256 * i;
    const int a = idx >> 5, d = idx & 31;
    ags[a][d] = agent_buf[(((size_t)b * NH + h) * NA + a) * HD + d] * SCALE;
  }
  __syncthreads();
  const int a = t >> 4, cb = (t & 15) * 16;
  float o[16];
#pragma unroll
  for (int k = 0; k < 16; ++k) o[k] = 0.f;
  for (int d = 0; d < 32; ++d) {
    const float av = ags[a][d];
#pragma unroll
    for (int k = 0; k < 16; ++k) o[k] += av * bfbits2f(Wk[d * 256 + cb + k]);
  }
  unsigned int w[8];
#pragma unroll
  for (int q = 0; q < 8; ++q)
    w[q] = (unsigned int)f2bfbits(o[2 * q]) | ((unsigned int)f2bfbits(o[2 * q + 1]) << 16);
  u16* op = wt + ((size_t)(b * NHA + h * 16 + a)) * C_ + cb;
  *(uint4*)op = make_uint4(w[0], w[1], w[2], w[3]);
  *(uint4*)(op + 8) = make_uint4(w[4], w[5], w[6], w[7]);
  if ((t & 15) == 0) {
    float s = 0.f;
#pragma unroll
    for (int d = 0; d < 32; ++d) s += ags[a][d] * kv_b[h * 32 + d];
    kvbD[b * NHA + h * 16 + a] = s;
  }
}

// ---------------- biases: posbT (pos, ha) f32 only ----------------
__global__ __launch_bounds__(256) void k_bias(const float* __restrict__ an_b,
                                              const float* __restrict__ ah_b, const float* __restrict__ aw_b,
                                              float* __restrict__ posbT) {
  const int idx = blockIdx.x * 256 + threadIdx.x;  // total 128*4096
  const int ha = idx & 127;
  const int pos = idx >> 7;
  const int h = ha >> 4, a = ha & 15;
  const int y = pos >> 6, x = pos & 63;
  const float sy = (y + 0.5f) * 0.0625f - 0.5f;
  const float sx = (x + 0.5f) * 0.0625f - 0.5f;
  const int y0 = (int)floorf(sy);
  const int x0 = (int)floorf(sx);
  const float wy = sy - (float)y0, wx = sx - (float)x0;
  const int y0c = min(max(y0, 0), 3), y1c = min(max(y0 + 1, 0), 3);
  const int x0c = min(max(x0, 0), 3), x1c = min(max(x0 + 1, 0), 3);
  const float* an4 = an_b + ((size_t)h * NA + a) * 16;
  const float pa_ = (1.f - wy) * ((1.f - wx) * an4[y0c * 4 + x0c] + wx * an4[y0c * 4 + x1c]) +
                    wy * ((1.f - wx) * an4[y1c * 4 + x0c] + wx * an4[y1c * 4 + x1c]);
  posbT[(size_t)pos * NHA + ha] = pa_ + ah_b[((size_t)h * NA + a) * HH + y] + aw_b[((size_t)h * NA + a) * WW + x];
}

// ---------------- transpose+convert inputs: in (b,c,n) f32 -> At (b,n,c) bf16 ----------------
__global__ __launch_bounds__(256) void k_prep_in(const float* __restrict__ in1, const float* __restrict__ in2,
                                                 u16* __restrict__ At1, u16* __restrict__ At2) {
  const int z = blockIdx.z;
  const int src = z >> 3, b = z & 7;
  const float* in = src ? in2 : in1;
  u16* At = src ? At2 : At1;
  const int pos0 = blockIdx.x * 64;
  const int ci0 = blockIdx.y * 64;
  __shared__ float tile[64][68];
  const int t = threadIdx.x;
  const int rpos = (t & 15) << 2, rci = t >> 4;
#pragma unroll
  for (int i = 0; i < 4; ++i) {
    const int ci_l = rci + 16 * i;
    const float4 v = *(const float4*)(in + ((size_t)b * C_ + ci0 + ci_l) * NPOS + pos0 + rpos);
    tile[ci_l][rpos + 0] = v.x; tile[ci_l][rpos + 1] = v.y;
    tile[ci_l][rpos + 2] = v.z; tile[ci_l][rpos + 3] = v.w;
  }
  __syncthreads();
#pragma unroll
  for (int i = 0; i < 2; ++i) {
    const int u = t + 256 * i;
    const int p = u >> 3, s = u & 7;
    unsigned int w[4];
#pragma unroll
    for (int q = 0; q < 4; ++q) {
      const u16 lo = f2bfbits(tile[s * 8 + 2 * q][p]);
      const u16 hi = f2bfbits(tile[s * 8 + 2 * q + 1][p]);
      w[q] = (unsigned int)lo | ((unsigned int)hi << 16);
    }
    *(uint4*)(At + ((size_t)(pos0 + p)) * C_ + (size_t)b * NPOS * C_ + ci0 + s * 8) =
        make_uint4(w[0], w[1], w[2], w[3]);
  }
}

// ---------------- transpose+convert weights ----------------
__global__ __launch_bounds__(256) void k_prep_w(const float* __restrict__ kv_w, const float* __restrict__ proj_w,
                                                u16* __restrict__ Wkt, u16* __restrict__ Pwt) {
  const int x = blockIdx.x;
  const float* W; u16* T; int j0, ci0, ncols;
  if (x < 32) { W = kv_w;  T = Wkt; j0 = (x & 7) * 64; ci0 = (x >> 3) * 64; ncols = 512; }
  else        { W = proj_w; T = Pwt; j0 = ((x - 32) & 3) * 64; ci0 = ((x - 32) >> 2) * 64; ncols = 256; }
  __shared__ float tile[64][68];
  const int t = threadIdx.x;
  const int rj = (t & 15) << 2, rci = t >> 4;
#pragma unroll
  for (int i = 0; i < 4; ++i) {
    const int ci_l = rci + 16 * i;
    const float4 v = *(const float4*)(W + (size_t)(ci0 + ci_l) * ncols + j0 + rj);
    tile[ci_l][rj + 0] = v.x; tile[ci_l][rj + 1] = v.y;
    tile[ci_l][rj + 2] = v.z; tile[ci_l][rj + 3] = v.w;
  }
  __syncthreads();
#pragma unroll
  for (int i = 0; i < 2; ++i) {
    const int u = t + 256 * i;
    const int p = u >> 3, s = u & 7;
    unsigned int w[4];
#pragma unroll
    for (int q = 0; q < 4; ++q) {
      const u16 lo = f2bfbits(tile[s * 8 + 2 * q][p]);
      const u16 hi = f2bfbits(tile[s * 8 + 2 * q + 1][p]);
      w[q] = (unsigned int)lo | ((unsigned int)hi << 16);
    }
    *(uint4*)(T + (size_t)(j0 + p) * C_ + ci0 + s * 8) = make_uint4(w[0], w[1], w[2], w[3]);
  }
}

// ---------------- dwconv weight transpose: dwcT[q][ci], q=0..8 taps, q=9 bias ----------------
__global__ __launch_bounds__(256) void k_prep_dwc(const float* __restrict__ dwc_w, const float* __restrict__ dwc_b,
                                                  float* __restrict__ dwcT) {
  const int ci = threadIdx.x;
#pragma unroll
  for (int q = 0; q < 9; ++q) dwcT[q * 256 + ci] = dwc_w[ci * 9 + q];
  dwcT[9 * 256 + ci] = dwc_b[ci];
}

// ---------------- V projection only: V[b,pos,256] = At @ Wv + bv ----------------
__global__ __launch_bounds__(256) void k_v_mfma(const u16* __restrict__ At1, const u16* __restrict__ At2,
                                                const u16* __restrict__ Wkt, const float* __restrict__ kv_b,
                                                u16* __restrict__ v1, u16* __restrict__ v2) {
  const int z = blockIdx.z;
  const int src = z >> 3, b = z & 7;
  const u16* At = src ? At2 : At1;
  u16* vout = src ? v2 : v1;
  const int pos0 = blockIdx.x * 128;
  const int j0 = blockIdx.y * 128;

  __shared__ __align__(16) u16 SM[16384];
  u16* Ab = SM;
  u16* Bb = SM + 8192;

  const int t = threadIdx.x;
  const int wave = t >> 6, lane = t & 63;
  const int wm = wave >> 1, wn = wave & 1;
  const int g = lane >> 4;

  const u16* Ag = Wkt + (size_t)(256 + j0) * C_;
  const u16* Bg = At + ((size_t)b * NPOS + pos0) * C_;

  f32x4 acc[4][4];
#pragma unroll
  for (int m = 0; m < 4; ++m)
#pragma unroll
    for (int n = 0; n < 4; ++n) { acc[m][n][0]=0.f; acc[m][n][1]=0.f; acc[m][n][2]=0.f; acc[m][n][3]=0.f; }

  uint4 ra[4], rb[4];
#define V_LOAD(KT)                                                         \
  _Pragma("unroll") for (int i = 0; i < 4; ++i) {                          \
    const int u = t + 256 * i, rr = u >> 3, ss = u & 7;                    \
    ra[i] = *(const uint4*)(Ag + (size_t)rr * C_ + (KT) * 64 + ss * 8);    \
    rb[i] = *(const uint4*)(Bg + (size_t)rr * C_ + (KT) * 64 + ss * 8);    \
  }
#define V_WRITE()                                                          \
  _Pragma("unroll") for (int i = 0; i < 4; ++i) {                          \
    const int u = t + 256 * i, rr = u >> 3, ss = u & 7;                    \
    const int sw = ((ss ^ (rr & 7)) << 3);                                 \
    *(uint4*)(Ab + rr * 64 + sw) = ra[i];                                  \
    *(uint4*)(Bb + rr * 64 + sw) = rb[i];                                  \
  }

  V_LOAD(0);
  V_WRITE();
  V_LOAD(1);
  __syncthreads();

  for (int kt = 0; kt < 4; ++kt) {
#pragma unroll
    for (int kk = 0; kk < 2; ++kk) {
      bf16x8 af[4], bfr[4];
#pragma unroll
      for (int m = 0; m < 4; ++m) {
        const int r = wm * 64 + m * 16 + (lane & 15);
        af[m] = *(const bf16x8*)(Ab + r * 64 + (((kk * 4 + g) ^ (r & 7)) << 3));
      }
#pragma unroll
      for (int n = 0; n < 4; ++n) {
        const int c = wn * 64 + n * 16 + (lane & 15);
        bfr[n] = *(const bf16x8*)(Bb + c * 64 + (((kk * 4 + g) ^ (c & 7)) << 3));
      }
#pragma unroll
      for (int m = 0; m < 4; ++m)
#pragma unroll
        for (int n = 0; n < 4; ++n)
          acc[m][n] = __builtin_amdgcn_mfma_f32_16x16x32_bf16(af[m], bfr[n], acc[m][n], 0, 0, 0);
    }
    if (kt < 3) {
      __syncthreads();
      V_WRITE();
      if (kt < 2) V_LOAD(kt + 2);
      __syncthreads();
    }
  }
#undef V_LOAD
#undef V_WRITE

  __syncthreads();
#pragma unroll
  for (int m = 0; m < 4; ++m) {
    const int jl = wm * 64 + m * 16 + (lane >> 4) * 4;
    const float4 bv = *(const float4*)(kv_b + 256 + j0 + jl);
#pragma unroll
    for (int n = 0; n < 4; ++n) {
      const int pos_l = wn * 64 + n * 16 + (lane & 15);
      const f32x4 a = acc[m][n];
      ushort4 st;
      st.x = f2bfbits(a[0] + bv.x); st.y = f2bfbits(a[1] + bv.y);
      st.z = f2bfbits(a[2] + bv.z); st.w = f2bfbits(a[3] + bv.w);
      const int slot = (jl >> 3) ^ (pos_l & 7);
      *(ushort4*)(SM + pos_l * 128 + slot * 8 + (jl & 7)) = st;
    }
  }
  __syncthreads();
#pragma unroll
  for (int i = 0; i < 8; ++i) {
    const int idx = t + 256 * i;
    const int row = idx >> 4, sl = idx & 15;
    const uint4 v = *(const uint4*)(SM + row * 128 + ((sl ^ (row & 7)) << 3));
    *(uint4*)(vout + ((size_t)b * NPOS + pos0 + row) * C_ + j0 + sl * 8) = v;
  }
}

// ---------------- score GEMM: E[sb,ha,pos] = exp(At @ wt^T + posbT + kvbD) bf16, + row sums ----------------
__global__ __launch_bounds__(256) void k_score(const u16* __restrict__ At1, const u16* __restrict__ At2,
                                               const u16* __restrict__ wt, const float* __restrict__ posbT,
                                               const float* __restrict__ kvbD,
                                               u16* __restrict__ E, float* __restrict__ lsumP) {
  const int z = blockIdx.z;
  const int src = z >> 3, b = z & 7;
  const int sb = src * 8 + b;
  const u16* At = src ? At2 : At1;
  const int pos0 = blockIdx.x * 128;

  __shared__ __align__(16) u16 SM[16384];
  __shared__ float lsum_sm[2][128];
  u16* Ab = SM;
  u16* Bb = SM + 8192;

  const int t = threadIdx.x;
  const int wave = t >> 6, lane = t & 63;
  const int wm = wave >> 1, wn = wave & 1;
  const int g = lane >> 4;

  const u16* Ag = At + ((size_t)b * NPOS + pos0) * C_;
  const u16* Bg = wt + (size_t)b * NHA * C_;

  f32x4 acc[4][4];
#pragma unroll
  for (int m = 0; m < 4; ++m)
#pragma unroll
    for (int n = 0; n < 4; ++n) { acc[m][n][0]=0.f; acc[m][n][1]=0.f; acc[m][n][2]=0.f; acc[m][n][3]=0.f; }

  uint4 ra[4], rb[4];
#define S_LOAD(KT)                                                         \
  _Pragma("unroll") for (int i = 0; i < 4; ++i) {                          \
    const int u = t + 256 * i, rr = u >> 3, ss = u & 7;                    \
    ra[i] = *(const uint4*)(Ag + (size_t)rr * C_ + (KT) * 64 + ss * 8);    \
    rb[i] = *(const uint4*)(Bg + (size_t)rr * C_ + (KT) * 64 + ss * 8);    \
  }
#define S_WRITE()                                                          \
  _Pragma("unroll") for (int i = 0; i < 4; ++i) {                          \
    const int u = t + 256 * i, rr = u >> 3, ss = u & 7;                    \
    const int sw = ((ss ^ (rr & 7)) << 3);                                 \
    *(uint4*)(Ab + rr * 64 + sw) = ra[i];                                  \
    *(uint4*)(Bb + rr * 64 + sw) = rb[i];                                  \
  }

  S_LOAD(0);
  S_WRITE();
  S_LOAD(1);
  __syncthreads();

  for (int kt = 0; kt < 4; ++kt) {
#pragma unroll
    for (int kk = 0; kk < 2; ++kk) {
      bf16x8 af[4], bfr[4];
#pragma unroll
      for (int m = 0; m < 4; ++m) {
        const int r = wm * 64 + m * 16 + (lane & 15);
        af[m] = *(const bf16x8*)(Ab + r * 64 + (((kk * 4 + g) ^ (r & 7)) << 3));
      }
#pragma unroll
      for (int n = 0; n < 4; ++n) {
        const int c = wn * 64 + n * 16 + (lane & 15);
        bfr[n] = *(const bf16x8*)(Bb + c * 64 + (((kk * 4 + g) ^ (c & 7)) << 3));
      }
#pragma unroll
      for (int m = 0; m < 4; ++m)
#pragma unroll
        for (int n = 0; n < 4; ++n)
          acc[m][n] = __builtin_amdgcn_mfma_f32_16x16x32_bf16(af[m], bfr[n], acc[m][n], 0, 0, 0);
    }
    if (kt < 3) {
      __syncthreads();
      S_WRITE();
      if (kt < 2) S_LOAD(kt + 2);
      __syncthreads();
    }
  }
#undef S_LOAD
#undef S_WRITE

  __syncthreads();
  float ls[4] = {0.f, 0.f, 0.f, 0.f};
#pragma unroll
  for (int n = 0; n < 4; ++n) {
    const int ha_l = wn * 64 + n * 16 + (lane & 15);
    const float kb = kvbD[b * NHA + ha_l];
#pragma unroll
    for (int m = 0; m < 4; ++m) {
      const int pos_l = wm * 64 + m * 16 + (lane >> 4) * 4;
      float e[4];
#pragma unroll
      for (int j = 0; j < 4; ++j) {
        const float s = acc[m][n][j] + posbT[(size_t)(pos0 + pos_l + j) * NHA + ha_l] + kb;
        e[j] = __expf(s);
        ls[n] += e[j];
      }
      ushort4 st;
      st.x = f2bfbits(e[0]); st.y = f2bfbits(e[1]); st.z = f2bfbits(e[2]); st.w = f2bfbits(e[3]);
      const int sw = (pos_l >> 3) ^ (ha_l & 15);
      *(ushort4*)(SM + ha_l * 128 + sw * 8 + (pos_l & 7)) = st;
    }
  }
#pragma unroll
  for (int n = 0; n < 4; ++n) {
    float v = ls[n];
    v += __shfl_xor(v, 16);
    v += __shfl_xor(v, 32);
    ls[n] = v;
  }
  if (lane < 16) {
#pragma unroll
    for (int n = 0; n < 4; ++n) lsum_sm[wm][wn * 64 + n * 16 + lane] = ls[n];
  }
  __syncthreads();
  if (t < 128)
    lsumP[((size_t)sb * 32 + blockIdx.x) * NHA + t] = lsum_sm[0][t] + lsum_sm[1][t];
#pragma unroll
  for (int i = 0; i < 8; ++i) {
    const int idx = t + 256 * i;
    const int row = idx >> 4, sl = idx & 15;
    const uint4 v = *(const uint4*)(SM + row * 128 + ((sl ^ (row & 15)) << 3));
    *(uint4*)(E + ((size_t)sb * NHA + row) * NPOS + pos0 + sl * 8) = v;
  }
}

// ---------------- PV GEMM: T_p[sb,kc,ha,ci] = sum_pos in[ci,pos] * E[ha,pos] ----------------
__global__ __launch_bounds__(256) void k_pv(const float* __restrict__ in1, const float* __restrict__ in2,
                                            const u16* __restrict__ E, float* __restrict__ T_p) {
  const int kc = blockIdx.x;
  const int ci0 = blockIdx.y * 128;
  const int sb = blockIdx.z;
  const int src = sb >> 3, b = sb & 7;
  const float* in = src ? in2 : in1;
  const int kpos0 = kc * 512;

  __shared__ __align__(16) u16 As[8192];
  __shared__ __align__(16) u16 Bs[8192];

  const int t = threadIdx.x;
  const int wave = t >> 6, lane = t & 63;
  const int wm = wave >> 1, wn = wave & 1;
  const int g = lane >> 4;

  const float* Ain = in + (size_t)b * C_ * NPOS;
  const u16* Eg = E + (size_t)sb * NHA * NPOS;

  f32x4 acc[4][4];
#pragma unroll
  for (int m = 0; m < 4; ++m)
#pragma unroll
    for (int n = 0; n < 4; ++n) { acc[m][n][0]=0.f; acc[m][n][1]=0.f; acc[m][n][2]=0.f; acc[m][n][3]=0.f; }

  float4 pa[8];
  uint4 pb[4];
#define PV_LOAD(KT)                                                            \
  _Pragma("unroll") for (int i = 0; i < 8; ++i) {                              \
    const int idx = t + 256 * i, rr = idx >> 4, fq = idx & 15;                 \
    pa[i] = *(const float4*)(Ain + (size_t)(ci0 + rr) * NPOS + kpos0 + (KT) * 64 + fq * 4); \
  }                                                                            \
  _Pragma("unroll") for (int i = 0; i < 4; ++i) {                              \
    const int idx = t + 256 * i, rr = idx >> 3, ss = idx & 7;                  \
    pb[i] = *(const uint4*)(Eg + (size_t)rr * NPOS + kpos0 + (KT) * 64 + ss * 8); \
  }
#define PV_WRITE()                                                             \
  _Pragma("unroll") for (int i = 0; i < 8; ++i) {                              \
    const int idx = t + 256 * i, rr = idx >> 4, fq = idx & 15;                 \
    ushort4 st;                                                                \
    st.x = f2bfbits(pa[i].x); st.y = f2bfbits(pa[i].y);                        \
    st.z = f2bfbits(pa[i].z); st.w = f2bfbits(pa[i].w);                        \
    const int sw = ((fq >> 1) ^ (rr & 7));                                     \
    *(ushort4*)(As + rr * 64 + sw * 8 + (fq & 1) * 4) = st;                    \
  }                                                                            \
  _Pragma("unroll") for (int i = 0; i < 4; ++i) {                              \
    const int idx = t + 256 * i, rr = idx >> 3, ss = idx & 7;                  \
    *(uint4*)(Bs + rr * 64 + ((ss ^ (rr & 7)) << 3)) = pb[i];                  \
  }

  PV_LOAD(0);
  PV_WRITE();
  PV_LOAD(1);
  __syncthreads();

  for (int kt = 0; kt < 8; ++kt) {
#pragma unroll
    for (int kk = 0; kk < 2; ++kk) {
      bf16x8 af[4], bfr[4];
#pragma unroll
      for (int m = 0; m < 4; ++m) {
        const int r = wm * 64 + m * 16 + (lane & 15);
        af[m] = *(const bf16x8*)(As + r * 64 + (((kk * 4 + g) ^ (r & 7)) << 3));
      }
#pragma unroll
      for (int n = 0; n < 4; ++n) {
        const int c = wn * 64 + n * 16 + (lane & 15);
        bfr[n] = *(const bf16x8*)(Bs + c * 64 + (((kk * 4 + g) ^ (c & 7)) << 3));
      }
#pragma unroll
      for (int m = 0; m < 4; ++m)
#pragma unroll
        for (int n = 0; n < 4; ++n)
          acc[m][n] = __builtin_amdgcn_mfma_f32_16x16x32_bf16(af[m], bfr[n], acc[m][n], 0, 0, 0);
    }
    if (kt < 7) {
      __syncthreads();
      PV_WRITE();
      if (kt < 6) PV_LOAD(kt + 2);
      __syncthreads();
    }
  }
#undef PV_LOAD
#undef PV_WRITE

#pragma unroll
  for (int m = 0; m < 4; ++m) {
    const int ci_l = wm * 64 + m * 16 + (lane >> 4) * 4;
#pragma unroll
    for (int n = 0; n < 4; ++n) {
      const int ha_l = wn * 64 + n * 16 + (lane & 15);
      const f32x4 a = acc[m][n];
      *(float4*)(T_p + (((size_t)sb * 8 + kc) * NHA + ha_l) * C_ + ci0 + ci_l) =
          make_float4(a[0], a[1], a[2], a[3]);
    }
  }
}

// ---------------- agent_v = (sum_kc T)/lsum @ Wv + bv ----------------
__global__ __launch_bounds__(256) void k_agentv(const float* __restrict__ T_p, const float* __restrict__ lsumP,
                                                const u16* __restrict__ Wkt, const float* __restrict__ kv_b,
                                                float* __restrict__ agent_v) {
  const int h = blockIdx.x, sb = blockIdx.y;
  const int t = threadIdx.x;
  __shared__ float Tred[16 * 256];
  __shared__ u16 Wv[32 * 256];
  __shared__ float lsum_s[16];
#pragma unroll
  for (int i = 0; i < 4; ++i) {
    const int idx = t + 256 * i;
    const int r = idx >> 5, sl = idx & 31;
    *(uint4*)(Wv + r * 256 + sl * 8) = *(const uint4*)(Wkt + (size_t)(256 + h * 32 + r) * C_ + sl * 8);
  }
#pragma unroll
  for (int i = 0; i < 16; ++i) {
    const int idx = t + 256 * i;
    const int a = idx >> 8, ci = idx & 255;
    float s = 0.f;
#pragma unroll
    for (int kc = 0; kc < 8; ++kc)
      s += T_p[(((size_t)sb * 8 + kc) * NHA + h * 16 + a) * C_ + ci];
    Tred[a * 256 + ci] = s;
  }
  if (t < 16) {
    float s = 0.f;
#pragma unroll
    for (int pt = 0; pt < 32; ++pt) s += lsumP[((size_t)sb * 32 + pt) * NHA + h * 16 + t];
    lsum_s[t] = s;
  }
  __syncthreads();
  const int a = t >> 4, dp = (t & 15) * 2;
  float o0 = 0.f, o1 = 0.f;
  const float* Tr = Tred + a * 256;
  for (int ci = 0; ci < 256; ++ci) {
    const float tv = Tr[ci];
    o0 += tv * bfbits2f(Wv[dp * 256 + ci]);
    o1 += tv * bfbits2f(Wv[(dp + 1) * 256 + ci]);
  }
  const float inv = 1.0f / lsum_s[a];
  float* op = agent_v + (size_t)sb * NHA * HD + (h * 16 + a) * HD + dp;
  op[0] = o0 * inv + kv_b[256 + h * 32 + dp];
  op[1] = o1 * inv + kv_b[256 + h * 32 + dp + 1];
}

// ---------------- query attention over 16 agents + inline agent-bias, bf16 outputs ----------------
__global__ __launch_bounds__(256) void k_qattn(const float* __restrict__ g,
                                               const float* __restrict__ q_w, const float* __restrict__ q_b,
                                               const float* __restrict__ agent_buf,
                                               const float* __restrict__ agent_v,
                                               const float* __restrict__ na_b,
                                               const float* __restrict__ ha_b,
                                               const float* __restrict__ wa_b,
                                               u16* __restrict__ o1s, u16* __restrict__ o2s) {
  const int h = blockIdx.y, b = blockIdx.z;
  const int t = threadIdx.x;
  const int pos = blockIdx.x * 256 + t;
  __shared__ float dotW[16], dotB[16];
  __shared__ float av1[16][32], av2[16][32];
  for (int idx = t; idx < 512; idx += 256) {
    const int a = idx >> 5, d = idx & 31;
    av1[a][d] = agent_v[(size_t)b * NHA * HD + (h * 16 + a) * HD + d];
    av2[a][d] = agent_v[(size_t)(8 + b) * NHA * HD + (h * 16 + a) * HD + d];
  }
  if (t < 16) {
    float dw = 0.f, db = 0.f;
    const float* agp = agent_buf + (((size_t)b * NH + h) * NA + t) * HD;
#pragma unroll
    for (int d = 0; d < HD; ++d) {
      const float ad = agp[d];
      dw += ad * q_w[h * HD + d];
      db += ad * q_b[h * HD + d];
    }
    dotW[t] = dw * SCALE;
    dotB[t] = db * SCALE;
  }
  __syncthreads();
  // inline agent bias: bilinear(na_b) + ha_b + wa_b
  const int y = pos >> 6, x = pos & 63;
  const float sy = (y + 0.5f) * 0.0625f - 0.5f;
  const float sx = (x + 0.5f) * 0.0625f - 0.5f;
  const int y0 = (int)floorf(sy);
  const int x0 = (int)floorf(sx);
  const float wy = sy - (float)y0, wx = sx - (float)x0;
  const int y0c = min(max(y0, 0), 3), y1c = min(max(y0 + 1, 0), 3);
  const int x0c = min(max(x0, 0), 3), x1c = min(max(x0 + 1, 0), 3);
  const float c00 = (1.f - wy) * (1.f - wx), c01 = (1.f - wy) * wx;
  const float c10 = wy * (1.f - wx), c11 = wy * wx;
  const int i00 = y0c * 4 + x0c, i01 = y0c * 4 + x1c;
  const int i10 = y1c * 4 + x0c, i11 = y1c * 4 + x1c;
  float hav[16], wav[16];
  {
    const float* hp = ha_b + ((size_t)h * HH + y) * NA;
    const float* wp = wa_b + ((size_t)h * WW + x) * NA;
#pragma unroll
    for (int q = 0; q < 4; ++q) {
      *(float4*)(hav + 4 * q) = *(const float4*)(hp + 4 * q);
      *(float4*)(wav + 4 * q) = *(const float4*)(wp + 4 * q);
    }
  }
  const float gv = g[(size_t)b * NPOS + pos];
  float s[16];
  float m = -1e30f;
#pragma unroll
  for (int a = 0; a < 16; ++a) {
    const float* na4 = na_b + ((size_t)h * NA + a) * 16;
    const float nv = c00 * na4[i00] + c01 * na4[i01] + c10 * na4[i10] + c11 * na4[i11];
    s[a] = gv * dotW[a] + dotB[a] + nv + hav[a] + wav[a];
    m = fmaxf(m, s[a]);
  }
  float l = 0.f;
#pragma unroll
  for (int a = 0; a < 16; ++a) {
    s[a] = __expf(s[a] - m);
    l += s[a];
  }
  const float inv = 1.0f / l;
  float o1[32] = {}, o2[32] = {};
#pragma unroll
  for (int a = 0; a < 16; ++a) {
    const float pa = s[a] * inv;
#pragma unroll
    for (int d = 0; d < 32; ++d) {
      o1[d] += pa * av1[a][d];
      o2[d] += pa * av2[a][d];
    }
  }
  u16* o1p = o1s + ((size_t)b * NPOS + pos) * C_ + h * HD;
  u16* o2p = o2s + ((size_t)b * NPOS + pos) * C_ + h * HD;
#pragma unroll
  for (int blk = 0; blk < 4; ++blk) {
    unsigned int w1[4], w2[4];
#pragma unroll
    for (int q = 0; q < 4; ++q) {
      w1[q] = (unsigned int)f2bfbits(o1[blk * 8 + 2 * q]) | ((unsigned int)f2bfbits(o1[blk * 8 + 2 * q + 1]) << 16);
      w2[q] = (unsigned int)f2bfbits(o2[blk * 8 + 2 * q]) | ((unsigned int)f2bfbits(o2[blk * 8 + 2 * q + 1]) << 16);
    }
    *(uint4*)(o1p + blk * 8) = make_uint4(w1[0], w1[1], w1[2], w1[3]);
    *(uint4*)(o2p + blk * 8) = make_uint4(w2[0], w2[1], w2[2], w2[3]);
  }
}

// ---------------- depthwise 3x3 conv v2: 8ch/thread vectorized, RMW o1s/o2s ----------------
__global__ __launch_bounds__(256) void k_dwconv(const u16* __restrict__ v1, const u16* __restrict__ v2,
                                                const float* __restrict__ dwcT,
                                                u16* __restrict__ o1s, u16* __restrict__ o2s) {
  const u16* V = blockIdx.z ? v2 : v1;
  u16* out = blockIdx.z ? o2s : o1s;
  const int b = blockIdx.y;
  const int t = threadIdx.x;
  const int cg = t & 31;            // channel group (8 ch)
  const int ch = cg * 8;
  const int px = t >> 5;            // 0..7
  const int pos = (blockIdx.x << 3) + px;
  const int y = pos >> 6, x = pos & 63;

  float acc[8];
  {
    const float4 b0 = *(const float4*)(dwcT + 9 * 256 + ch);
    const float4 b1 = *(const float4*)(dwcT + 9 * 256 + ch + 4);
    acc[0] = b0.x; acc[1] = b0.y; acc[2] = b0.z; acc[3] = b0.w;
    acc[4] = b1.x; acc[5] = b1.y; acc[6] = b1.z; acc[7] = b1.w;
  }
  const u16* vb = V + (size_t)b * NPOS * C_ + ch;
#pragma unroll
  for (int dy = -1; dy <= 1; ++dy) {
    const int yy = y + dy;
    if (yy < 0 || yy > 63) continue;
#pragma unroll
    for (int dx = -1; dx <= 1; ++dx) {
      const int xx = x + dx;
      if (xx < 0 || xx > 63) continue;
      const int q = (dy + 1) * 3 + (dx + 1);
      const float4 w0 = *(const float4*)(dwcT + q * 256 + ch);
      const float4 w1 = *(const float4*)(dwcT + q * 256 + ch + 4);
      const uint4 vv = *(const uint4*)(vb + (size_t)(yy * 64 + xx) * C_);
      float f8[8];
      unpack8(vv, f8);
      acc[0] += w0.x * f8[0]; acc[1] += w0.y * f8[1];
      acc[2] += w0.z * f8[2]; acc[3] += w0.w * f8[3];
      acc[4] += w1.x * f8[4]; acc[5] += w1.y * f8[5];
      acc[6] += w1.z * f8[6]; acc[7] += w1.w * f8[7];
    }
  }
  u16* op = out + ((size_t)b * NPOS + pos) * C_ + ch;
  const uint4 ov = *(const uint4*)op;
  float f8[8];
  unpack8(ov, f8);
  unsigned int wo[4];
#pragma unroll
  for (int q2 = 0; q2 < 4; ++q2)
    wo[q2] = (unsigned int)f2bfbits(f8[2 * q2] + acc[2 * q2]) |
             ((unsigned int)f2bfbits(f8[2 * q2 + 1] + acc[2 * q2 + 1]) << 16);
  *(uint4*)op = make_uint4(wo[0], wo[1], wo[2], wo[3]);
}

// ---------------- output projection, bf16 MFMA -> (b,c,n) f32 + bias + residual ----------------
__global__ __launch_bounds__(256) void k_proj_mfma(const u16* __restrict__ o1s, const u16* __restrict__ o2s,
                                                   const u16* __restrict__ Pwt, const float* __restrict__ proj_b,
                                                   const float* __restrict__ in1, const float* __restrict__ in2,
                                                   float* __restrict__ out1, float* __restrict__ out2) {
  const int z = blockIdx.z;
  const int src = z >> 3, b = z & 7;
  const u16* S = src ? o2s : o1s;
  const float* inp = src ? in2 : in1;
  float* outp = src ? out2 : out1;
  const int pos0 = blockIdx.x * 128;
  const int co0 = blockIdx.y * 128;

  __shared__ __align__(16) u16 SM[16384];
  u16* Ab = SM;
  u16* Bb = SM + 8192;
  float* SMF = (float*)SM;

  const int t = threadIdx.x;
  const int wave = t >> 6, lane = t & 63;
  const int wm = wave >> 1, wn = wave & 1;
  const int g = lane >> 4;

  const u16* Ag = S + ((size_t)b * NPOS + pos0) * C_;
  const u16* Bg = Pwt + (size_t)co0 * C_;

  f32x4 acc[4][4];
#pragma unroll
  for (int m = 0; m < 4; ++m)
#pragma unroll
    for (int n = 0; n < 4; ++n) { acc[m][n][0]=0.f; acc[m][n][1]=0.f; acc[m][n][2]=0.f; acc[m][n][3]=0.f; }

  uint4 ra[4], rb[4];
#define PJ_LOAD(KT)                                                        \
  _Pragma("unroll") for (int i = 0; i < 4; ++i) {                          \
    const int u = t + 256 * i, rr = u >> 3, ss = u & 7;                    \
    ra[i] = *(const uint4*)(Ag + (size_t)rr * C_ + (KT) * 64 + ss * 8);    \
    rb[i] = *(const uint4*)(Bg + (size_t)rr * C_ + (KT) * 64 + ss * 8);    \
  }
#define PJ_WRITE()                                                         \
  _Pragma("unroll") for (int i = 0; i < 4; ++i) {                          \
    const int u = t + 256 * i, rr = u >> 3, ss = u & 7;                    \
    const int sw = ((ss ^ (rr & 7)) << 3);                                 \
    *(uint4*)(Ab + rr * 64 + sw) = ra[i];                                  \
    *(uint4*)(Bb + rr * 64 + sw) = rb[i];                                  \
  }

  PJ_LOAD(0);
  PJ_WRITE();
  PJ_LOAD(1);
  __syncthreads();

  for (int kt = 0; kt < 4; ++kt) {
#pragma unroll
    for (int kk = 0; kk < 2; ++kk) {
      bf16x8 af[4], bfr[4];
#pragma unroll
      for (int m = 0; m < 4; ++m) {
        const int r = wm * 64 + m * 16 + (lane & 15);
        af[m] = *(const bf16x8*)(Ab + r * 64 + (((kk * 4 + g) ^ (r & 7)) << 3));
      }
#pragma unroll
      for (int n = 0; n < 4; ++n) {
        const int c = wn * 64 + n * 16 + (lane & 15);
        bfr[n] = *(const bf16x8*)(Bb + c * 64 + (((kk * 4 + g) ^ (c & 7)) << 3));
      }
#pragma unroll
      for (int m = 0; m < 4; ++m)
#pragma unroll
        for (int n = 0; n < 4; ++n)
          acc[m][n] = __builtin_amdgcn_mfma_f32_16x16x32_bf16(af[m], bfr[n], acc[m][n], 0, 0, 0);
    }
    if (kt < 3) {
      __syncthreads();
      PJ_WRITE();
      if (kt < 2) PJ_LOAD(kt + 2);
      __syncthreads();
    }
  }
#undef PJ_LOAD
#undef PJ_WRITE

#pragma unroll
  for (int hf = 0; hf < 2; ++hf) {
    __syncthreads();
    if (wn == hf) {
#pragma unroll
      for (int n = 0; n < 4; ++n) {
        const int co_l = n * 16 + (lane & 15);
#pragma unroll
        for (int m = 0; m < 4; ++m) {
          const int pos_l = wm * 64 + m * 16 + (lane >> 4) * 4;
          const int slot = (pos_l >> 2) ^ (co_l & 7);
          const f32x4 a = acc[m][n];
          *(float4*)(SMF + co_l * 128 + slot * 4) = make_float4(a[0], a[1], a[2], a[3]);
        }
      }
    }
    __syncthreads();
#pragma unroll
    for (int i = 0; i < 8; ++i) {
      const int idx = t + 256 * i;
      const int row = idx >> 5, sl = idx & 31;
      const float4 v = *(const float4*)(SMF + row * 128 + ((sl ^ (row & 7)) << 2));
      const int co = co0 + hf * 64 + row;
      const float pb = proj_b[co];
      const size_t base = ((size_t)b * C_ + co) * NPOS + pos0 + sl * 4;
      const float4 res = *(const float4*)(inp + base);
      *(float4*)(outp + base) = make_float4(v.x + pb + res.x, v.y + pb + res.y,
                                            v.z + pb + res.z, v.w + pb + res.w);
    }
  }
}

extern "C" void kernel_launch(void* const* d_in, const int* in_sizes, int n_in,
                              void* d_out, int out_size, void* d_ws, size_t ws_size,
                              hipStream_t stream) {
  const float* input1 = (const float*)d_in[0];
  const float* input2 = (const float*)d_in[1];
  const float* guid   = (const float*)d_in[2];
  const float* kv_w   = (const float*)d_in[3];
  const float* kv_b   = (const float*)d_in[4];
  const float* q_w    = (const float*)d_in[5];
  const float* q_b    = (const float*)d_in[6];
  const float* proj_w = (const float*)d_in[7];
  const float* proj_b = (const float*)d_in[8];
  const float* dwc_w  = (const float*)d_in[9];
  const float* dwc_b  = (const float*)d_in[10];
  const float* an_b   = (const float*)d_in[11];
  const float* na_b   = (const float*)d_in[12];
  const float* ah_b   = (const float*)d_in[13];
  const float* aw_b   = (const float*)d_in[14];
  const float* ha_b   = (const float*)d_in[15];
  const float* wa_b   = (const float*)d_in[16];

  char* W = (char*)d_ws;
  u16* At1 = (u16*)W;        W += (size_t)B_ * NPOS * C_ * 2;
  u16* At2 = (u16*)W;        W += (size_t)B_ * NPOS * C_ * 2;
  u16* v1  = (u16*)W;        W += (size_t)B_ * NPOS * C_ * 2;
  u16* v2  = (u16*)W;        W += (size_t)B_ * NPOS * C_ * 2;
  u16* o1s = (u16*)W;        W += (size_t)B_ * NPOS * C_ * 2;
  u16* o2s = (u16*)W;        W += (size_t)B_ * NPOS * C_ * 2;
  u16* E   = (u16*)W;        W += (size_t)16 * NHA * NPOS * 2;
  float* T_p = (float*)W;    W += (size_t)16 * 8 * NHA * C_ * 4;
  u16* Wkt = (u16*)W;        W += (size_t)512 * C_ * 2;
  u16* Pwt = (u16*)W;        W += (size_t)C_ * C_ * 2;
  u16* wt  = (u16*)W;        W += (size_t)B_ * NHA * C_ * 2;
  float* posbT = (float*)W;  W += (size_t)NPOS * NHA * 4;
  float* agentb = (float*)W; W += (size_t)B_ * NH * NA * HD * 4;
  float* kvbD   = (float*)W; W += (size_t)B_ * NHA * 4;
  float* lsumP  = (float*)W; W += (size_t)16 * 32 * NHA * 4;
  float* agent_v = (float*)W; W += (size_t)16 * NHA * HD * 4;
  float* dwcT    = (float*)W; W += (size_t)10 * 256 * 4;

  float* out1 = (float*)d_out;
  float* out2 = out1 + (size_t)B_ * C_ * NPOS;

  hipLaunchKernelGGL(k_agent, dim3(B_), dim3(256), 0, stream, guid, q_w, q_b, agentb);
  hipLaunchKernelGGL(k_bias, dim3((NHA * NPOS) / 256), dim3(256), 0, stream,
                     an_b, ah_b, aw_b, posbT);
  hipLaunchKernelGGL(k_prep_w, dim3(48), dim3(256), 0, stream, kv_w, proj_w, Wkt, Pwt);
  hipLaunchKernelGGL(k_prep_dwc, dim3(1), dim3(256), 0, stream, dwc_w, dwc_b, dwcT);
  hipLaunchKernelGGL(k_wtilde, dim3(NH, B_), dim3(256), 0, stream, Wkt, kv_b, agentb, wt, kvbD);
  hipLaunchKernelGGL(k_prep_in, dim3(64, 4, 16), dim3(256), 0, stream, input1, input2, At1, At2);
  hipLaunchKernelGGL(k_v_mfma, dim3(32, 2, 16), dim3(256), 0, stream,
                     At1, At2, Wkt, kv_b, v1, v2);
  hipLaunchKernelGGL(k_score, dim3(32, 1, 16), dim3(256), 0, stream,
                     At1, At2, wt, posbT, kvbD, E, lsumP);
  hipLaunchKernelGGL(k_pv, dim3(8, 2, 16), dim3(256), 0, stream, input1, input2, E, T_p);
  hipLaunchKernelGGL(k_agentv, dim3(NH, 16), dim3(256), 0, stream, T_p, lsumP, Wkt, kv_b, agent_v);
  hipLaunchKernelGGL(k_qattn, dim3(NPOS / 256, NH, B_), dim3(256), 0, stream,
                     guid, q_w, q_b, agentb, agent_v, na_b, ha_b, wa_b, o1s, o2s);
  hipLaunchKernelGGL(k_dwconv, dim3(NPOS / 8, B_, 2), dim3(256), 0, stream,
                     v1, v2, dwcT, o1s, o2s);
  hipLaunchKernelGGL(k_proj_mfma, dim3(32, 2, 16), dim3(256), 0, stream,
                     o1s, o2s, Pwt, proj_b, input1, input2, out1, out2);
}

// Round 9
// 245.991 us; speedup vs baseline: 2.8768x; 1.1042x over previous
//
#include <hip/hip_runtime.h>
#include <hip/hip_bf16.h>
#include <cstddef>

#define B_   8
#define C_   256
#define HH   64
#define WW   64
#define NPOS 4096
#define NH   8
#define HD   32
#define NA   16
#define NHA  128      // NH*NA
#define SCALE 0.17677669529663687f

typedef unsigned short u16;
typedef __attribute__((ext_vector_type(8))) short bf16x8;
typedef __attribute__((ext_vector_type(4))) float f32x4;

__device__ __forceinline__ float bfbits2f(u16 u) {
  union { unsigned int i; float f; } x; x.i = ((unsigned int)u) << 16; return x.f;
}
__device__ __forceinline__ u16 f2bfbits(float f) {
  union { float f; unsigned int i; } x; x.f = f;
  unsigned int r = x.i + 0x7fffu + ((x.i >> 16) & 1u);
  return (u16)(r >> 16);
}
__device__ __forceinline__ void unpack8(const uint4 v, float* f) {
  f[0] = bfbits2f((u16)(v.x & 0xffff)); f[1] = bfbits2f((u16)(v.x >> 16));
  f[2] = bfbits2f((u16)(v.y & 0xffff)); f[3] = bfbits2f((u16)(v.y >> 16));
  f[4] = bfbits2f((u16)(v.z & 0xffff)); f[5] = bfbits2f((u16)(v.z >> 16));
  f[6] = bfbits2f((u16)(v.w & 0xffff)); f[7] = bfbits2f((u16)(v.w >> 16));
}

// ---------------- agent pooling + agent vectors ----------------
__global__ __launch_bounds__(256) void k_agent(const float* __restrict__ g,
                                               const float* __restrict__ q_w,
                                               const float* __restrict__ q_b,
                                               float* __restrict__ agent_buf) {
  const int b = blockIdx.x;
  const int t = threadIdx.x;
  __shared__ float red[256];
  __shared__ float gb[16];
  const int ag = t >> 4, sub = t & 15;
  const int p1 = ag >> 2, p2 = ag & 3;
  const int y = p1 * 16 + sub, x0 = p2 * 16;
  const float* gp = g + (size_t)b * NPOS + y * WW + x0;
  float s = 0.f;
#pragma unroll
  for (int i = 0; i < 16; ++i) s += gp[i];
  red[t] = s;
  __syncthreads();
  if (sub == 0) {
    float tot = 0.f;
    for (int i = 0; i < 16; ++i) tot += red[(ag << 4) + i];
    gb[ag] = tot * (1.0f / 256.0f);
  }
  __syncthreads();
  for (int idx = t; idx < NA * C_; idx += 256) {
    const int a = idx >> 8, ci = idx & 255;
    const int h = ci >> 5, d = ci & 31;
    agent_buf[(((size_t)b * NH + h) * NA + a) * HD + d] = gb[a] * q_w[ci] + q_b[ci];
  }
}

// ---------------- w~ = SCALE * (W_K agent), + kv_b-dot constant ----------------
__global__ __launch_bounds__(256) void k_wtilde(const u16* __restrict__ Wkt, const float* __restrict__ kv_b,
                                                const float* __restrict__ agent_buf,
                                                u16* __restrict__ wt, float* __restrict__ kvbD) {
  const int h = blockIdx.x, b = blockIdx.y;
  const int t = threadIdx.x;
  __shared__ u16 Wk[32 * 256];
  __shared__ float ags[16][32];
#pragma unroll
  for (int i = 0; i < 4; ++i) {
    const int idx = t + 256 * i;
    const int r = idx >> 5, sl = idx & 31;
    *(uint4*)(Wk + r * 256 + sl * 8) = *(const uint4*)(Wkt + (size_t)(h * 32 + r) * C_ + sl * 8);
  }
#pragma unroll
  for (int i = 0; i < 2; ++i) {
    const int idx = t + 256 * i;
    const int a = idx >> 5, d = idx & 31;
    ags[a][d] = agent_buf[(((size_t)b * NH + h) * NA + a) * HD + d] * SCALE;
  }
  __syncthreads();
  const int a = t >> 4, cb = (t & 15) * 16;
  float o[16];
#pragma unroll
  for (int k = 0; k < 16; ++k) o[k] = 0.f;
  for (int d = 0; d < 32; ++d) {
    const float av = ags[a][d];
#pragma unroll
    for (int k = 0; k < 16; ++k) o[k] += av * bfbits2f(Wk[d * 256 + cb + k]);
  }
  unsigned int w[8];
#pragma unroll
  for (int q = 0; q < 8; ++q)
    w[q] = (unsigned int)f2bfbits(o[2 * q]) | ((unsigned int)f2bfbits(o[2 * q + 1]) << 16);
  u16* op = wt + ((size_t)(b * NHA + h * 16 + a)) * C_ + cb;
  *(uint4*)op = make_uint4(w[0], w[1], w[2], w[3]);
  *(uint4*)(op + 8) = make_uint4(w[4], w[5], w[6], w[7]);
  if ((t & 15) == 0) {
    float s = 0.f;
#pragma unroll
    for (int d = 0; d < 32; ++d) s += ags[a][d] * kv_b[h * 32 + d];
    kvbD[b * NHA + h * 16 + a] = s;
  }
}

// ---------------- biases: posbT (pos, ha) f32 only ----------------
__global__ __launch_bounds__(256) void k_bias(const float* __restrict__ an_b,
                                              const float* __restrict__ ah_b, const float* __restrict__ aw_b,
                                              float* __restrict__ posbT) {
  const int idx = blockIdx.x * 256 + threadIdx.x;  // total 128*4096
  const int ha = idx & 127;
  const int pos = idx >> 7;
  const int h = ha >> 4, a = ha & 15;
  const int y = pos >> 6, x = pos & 63;
  const float sy = (y + 0.5f) * 0.0625f - 0.5f;
  const float sx = (x + 0.5f) * 0.0625f - 0.5f;
  const int y0 = (int)floorf(sy);
  const int x0 = (int)floorf(sx);
  const float wy = sy - (float)y0, wx = sx - (float)x0;
  const int y0c = min(max(y0, 0), 3), y1c = min(max(y0 + 1, 0), 3);
  const int x0c = min(max(x0, 0), 3), x1c = min(max(x0 + 1, 0), 3);
  const float* an4 = an_b + ((size_t)h * NA + a) * 16;
  const float pa_ = (1.f - wy) * ((1.f - wx) * an4[y0c * 4 + x0c] + wx * an4[y0c * 4 + x1c]) +
                    wy * ((1.f - wx) * an4[y1c * 4 + x0c] + wx * an4[y1c * 4 + x1c]);
  posbT[(size_t)pos * NHA + ha] = pa_ + ah_b[((size_t)h * NA + a) * HH + y] + aw_b[((size_t)h * NA + a) * WW + x];
}

// ---------------- transpose+convert inputs: in (b,c,n) f32 -> At (b,n,c) bf16 ----------------
__global__ __launch_bounds__(256) void k_prep_in(const float* __restrict__ in1, const float* __restrict__ in2,
                                                 u16* __restrict__ At1, u16* __restrict__ At2) {
  const int z = blockIdx.z;
  const int src = z >> 3, b = z & 7;
  const float* in = src ? in2 : in1;
  u16* At = src ? At2 : At1;
  const int pos0 = blockIdx.x * 64;
  const int ci0 = blockIdx.y * 64;
  __shared__ float tile[64][68];
  const int t = threadIdx.x;
  const int rpos = (t & 15) << 2, rci = t >> 4;
#pragma unroll
  for (int i = 0; i < 4; ++i) {
    const int ci_l = rci + 16 * i;
    const float4 v = *(const float4*)(in + ((size_t)b * C_ + ci0 + ci_l) * NPOS + pos0 + rpos);
    tile[ci_l][rpos + 0] = v.x; tile[ci_l][rpos + 1] = v.y;
    tile[ci_l][rpos + 2] = v.z; tile[ci_l][rpos + 3] = v.w;
  }
  __syncthreads();
#pragma unroll
  for (int i = 0; i < 2; ++i) {
    const int u = t + 256 * i;
    const int p = u >> 3, s = u & 7;
    unsigned int w[4];
#pragma unroll
    for (int q = 0; q < 4; ++q) {
      const u16 lo = f2bfbits(tile[s * 8 + 2 * q][p]);
      const u16 hi = f2bfbits(tile[s * 8 + 2 * q + 1][p]);
      w[q] = (unsigned int)lo | ((unsigned int)hi << 16);
    }
    *(uint4*)(At + ((size_t)(pos0 + p)) * C_ + (size_t)b * NPOS * C_ + ci0 + s * 8) =
        make_uint4(w[0], w[1], w[2], w[3]);
  }
}

// ---------------- transpose+convert weights ----------------
__global__ __launch_bounds__(256) void k_prep_w(const float* __restrict__ kv_w, const float* __restrict__ proj_w,
                                                u16* __restrict__ Wkt, u16* __restrict__ Pwt) {
  const int x = blockIdx.x;
  const float* W; u16* T; int j0, ci0, ncols;
  if (x < 32) { W = kv_w;  T = Wkt; j0 = (x & 7) * 64; ci0 = (x >> 3) * 64; ncols = 512; }
  else        { W = proj_w; T = Pwt; j0 = ((x - 32) & 3) * 64; ci0 = ((x - 32) >> 2) * 64; ncols = 256; }
  __shared__ float tile[64][68];
  const int t = threadIdx.x;
  const int rj = (t & 15) << 2, rci = t >> 4;
#pragma unroll
  for (int i = 0; i < 4; ++i) {
    const int ci_l = rci + 16 * i;
    const float4 v = *(const float4*)(W + (size_t)(ci0 + ci_l) * ncols + j0 + rj);
    tile[ci_l][rj + 0] = v.x; tile[ci_l][rj + 1] = v.y;
    tile[ci_l][rj + 2] = v.z; tile[ci_l][rj + 3] = v.w;
  }
  __syncthreads();
#pragma unroll
  for (int i = 0; i < 2; ++i) {
    const int u = t + 256 * i;
    const int p = u >> 3, s = u & 7;
    unsigned int w[4];
#pragma unroll
    for (int q = 0; q < 4; ++q) {
      const u16 lo = f2bfbits(tile[s * 8 + 2 * q][p]);
      const u16 hi = f2bfbits(tile[s * 8 + 2 * q + 1][p]);
      w[q] = (unsigned int)lo | ((unsigned int)hi << 16);
    }
    *(uint4*)(T + (size_t)(j0 + p) * C_ + ci0 + s * 8) = make_uint4(w[0], w[1], w[2], w[3]);
  }
}

// ---------------- dwconv weight transpose: dwcT[q][ci], q=0..8 taps, q=9 bias ----------------
__global__ __launch_bounds__(256) void k_prep_dwc(const float* __restrict__ dwc_w, const float* __restrict__ dwc_b,
                                                  float* __restrict__ dwcT) {
  const int ci = threadIdx.x;
#pragma unroll
  for (int q = 0; q < 9; ++q) dwcT[q * 256 + ci] = dwc_w[ci * 9 + q];
  dwcT[9 * 256 + ci] = dwc_b[ci];
}

// ---------------- V projection only: V[b,pos,256] = At @ Wv + bv ----------------
__global__ __launch_bounds__(256) void k_v_mfma(const u16* __restrict__ At1, const u16* __restrict__ At2,
                                                const u16* __restrict__ Wkt, const float* __restrict__ kv_b,
                                                u16* __restrict__ v1, u16* __restrict__ v2) {
  const int z = blockIdx.z;
  const int src = z >> 3, b = z & 7;
  const u16* At = src ? At2 : At1;
  u16* vout = src ? v2 : v1;
  const int pos0 = blockIdx.x * 128;
  const int j0 = blockIdx.y * 128;

  __shared__ __align__(16) u16 SM[16384];
  u16* Ab = SM;
  u16* Bb = SM + 8192;

  const int t = threadIdx.x;
  const int wave = t >> 6, lane = t & 63;
  const int wm = wave >> 1, wn = wave & 1;
  const int g = lane >> 4;

  const u16* Ag = Wkt + (size_t)(256 + j0) * C_;
  const u16* Bg = At + ((size_t)b * NPOS + pos0) * C_;

  f32x4 acc[4][4];
#pragma unroll
  for (int m = 0; m < 4; ++m)
#pragma unroll
    for (int n = 0; n < 4; ++n) { acc[m][n][0]=0.f; acc[m][n][1]=0.f; acc[m][n][2]=0.f; acc[m][n][3]=0.f; }

  uint4 ra[4], rb[4];
#define V_LOAD(KT)                                                         \
  _Pragma("unroll") for (int i = 0; i < 4; ++i) {                          \
    const int u = t + 256 * i, rr = u >> 3, ss = u & 7;                    \
    ra[i] = *(const uint4*)(Ag + (size_t)rr * C_ + (KT) * 64 + ss * 8);    \
    rb[i] = *(const uint4*)(Bg + (size_t)rr * C_ + (KT) * 64 + ss * 8);    \
  }
#define V_WRITE()                                                          \
  _Pragma("unroll") for (int i = 0; i < 4; ++i) {                          \
    const int u = t + 256 * i, rr = u >> 3, ss = u & 7;                    \
    const int sw = ((ss ^ (rr & 7)) << 3);                                 \
    *(uint4*)(Ab + rr * 64 + sw) = ra[i];                                  \
    *(uint4*)(Bb + rr * 64 + sw) = rb[i];                                  \
  }

  V_LOAD(0);
  V_WRITE();
  V_LOAD(1);
  __syncthreads();

  for (int kt = 0; kt < 4; ++kt) {
#pragma unroll
    for (int kk = 0; kk < 2; ++kk) {
      bf16x8 af[4], bfr[4];
#pragma unroll
      for (int m = 0; m < 4; ++m) {
        const int r = wm * 64 + m * 16 + (lane & 15);
        af[m] = *(const bf16x8*)(Ab + r * 64 + (((kk * 4 + g) ^ (r & 7)) << 3));
      }
#pragma unroll
      for (int n = 0; n < 4; ++n) {
        const int c = wn * 64 + n * 16 + (lane & 15);
        bfr[n] = *(const bf16x8*)(Bb + c * 64 + (((kk * 4 + g) ^ (c & 7)) << 3));
      }
#pragma unroll
      for (int m = 0; m < 4; ++m)
#pragma unroll
        for (int n = 0; n < 4; ++n)
          acc[m][n] = __builtin_amdgcn_mfma_f32_16x16x32_bf16(af[m], bfr[n], acc[m][n], 0, 0, 0);
    }
    if (kt < 3) {
      __syncthreads();
      V_WRITE();
      if (kt < 2) V_LOAD(kt + 2);
      __syncthreads();
    }
  }
#undef V_LOAD
#undef V_WRITE

  __syncthreads();
#pragma unroll
  for (int m = 0; m < 4; ++m) {
    const int jl = wm * 64 + m * 16 + (lane >> 4) * 4;
    const float4 bv = *(const float4*)(kv_b + 256 + j0 + jl);
#pragma unroll
    for (int n = 0; n < 4; ++n) {
      const int pos_l = wn * 64 + n * 16 + (lane & 15);
      const f32x4 a = acc[m][n];
      ushort4 st;
      st.x = f2bfbits(a[0] + bv.x); st.y = f2bfbits(a[1] + bv.y);
      st.z = f2bfbits(a[2] + bv.z); st.w = f2bfbits(a[3] + bv.w);
      const int slot = (jl >> 3) ^ (pos_l & 7);
      *(ushort4*)(SM + pos_l * 128 + slot * 8 + (jl & 7)) = st;
    }
  }
  __syncthreads();
#pragma unroll
  for (int i = 0; i < 8; ++i) {
    const int idx = t + 256 * i;
    const int row = idx >> 4, sl = idx & 15;
    const uint4 v = *(const uint4*)(SM + row * 128 + ((sl ^ (row & 7)) << 3));
    *(uint4*)(vout + ((size_t)b * NPOS + pos0 + row) * C_ + j0 + sl * 8) = v;
  }
}

// ---------------- score GEMM: E[sb,ha,pos] = exp(At @ wt^T + posbT + kvbD) bf16, + row sums ----------------
__global__ __launch_bounds__(256) void k_score(const u16* __restrict__ At1, const u16* __restrict__ At2,
                                               const u16* __restrict__ wt, const float* __restrict__ posbT,
                                               const float* __restrict__ kvbD,
                                               u16* __restrict__ E, float* __restrict__ lsumP) {
  const int z = blockIdx.z;
  const int src = z >> 3, b = z & 7;
  const int sb = src * 8 + b;
  const u16* At = src ? At2 : At1;
  const int pos0 = blockIdx.x * 128;

  __shared__ __align__(16) u16 SM[16384];
  __shared__ float lsum_sm[2][128];
  u16* Ab = SM;
  u16* Bb = SM + 8192;

  const int t = threadIdx.x;
  const int wave = t >> 6, lane = t & 63;
  const int wm = wave >> 1, wn = wave & 1;
  const int g = lane >> 4;

  const u16* Ag = At + ((size_t)b * NPOS + pos0) * C_;
  const u16* Bg = wt + (size_t)b * NHA * C_;

  f32x4 acc[4][4];
#pragma unroll
  for (int m = 0; m < 4; ++m)
#pragma unroll
    for (int n = 0; n < 4; ++n) { acc[m][n][0]=0.f; acc[m][n][1]=0.f; acc[m][n][2]=0.f; acc[m][n][3]=0.f; }

  uint4 ra[4], rb[4];
#define S_LOAD(KT)                                                         \
  _Pragma("unroll") for (int i = 0; i < 4; ++i) {                          \
    const int u = t + 256 * i, rr = u >> 3, ss = u & 7;                    \
    ra[i] = *(const uint4*)(Ag + (size_t)rr * C_ + (KT) * 64 + ss * 8);    \
    rb[i] = *(const uint4*)(Bg + (size_t)rr * C_ + (KT) * 64 + ss * 8);    \
  }
#define S_WRITE()                                                          \
  _Pragma("unroll") for (int i = 0; i < 4; ++i) {                          \
    const int u = t + 256 * i, rr = u >> 3, ss = u & 7;                    \
    const int sw = ((ss ^ (rr & 7)) << 3);                                 \
    *(uint4*)(Ab + rr * 64 + sw) = ra[i];                                  \
    *(uint4*)(Bb + rr * 64 + sw) = rb[i];                                  \
  }

  S_LOAD(0);
  S_WRITE();
  S_LOAD(1);
  __syncthreads();

  for (int kt = 0; kt < 4; ++kt) {
#pragma unroll
    for (int kk = 0; kk < 2; ++kk) {
      bf16x8 af[4], bfr[4];
#pragma unroll
      for (int m = 0; m < 4; ++m) {
        const int r = wm * 64 + m * 16 + (lane & 15);
        af[m] = *(const bf16x8*)(Ab + r * 64 + (((kk * 4 + g) ^ (r & 7)) << 3));
      }
#pragma unroll
      for (int n = 0; n < 4; ++n) {
        const int c = wn * 64 + n * 16 + (lane & 15);
        bfr[n] = *(const bf16x8*)(Bb + c * 64 + (((kk * 4 + g) ^ (c & 7)) << 3));
      }
#pragma unroll
      for (int m = 0; m < 4; ++m)
#pragma unroll
        for (int n = 0; n < 4; ++n)
          acc[m][n] = __builtin_amdgcn_mfma_f32_16x16x32_bf16(af[m], bfr[n], acc[m][n], 0, 0, 0);
    }
    if (kt < 3) {
      __syncthreads();
      S_WRITE();
      if (kt < 2) S_LOAD(kt + 2);
      __syncthreads();
    }
  }
#undef S_LOAD
#undef S_WRITE

  __syncthreads();
  float ls[4] = {0.f, 0.f, 0.f, 0.f};
#pragma unroll
  for (int n = 0; n < 4; ++n) {
    const int ha_l = wn * 64 + n * 16 + (lane & 15);
    const float kb = kvbD[b * NHA + ha_l];
#pragma unroll
    for (int m = 0; m < 4; ++m) {
      const int pos_l = wm * 64 + m * 16 + (lane >> 4) * 4;
      float e[4];
#pragma unroll
      for (int j = 0; j < 4; ++j) {
        const float s = acc[m][n][j] + posbT[(size_t)(pos0 + pos_l + j) * NHA + ha_l] + kb;
        e[j] = __expf(s);
        ls[n] += e[j];
      }
      ushort4 st;
      st.x = f2bfbits(e[0]); st.y = f2bfbits(e[1]); st.z = f2bfbits(e[2]); st.w = f2bfbits(e[3]);
      const int sw = (pos_l >> 3) ^ (ha_l & 15);
      *(ushort4*)(SM + ha_l * 128 + sw * 8 + (pos_l & 7)) = st;
    }
  }
#pragma unroll
  for (int n = 0; n < 4; ++n) {
    float v = ls[n];
    v += __shfl_xor(v, 16);
    v += __shfl_xor(v, 32);
    ls[n] = v;
  }
  if (lane < 16) {
#pragma unroll
    for (int n = 0; n < 4; ++n) lsum_sm[wm][wn * 64 + n * 16 + lane] = ls[n];
  }
  __syncthreads();
  if (t < 128)
    lsumP[((size_t)sb * 32 + blockIdx.x) * NHA + t] = lsum_sm[0][t] + lsum_sm[1][t];
#pragma unroll
  for (int i = 0; i < 8; ++i) {
    const int idx = t + 256 * i;
    const int row = idx >> 4, sl = idx & 15;
    const uint4 v = *(const uint4*)(SM + row * 128 + ((sl ^ (row & 15)) << 3));
    *(uint4*)(E + ((size_t)sb * NHA + row) * NPOS + pos0 + sl * 8) = v;
  }
}

// ---------------- PV GEMM: T_p[sb,kc,ha,ci] = sum_pos in[ci,pos] * E[ha,pos] ----------------
__global__ __launch_bounds__(256) void k_pv(const float* __restrict__ in1, const float* __restrict__ in2,
                                            const u16* __restrict__ E, float* __restrict__ T_p) {
  const int kc = blockIdx.x;
  const int ci0 = blockIdx.y * 128;
  const int sb = blockIdx.z;
  const int src = sb >> 3, b = sb & 7;
  const float* in = src ? in2 : in1;
  const int kpos0 = kc * 512;

  __shared__ __align__(16) u16 As[8192];
  __shared__ __align__(16) u16 Bs[8192];

  const int t = threadIdx.x;
  const int wave = t >> 6, lane = t & 63;
  const int wm = wave >> 1, wn = wave & 1;
  const int g = lane >> 4;

  const float* Ain = in + (size_t)b * C_ * NPOS;
  const u16* Eg = E + (size_t)sb * NHA * NPOS;

  f32x4 acc[4][4];
#pragma unroll
  for (int m = 0; m < 4; ++m)
#pragma unroll
    for (int n = 0; n < 4; ++n) { acc[m][n][0]=0.f; acc[m][n][1]=0.f; acc[m][n][2]=0.f; acc[m][n][3]=0.f; }

  float4 pa[8];
  uint4 pb[4];
#define PV_LOAD(KT)                                                            \
  _Pragma("unroll") for (int i = 0; i < 8; ++i) {                              \
    const int idx = t + 256 * i, rr = idx >> 4, fq = idx & 15;                 \
    pa[i] = *(const float4*)(Ain + (size_t)(ci0 + rr) * NPOS + kpos0 + (KT) * 64 + fq * 4); \
  }                                                                            \
  _Pragma("unroll") for (int i = 0; i < 4; ++i) {                              \
    const int idx = t + 256 * i, rr = idx >> 3, ss = idx & 7;                  \
    pb[i] = *(const uint4*)(Eg + (size_t)rr * NPOS + kpos0 + (KT) * 64 + ss * 8); \
  }
#define PV_WRITE()                                                             \
  _Pragma("unroll") for (int i = 0; i < 8; ++i) {                              \
    const int idx = t + 256 * i, rr = idx >> 4, fq = idx & 15;                 \
    ushort4 st;                                                                \
    st.x = f2bfbits(pa[i].x); st.y = f2bfbits(pa[i].y);                        \
    st.z = f2bfbits(pa[i].z); st.w = f2bfbits(pa[i].w);                        \
    const int sw = ((fq >> 1) ^ (rr & 7));                                     \
    *(ushort4*)(As + rr * 64 + sw * 8 + (fq & 1) * 4) = st;                    \
  }                                                                            \
  _Pragma("unroll") for (int i = 0; i < 4; ++i) {                              \
    const int idx = t + 256 * i, rr = idx >> 3, ss = idx & 7;                  \
    *(uint4*)(Bs + rr * 64 + ((ss ^ (rr & 7)) << 3)) = pb[i];                  \
  }

  PV_LOAD(0);
  PV_WRITE();
  PV_LOAD(1);
  __syncthreads();

  for (int kt = 0; kt < 8; ++kt) {
#pragma unroll
    for (int kk = 0; kk < 2; ++kk) {
      bf16x8 af[4], bfr[4];
#pragma unroll
      for (int m = 0; m < 4; ++m) {
        const int r = wm * 64 + m * 16 + (lane & 15);
        af[m] = *(const bf16x8*)(As + r * 64 + (((kk * 4 + g) ^ (r & 7)) << 3));
      }
#pragma unroll
      for (int n = 0; n < 4; ++n) {
        const int c = wn * 64 + n * 16 + (lane & 15);
        bfr[n] = *(const bf16x8*)(Bs + c * 64 + (((kk * 4 + g) ^ (c & 7)) << 3));
      }
#pragma unroll
      for (int m = 0; m < 4; ++m)
#pragma unroll
        for (int n = 0; n < 4; ++n)
          acc[m][n] = __builtin_amdgcn_mfma_f32_16x16x32_bf16(af[m], bfr[n], acc[m][n], 0, 0, 0);
    }
    if (kt < 7) {
      __syncthreads();
      PV_WRITE();
      if (kt < 6) PV_LOAD(kt + 2);
      __syncthreads();
    }
  }
#undef PV_LOAD
#undef PV_WRITE

#pragma unroll
  for (int m = 0; m < 4; ++m) {
    const int ci_l = wm * 64 + m * 16 + (lane >> 4) * 4;
#pragma unroll
    for (int n = 0; n < 4; ++n) {
      const int ha_l = wn * 64 + n * 16 + (lane & 15);
      const f32x4 a = acc[m][n];
      *(float4*)(T_p + (((size_t)sb * 8 + kc) * NHA + ha_l) * C_ + ci0 + ci_l) =
          make_float4(a[0], a[1], a[2], a[3]);
    }
  }
}

// ---------------- agent_v = (sum_kc T)/lsum @ Wv + bv ----------------
__global__ __launch_bounds__(256) void k_agentv(const float* __restrict__ T_p, const float* __restrict__ lsumP,
                                                const u16* __restrict__ Wkt, const float* __restrict__ kv_b,
                                                float* __restrict__ agent_v) {
  const int h = blockIdx.x, sb = blockIdx.y;
  const int t = threadIdx.x;
  __shared__ float Tred[16 * 256];
  __shared__ u16 Wv[32 * 256];
  __shared__ float lsum_s[16];
#pragma unroll
  for (int i = 0; i < 4; ++i) {
    const int idx = t + 256 * i;
    const int r = idx >> 5, sl = idx & 31;
    *(uint4*)(Wv + r * 256 + sl * 8) = *(const uint4*)(Wkt + (size_t)(256 + h * 32 + r) * C_ + sl * 8);
  }
#pragma unroll
  for (int i = 0; i < 16; ++i) {
    const int idx = t + 256 * i;
    const int a = idx >> 8, ci = idx & 255;
    float s = 0.f;
#pragma unroll
    for (int kc = 0; kc < 8; ++kc)
      s += T_p[(((size_t)sb * 8 + kc) * NHA + h * 16 + a) * C_ + ci];
    Tred[a * 256 + ci] = s;
  }
  if (t < 16) {
    float s = 0.f;
#pragma unroll
    for (int pt = 0; pt < 32; ++pt) s += lsumP[((size_t)sb * 32 + pt) * NHA + h * 16 + t];
    lsum_s[t] = s;
  }
  __syncthreads();
  const int a = t >> 4, dp = (t & 15) * 2;
  float o0 = 0.f, o1 = 0.f;
  const float* Tr = Tred + a * 256;
  for (int ci = 0; ci < 256; ++ci) {
    const float tv = Tr[ci];
    o0 += tv * bfbits2f(Wv[dp * 256 + ci]);
    o1 += tv * bfbits2f(Wv[(dp + 1) * 256 + ci]);
  }
  const float inv = 1.0f / lsum_s[a];
  float* op = agent_v + (size_t)sb * NHA * HD + (h * 16 + a) * HD + dp;
  op[0] = o0 * inv + kv_b[256 + h * 32 + dp];
  op[1] = o1 * inv + kv_b[256 + h * 32 + dp + 1];
}

// ---------------- query attention v2: one src per block, inline agent-bias ----------------
__global__ __launch_bounds__(256) void k_qattn(const float* __restrict__ g,
                                               const float* __restrict__ q_w, const float* __restrict__ q_b,
                                               const float* __restrict__ agent_buf,
                                               const float* __restrict__ agent_v,
                                               const float* __restrict__ na_b,
                                               const float* __restrict__ ha_b,
                                               const float* __restrict__ wa_b,
                                               u16* __restrict__ o1s, u16* __restrict__ o2s) {
  const int h = blockIdx.y;
  const int sb = blockIdx.z;
  const int src = sb >> 3, b = sb & 7;
  u16* out = src ? o2s : o1s;
  const int t = threadIdx.x;
  const int pos = blockIdx.x * 256 + t;
  __shared__ float dotW[16], dotB[16];
  __shared__ float av[16][32];
  __shared__ float nab[16][16];   // na_b table for this h (1KB)
  for (int idx = t; idx < 512; idx += 256) {
    const int a = idx >> 5, d = idx & 31;
    av[a][d] = agent_v[(size_t)sb * NHA * HD + (h * 16 + a) * HD + d];
  }
  if (t < 256 && t < 16 * 16) {
    const int a = t >> 4, q = t & 15;
    nab[a][q] = na_b[((size_t)h * NA + a) * 16 + q];
  }
  if (t < 16) {
    float dw = 0.f, db = 0.f;
    const float* agp = agent_buf + (((size_t)b * NH + h) * NA + t) * HD;
#pragma unroll
    for (int d = 0; d < HD; ++d) {
      const float ad = agp[d];
      dw += ad * q_w[h * HD + d];
      db += ad * q_b[h * HD + d];
    }
    dotW[t] = dw * SCALE;
    dotB[t] = db * SCALE;
  }
  __syncthreads();
  // inline agent bias: bilinear(na_b) + ha_b + wa_b
  const int y = pos >> 6, x = pos & 63;
  const float sy = (y + 0.5f) * 0.0625f - 0.5f;
  const float sx = (x + 0.5f) * 0.0625f - 0.5f;
  const int y0 = (int)floorf(sy);
  const int x0 = (int)floorf(sx);
  const float wy = sy - (float)y0, wx = sx - (float)x0;
  const int y0c = min(max(y0, 0), 3), y1c = min(max(y0 + 1, 0), 3);
  const int x0c = min(max(x0, 0), 3), x1c = min(max(x0 + 1, 0), 3);
  const float c00 = (1.f - wy) * (1.f - wx), c01 = (1.f - wy) * wx;
  const float c10 = wy * (1.f - wx), c11 = wy * wx;
  const int i00 = y0c * 4 + x0c, i01 = y0c * 4 + x1c;
  const int i10 = y1c * 4 + x0c, i11 = y1c * 4 + x1c;
  const float* hp = ha_b + ((size_t)h * HH + y) * NA;
  const float* wp = wa_b + ((size_t)h * WW + x) * NA;
  const float gv = g[(size_t)b * NPOS + pos];
  float s[16];
  float m = -1e30f;
#pragma unroll
  for (int a = 0; a < 16; ++a) {
    const float nv = c00 * nab[a][i00] + c01 * nab[a][i01] + c10 * nab[a][i10] + c11 * nab[a][i11];
    s[a] = gv * dotW[a] + dotB[a] + nv + hp[a] + wp[a];
    m = fmaxf(m, s[a]);
  }
  float l = 0.f;
#pragma unroll
  for (int a = 0; a < 16; ++a) {
    s[a] = __expf(s[a] - m);
    l += s[a];
  }
  const float inv = 1.0f / l;
  float o[32] = {};
#pragma unroll
  for (int a = 0; a < 16; ++a) {
    const float pa = s[a] * inv;
#pragma unroll
    for (int q = 0; q < 8; ++q) {
      const float4 v4 = *(const float4*)&av[a][q * 4];
      o[q * 4 + 0] += pa * v4.x; o[q * 4 + 1] += pa * v4.y;
      o[q * 4 + 2] += pa * v4.z; o[q * 4 + 3] += pa * v4.w;
    }
  }
  u16* op = out + ((size_t)b * NPOS + pos) * C_ + h * HD;
#pragma unroll
  for (int blk = 0; blk < 4; ++blk) {
    unsigned int w1[4];
#pragma unroll
    for (int q = 0; q < 4; ++q)
      w1[q] = (unsigned int)f2bfbits(o[blk * 8 + 2 * q]) | ((unsigned int)f2bfbits(o[blk * 8 + 2 * q + 1]) << 16);
    *(uint4*)(op + blk * 8) = make_uint4(w1[0], w1[1], w1[2], w1[3]);
  }
}

// ---------------- depthwise 3x3 conv v2: 8ch/thread vectorized, RMW o1s/o2s ----------------
__global__ __launch_bounds__(256) void k_dwconv(const u16* __restrict__ v1, const u16* __restrict__ v2,
                                                const float* __restrict__ dwcT,
                                                u16* __restrict__ o1s, u16* __restrict__ o2s) {
  const u16* V = blockIdx.z ? v2 : v1;
  u16* out = blockIdx.z ? o2s : o1s;
  const int b = blockIdx.y;
  const int t = threadIdx.x;
  const int cg = t & 31;
  const int ch = cg * 8;
  const int px = t >> 5;
  const int pos = (blockIdx.x << 3) + px;
  const int y = pos >> 6, x = pos & 63;

  float acc[8];
  {
    const float4 b0 = *(const float4*)(dwcT + 9 * 256 + ch);
    const float4 b1 = *(const float4*)(dwcT + 9 * 256 + ch + 4);
    acc[0] = b0.x; acc[1] = b0.y; acc[2] = b0.z; acc[3] = b0.w;
    acc[4] = b1.x; acc[5] = b1.y; acc[6] = b1.z; acc[7] = b1.w;
  }
  const u16* vb = V + (size_t)b * NPOS * C_ + ch;
#pragma unroll
  for (int dy = -1; dy <= 1; ++dy) {
    const int yy = y + dy;
    if (yy < 0 || yy > 63) continue;
#pragma unroll
    for (int dx = -1; dx <= 1; ++dx) {
      const int xx = x + dx;
      if (xx < 0 || xx > 63) continue;
      const int q = (dy + 1) * 3 + (dx + 1);
      const float4 w0 = *(const float4*)(dwcT + q * 256 + ch);
      const float4 w1 = *(const float4*)(dwcT + q * 256 + ch + 4);
      const uint4 vv = *(const uint4*)(vb + (size_t)(yy * 64 + xx) * C_);
      float f8[8];
      unpack8(vv, f8);
      acc[0] += w0.x * f8[0]; acc[1] += w0.y * f8[1];
      acc[2] += w0.z * f8[2]; acc[3] += w0.w * f8[3];
      acc[4] += w1.x * f8[4]; acc[5] += w1.y * f8[5];
      acc[6] += w1.z * f8[6]; acc[7] += w1.w * f8[7];
    }
  }
  u16* op = out + ((size_t)b * NPOS + pos) * C_ + ch;
  const uint4 ov = *(const uint4*)op;
  float f8[8];
  unpack8(ov, f8);
  unsigned int wo[4];
#pragma unroll
  for (int q2 = 0; q2 < 4; ++q2)
    wo[q2] = (unsigned int)f2bfbits(f8[2 * q2] + acc[2 * q2]) |
             ((unsigned int)f2bfbits(f8[2 * q2 + 1] + acc[2 * q2 + 1]) << 16);
  *(uint4*)op = make_uint4(wo[0], wo[1], wo[2], wo[3]);
}

// ---------------- output projection, bf16 MFMA -> (b,c,n) f32 + bias + residual ----------------
__global__ __launch_bounds__(256) void k_proj_mfma(const u16* __restrict__ o1s, const u16* __restrict__ o2s,
                                                   const u16* __restrict__ Pwt, const float* __restrict__ proj_b,
                                                   const float* __restrict__ in1, const float* __restrict__ in2,
                                                   float* __restrict__ out1, float* __restrict__ out2) {
  const int z = blockIdx.z;
  const int src = z >> 3, b = z & 7;
  const u16* S = src ? o2s : o1s;
  const float* inp = src ? in2 : in1;
  float* outp = src ? out2 : out1;
  const int pos0 = blockIdx.x * 128;
  const int co0 = blockIdx.y * 128;

  __shared__ __align__(16) u16 SM[16384];
  u16* Ab = SM;
  u16* Bb = SM + 8192;
  float* SMF = (float*)SM;

  const int t = threadIdx.x;
  const int wave = t >> 6, lane = t & 63;
  const int wm = wave >> 1, wn = wave & 1;
  const int g = lane >> 4;

  const u16* Ag = S + ((size_t)b * NPOS + pos0) * C_;
  const u16* Bg = Pwt + (size_t)co0 * C_;

  f32x4 acc[4][4];
#pragma unroll
  for (int m = 0; m < 4; ++m)
#pragma unroll
    for (int n = 0; n < 4; ++n) { acc[m][n][0]=0.f; acc[m][n][1]=0.f; acc[m][n][2]=0.f; acc[m][n][3]=0.f; }

  uint4 ra[4], rb[4];
#define PJ_LOAD(KT)                                                        \
  _Pragma("unroll") for (int i = 0; i < 4; ++i) {                          \
    const int u = t + 256 * i, rr = u >> 3, ss = u & 7;                    \
    ra[i] = *(const uint4*)(Ag + (size_t)rr * C_ + (KT) * 64 + ss * 8);    \
    rb[i] = *(const uint4*)(Bg + (size_t)rr * C_ + (KT) * 64 + ss * 8);    \
  }
#define PJ_WRITE()                                                         \
  _Pragma("unroll") for (int i = 0; i < 4; ++i) {                          \
    const int u = t + 256 * i, rr = u >> 3, ss = u & 7;                    \
    const int sw = ((ss ^ (rr & 7)) << 3);                                 \
    *(uint4*)(Ab + rr * 64 + sw) = ra[i];                                  \
    *(uint4*)(Bb + rr * 64 + sw) = rb[i];                                  \
  }

  PJ_LOAD(0);
  PJ_WRITE();
  PJ_LOAD(1);
  __syncthreads();

  for (int kt = 0; kt < 4; ++kt) {
#pragma unroll
    for (int kk = 0; kk < 2; ++kk) {
      bf16x8 af[4], bfr[4];
#pragma unroll
      for (int m = 0; m < 4; ++m) {
        const int r = wm * 64 + m * 16 + (lane & 15);
        af[m] = *(const bf16x8*)(Ab + r * 64 + (((kk * 4 + g) ^ (r & 7)) << 3));
      }
#pragma unroll
      for (int n = 0; n < 4; ++n) {
        const int c = wn * 64 + n * 16 + (lane & 15);
        bfr[n] = *(const bf16x8*)(Bb + c * 64 + (((kk * 4 + g) ^ (c & 7)) << 3));
      }
#pragma unroll
      for (int m = 0; m < 4; ++m)
#pragma unroll
        for (int n = 0; n < 4; ++n)
          acc[m][n] = __builtin_amdgcn_mfma_f32_16x16x32_bf16(af[m], bfr[n], acc[m][n], 0, 0, 0);
    }
    if (kt < 3) {
      __syncthreads();
      PJ_WRITE();
      if (kt < 2) PJ_LOAD(kt + 2);
      __syncthreads();
    }
  }
#undef PJ_LOAD
#undef PJ_WRITE

#pragma unroll
  for (int hf = 0; hf < 2; ++hf) {
    __syncthreads();
    if (wn == hf) {
#pragma unroll
      for (int n = 0; n < 4; ++n) {
        const int co_l = n * 16 + (lane & 15);
#pragma unroll
        for (int m = 0; m < 4; ++m) {
          const int pos_l = wm * 64 + m * 16 + (lane >> 4) * 4;
          const int slot = (pos_l >> 2) ^ (co_l & 7);
          const f32x4 a = acc[m][n];
          *(float4*)(SMF + co_l * 128 + slot * 4) = make_float4(a[0], a[1], a[2], a[3]);
        }
      }
    }
    __syncthreads();
#pragma unroll
    for (int i = 0; i < 8; ++i) {
      const int idx = t + 256 * i;
      const int row = idx >> 5, sl = idx & 31;
      const float4 v = *(const float4*)(SMF + row * 128 + ((sl ^ (row & 7)) << 2));
      const int co = co0 + hf * 64 + row;
      const float pb = proj_b[co];
      const size_t base = ((size_t)b * C_ + co) * NPOS + pos0 + sl * 4;
      const float4 res = *(const float4*)(inp + base);
      *(float4*)(outp + base) = make_float4(v.x + pb + res.x, v.y + pb + res.y,
                                            v.z + pb + res.z, v.w + pb + res.w);
    }
  }
}

extern "C" void kernel_launch(void* const* d_in, const int* in_sizes, int n_in,
                              void* d_out, int out_size, void* d_ws, size_t ws_size,
                              hipStream_t stream) {
  const float* input1 = (const float*)d_in[0];
  const float* input2 = (const float*)d_in[1];
  const float* guid   = (const float*)d_in[2];
  const float* kv_w   = (const float*)d_in[3];
  const float* kv_b   = (const float*)d_in[4];
  const float* q_w    = (const float*)d_in[5];
  const float* q_b    = (const float*)d_in[6];
  const float* proj_w = (const float*)d_in[7];
  const float* proj_b = (const float*)d_in[8];
  const float* dwc_w  = (const float*)d_in[9];
  const float* dwc_b  = (const float*)d_in[10];
  const float* an_b   = (const float*)d_in[11];
  const float* na_b   = (const float*)d_in[12];
  const float* ah_b   = (const float*)d_in[13];
  const float* aw_b   = (const float*)d_in[14];
  const float* ha_b   = (const float*)d_in[15];
  const float* wa_b   = (const float*)d_in[16];

  char* W = (char*)d_ws;
  u16* At1 = (u16*)W;        W += (size_t)B_ * NPOS * C_ * 2;
  u16* At2 = (u16*)W;        W += (size_t)B_ * NPOS * C_ * 2;
  u16* v1  = (u16*)W;        W += (size_t)B_ * NPOS * C_ * 2;
  u16* v2  = (u16*)W;        W += (size_t)B_ * NPOS * C_ * 2;
  u16* o1s = (u16*)W;        W += (size_t)B_ * NPOS * C_ * 2;
  u16* o2s = (u16*)W;        W += (size_t)B_ * NPOS * C_ * 2;
  u16* E   = (u16*)W;        W += (size_t)16 * NHA * NPOS * 2;
  float* T_p = (float*)W;    W += (size_t)16 * 8 * NHA * C_ * 4;
  u16* Wkt = (u16*)W;        W += (size_t)512 * C_ * 2;
  u16* Pwt = (u16*)W;        W += (size_t)C_ * C_ * 2;
  u16* wt  = (u16*)W;        W += (size_t)B_ * NHA * C_ * 2;
  float* posbT = (float*)W;  W += (size_t)NPOS * NHA * 4;
  float* agentb = (float*)W; W += (size_t)B_ * NH * NA * HD * 4;
  float* kvbD   = (float*)W; W += (size_t)B_ * NHA * 4;
  float* lsumP  = (float*)W; W += (size_t)16 * 32 * NHA * 4;
  float* agent_v = (float*)W; W += (size_t)16 * NHA * HD * 4;
  float* dwcT    = (float*)W; W += (size_t)10 * 256 * 4;

  float* out1 = (float*)d_out;
  float* out2 = out1 + (size_t)B_ * C_ * NPOS;

  hipLaunchKernelGGL(k_agent, dim3(B_), dim3(256), 0, stream, guid, q_w, q_b, agentb);
  hipLaunchKernelGGL(k_bias, dim3((NHA * NPOS) / 256), dim3(256), 0, stream,
                     an_b, ah_b, aw_b, posbT);
  hipLaunchKernelGGL(k_prep_w, dim3(48), dim3(256), 0, stream, kv_w, proj_w, Wkt, Pwt);
  hipLaunchKernelGGL(k_prep_dwc, dim3(1), dim3(256), 0, stream, dwc_w, dwc_b, dwcT);
  hipLaunchKernelGGL(k_wtilde, dim3(NH, B_), dim3(256), 0, stream, Wkt, kv_b, agentb, wt, kvbD);
  hipLaunchKernelGGL(k_prep_in, dim3(64, 4, 16), dim3(256), 0, stream, input1, input2, At1, At2);
  hipLaunchKernelGGL(k_v_mfma, dim3(32, 2, 16), dim3(256), 0, stream,
                     At1, At2, Wkt, kv_b, v1, v2);
  hipLaunchKernelGGL(k_score, dim3(32, 1, 16), dim3(256), 0, stream,
                     At1, At2, wt, posbT, kvbD, E, lsumP);
  hipLaunchKernelGGL(k_pv, dim3(8, 2, 16), dim3(256), 0, stream, input1, input2, E, T_p);
  hipLaunchKernelGGL(k_agentv, dim3(NH, 16), dim3(256), 0, stream, T_p, lsumP, Wkt, kv_b, agent_v);
  hipLaunchKernelGGL(k_qattn, dim3(NPOS / 256, NH, 16), dim3(256), 0, stream,
                     guid, q_w, q_b, agentb, agent_v, na_b, ha_b, wa_b, o1s, o2s);
  hipLaunchKernelGGL(k_dwconv, dim3(NPOS / 8, B_, 2), dim3(256), 0, stream,
                     v1, v2, dwcT, o1s, o2s);
  hipLaunchKernelGGL(k_proj_mfma, dim3(32, 2, 16), dim3(256), 0, stream,
                     o1s, o2s, Pwt, proj_b, input1, input2, out1, out2);
}